// Round 8
// baseline (649.172 us; speedup 1.0000x reference)
//
#include <hip/hip_runtime.h>
#include <hip/hip_bf16.h>
#include <math.h>

#define NN 50000
#define DD 128
#define EE 800000

static constexpr float BN_EPS = 1e-3f;

typedef __attribute__((ext_vector_type(8))) short bf16x8;
typedef __attribute__((ext_vector_type(4))) float f32x4;

#define MFMA16(a, b, c) __builtin_amdgcn_mfma_f32_16x16x32_bf16((a), (b), (c), 0, 0, 0)

// fast exact-grade GELU: Abramowitz-Stegun 7.1.26 erf (abs err 1.5e-7)
__device__ __forceinline__ float gelu_f(float x) {
    float ax = fabsf(x) * 0.7071067811865475f;
    float t = __builtin_amdgcn_rcpf(fmaf(0.3275911f, ax, 1.0f));
    float p = t * fmaf(t, fmaf(t, fmaf(t, fmaf(t, 1.061405429f, -1.453152027f),
                                       1.421413741f), -0.284496736f), 0.254829592f);
    float e = __expf(-ax * ax);
    float er = fmaf(-p, e, 1.0f);        // erf(|x|/sqrt2) for ax>=0
    float s = copysignf(er, x);
    return 0.5f * x * (1.0f + s);
}

__device__ __forceinline__ ushort f2bf_rn(float f) {
    uint u = __float_as_uint(f);
    return (ushort)((u + 0x7FFFu + ((u >> 16) & 1u)) >> 16);
}
__device__ __forceinline__ float bf2f(ushort h) {
    return __uint_as_float(((uint)h) << 16);
}

// packed pair f32->bf16 RNE (compiler emits v_cvt_pk_bf16_f32); low16=a, high16=b
__device__ __forceinline__ uint pk2(float a, float b) {
    __hip_bfloat162 t = __float22bfloat162_rn(make_float2(a, b));
    uint r;
    __builtin_memcpy(&r, &t, 4);
    return r;
}

// packed bf16 atomic add (2 cols per op) — halves memory-side RMW op count
__device__ __forceinline__ void atomic_pk_add_bf16(ushort* addr, uint val) {
    asm volatile("global_atomic_pk_add_bf16 %0, %1, off"
                 :: "v"((void*)addr), "v"(val) : "memory");
}

// split f32x8 -> bf16 hi + bf16 lo fragments (f ~= hi + lo, |resid| ~ 2^-17|f|)
__device__ __forceinline__ void cvt_hilo(float4 x0, float4 x1, bf16x8& h, bf16x8& l) {
    float f[8] = {x0.x, x0.y, x0.z, x0.w, x1.x, x1.y, x1.z, x1.w};
    union U { uint u[4]; bf16x8 v; } uh, ul;
    #pragma unroll
    for (int j = 0; j < 4; ++j) {
        uint p = pk2(f[2 * j], f[2 * j + 1]);
        uh.u[j] = p;
        float h0 = __uint_as_float(p << 16);
        float h1 = __uint_as_float(p & 0xFFFF0000u);
        ul.u[j] = pk2(f[2 * j] - h0, f[2 * j + 1] - h1);
    }
    h = uh.v;
    l = ul.v;
}

// ---------------- fold + pack kernels ----------------
// Fold BN scale into W and pack into MFMA B-fragment order, split bf16 hi/lo.
// Fragment layout for 16x16x32: lane ln holds col = c*16+(ln&15), k = st*32+(ln>>4)*8+j.
// Element (k,col) of folded W -> plane offset ((c*(K/32)+st)*64+ln)*8+j.
__global__ void pack_w(const float* __restrict__ W, const float* __restrict__ g,
                       const float* __restrict__ v, ushort* __restrict__ hi,
                       ushort* __restrict__ lo, int K) {
    int idx = blockIdx.x * 256 + threadIdx.x;
    if (idx >= K * DD) return;
    int k = idx >> 7, col = idx & 127;
    float s = g[k] * rsqrtf(v[k] + BN_EPS);
    float f = s * W[idx];
    int S = K >> 5;
    int st = k >> 5, gq = (k >> 3) & 3, j = k & 7;
    int c = col >> 4, ln = (gq << 4) | (col & 15);
    int o = ((c * S + st) * 64 + ln) * 8 + j;
    ushort hb = f2bf_rn(f);
    hi[o] = hb;
    lo[o] = f2bf_rn(f - bf2f(hb));
}

// b'[j] = bias[j] + sum_k (b[k]-m[k]*s[k]) * W[k][j]   (kept f32, added post-MFMA)
__global__ void fold_b(const float* __restrict__ W, const float* __restrict__ g,
                       const float* __restrict__ bb, const float* __restrict__ m,
                       const float* __restrict__ v, const float* __restrict__ bias,
                       float* __restrict__ bf, int K) {
    int j = threadIdx.x;  // 128 threads
    float acc = 0.f;
    for (int k = 0; k < K; ++k) {
        float s = g[k] * rsqrtf(v[k] + BN_EPS);
        float t = bb[k] - m[k] * s;
        acc = fmaf(t, W[k * DD + j], acc);
    }
    bf[j] = bias[j] + acc;
}

// Y LDS row stride in ushorts: 136 (272 B) -> read banks 4*lr mod 32 (2-way, free)
#define YLD 136

// ---------------- edge kernel: gather -> MFMA FFN(2 layers) -> *ew -> pk-bf16 scatter ----
// 128 edges/block, 8 waves x 16 rows. Y handoff bf16 in LDS (34816 B). Per-wave Y slices
// -> no __syncthreads. Scatter: adjacent lanes (same rows, adjacent cols) exchange via
// shfl_xor(1), pack 2 cols into one global_atomic_pk_add_bf16 -> 16 atomics/thread.
__global__ __launch_bounds__(512, 4) void edge_kernel(
    const float* __restrict__ reps, const int* __restrict__ edges,
    const float* __restrict__ ew,
    const ushort* __restrict__ W1h, const ushort* __restrict__ W1l, const float* __restrict__ B1,
    const ushort* __restrict__ W2h, const ushort* __restrict__ W2l, const float* __restrict__ B2,
    ushort* __restrict__ aggb)
{
    __shared__ ushort Yh[128 * YLD];
    const int t = threadIdx.x;
    const int w = t >> 6, l = t & 63, lg = l >> 4, lr = l & 15;
    const int e0 = blockIdx.x * 128;
    const int erow = e0 + w * 16;

    float b1v[8], b2v[8];
    #pragma unroll
    for (int c = 0; c < 8; ++c) { b1v[c] = B1[c * 16 + lr]; b2v[c] = B2[c * 16 + lr]; }

    const int nb = edges[EE + erow + lr];  // neighbour (edges row 1)
    const float* src = reps + (size_t)nb * DD;

    // prefetch edge weight + dest node for the scatter (hide latency under MFMA)
    float ewv[4];
    int nd[4];
    #pragma unroll
    for (int i = 0; i < 4; ++i) {
        int e = erow + lg * 4 + i;
        ewv[i] = ew[e];
        nd[i] = edges[e];  // dest node (edges row 0)
    }

    f32x4 acc[8];
    #pragma unroll
    for (int c = 0; c < 8; ++c) acc[c] = (f32x4)(0.f);

    // ---- layer 1 (A hi+lo, 3 MFMAs) ----
    #pragma unroll
    for (int s = 0; s < 4; ++s) {
        float4 x0 = *reinterpret_cast<const float4*>(src + s * 32 + lg * 8);
        float4 x1 = *reinterpret_cast<const float4*>(src + s * 32 + lg * 8 + 4);
        bf16x8 ah, al;
        cvt_hilo(x0, x1, ah, al);
        #pragma unroll
        for (int c = 0; c < 8; ++c) {
            bf16x8 bh = *reinterpret_cast<const bf16x8*>(W1h + (size_t)((c * 4 + s) * 64 + l) * 8);
            bf16x8 bl = *reinterpret_cast<const bf16x8*>(W1l + (size_t)((c * 4 + s) * 64 + l) * 8);
            acc[c] = MFMA16(al, bh, acc[c]);
            acc[c] = MFMA16(ah, bl, acc[c]);
            acc[c] = MFMA16(ah, bh, acc[c]);
        }
    }
    // bias + GELU -> Yh bf16 (D layout: row=w*16+lg*4+i, col=c*16+lr); own-wave rows only
    #pragma unroll
    for (int c = 0; c < 8; ++c) {
        #pragma unroll
        for (int i = 0; i < 4; ++i) {
            float yv = gelu_f(acc[c][i] + b1v[c]);
            Yh[(w * 16 + lg * 4 + i) * YLD + c * 16 + lr] = f2bf_rn(yv);
        }
    }

    // ---- layer 2 (A = bf16 Y read straight from LDS; B hi/lo -> 2 MFMAs) ----
    #pragma unroll
    for (int c = 0; c < 8; ++c) acc[c] = (f32x4)(0.f);
    const ushort* yr = Yh + (w * 16 + lr) * YLD;
    #pragma unroll
    for (int s = 0; s < 4; ++s) {
        bf16x8 ah = *reinterpret_cast<const bf16x8*>(yr + s * 32 + lg * 8);
        #pragma unroll
        for (int c = 0; c < 8; ++c) {
            bf16x8 bh = *reinterpret_cast<const bf16x8*>(W2h + (size_t)((c * 4 + s) * 64 + l) * 8);
            bf16x8 bl = *reinterpret_cast<const bf16x8*>(W2l + (size_t)((c * 4 + s) * 64 + l) * 8);
            acc[c] = MFMA16(ah, bl, acc[c]);
            acc[c] = MFMA16(ah, bh, acc[c]);
        }
    }

    // ---- bias + GELU + *ew + packed-bf16 atomic scatter ----
    // lanes lr, lr^1 hold adjacent cols of the same 4 rows; exchange and pack.
    #pragma unroll
    for (int c = 0; c < 8; ++c) {
        #pragma unroll
        for (int i = 0; i < 4; ++i) {
            float vv = gelu_f(acc[c][i] + b2v[c]) * ewv[i];
            float pv = __shfl_xor(vv, 1);                        // partner col, same row
            uint pk = (lr & 1) ? pk2(pv, vv) : pk2(vv, pv);      // low16 = even col
            bool mine = ((lr & 1) == 0) ? (i < 2) : (i >= 2);    // balance: 16 atomics/thr
            if (mine) {
                ushort* dst = aggb + (size_t)nd[i] * DD + c * 16 + (lr & ~1);
                atomic_pk_add_bf16(dst, pk);
            }
        }
    }
}

// ---------------- node kernel: concat -> MFMA FFN(2 layers) -> L2 normalize ----
// 64 nodes/block, 4 waves x 16 rows. agg is bf16 -> layer-1 agg half reads A directly
// (no cvt, 2 MFMAs). Y bf16 in LDS. No __syncthreads.
__global__ __launch_bounds__(256, 4) void node_kernel(
    const float* __restrict__ reps, const ushort* __restrict__ aggb,
    const ushort* __restrict__ U1h, const ushort* __restrict__ U1l, const float* __restrict__ C1,
    const ushort* __restrict__ U2h, const ushort* __restrict__ U2l, const float* __restrict__ C2,
    float* __restrict__ out)
{
    __shared__ ushort Yh[64 * YLD];
    const int t = threadIdx.x;
    const int w = t >> 6, l = t & 63, lg = l >> 4, lr = l & 15;
    const int n0 = blockIdx.x * 64;
    int n = n0 + w * 16 + lr;
    int nc = n < NN ? n : NN - 1;  // clamp tail loads; stores guarded

    float c1v[8], c2v[8];
    #pragma unroll
    for (int c = 0; c < 8; ++c) { c1v[c] = C1[c * 16 + lr]; c2v[c] = C2[c * 16 + lr]; }

    f32x4 acc[8];
    #pragma unroll
    for (int c = 0; c < 8; ++c) acc[c] = (f32x4)(0.f);

    // ---- update layer 1, reps half (k=0..127): f32 A hi+lo, 3 MFMAs ----
    #pragma unroll
    for (int s = 0; s < 4; ++s) {
        const float* sp = reps + (size_t)nc * DD + s * 32 + lg * 8;
        float4 x0 = *reinterpret_cast<const float4*>(sp);
        float4 x1 = *reinterpret_cast<const float4*>(sp + 4);
        bf16x8 ah, al;
        cvt_hilo(x0, x1, ah, al);
        #pragma unroll
        for (int c = 0; c < 8; ++c) {
            bf16x8 bh = *reinterpret_cast<const bf16x8*>(U1h + (size_t)((c * 8 + s) * 64 + l) * 8);
            bf16x8 bl = *reinterpret_cast<const bf16x8*>(U1l + (size_t)((c * 8 + s) * 64 + l) * 8);
            acc[c] = MFMA16(al, bh, acc[c]);
            acc[c] = MFMA16(ah, bl, acc[c]);
            acc[c] = MFMA16(ah, bh, acc[c]);
        }
    }
    // ---- update layer 1, agg half (k=128..255): bf16 A direct, 2 MFMAs ----
    #pragma unroll
    for (int s = 4; s < 8; ++s) {
        bf16x8 ah = *reinterpret_cast<const bf16x8*>(aggb + (size_t)nc * DD + (s - 4) * 32 + lg * 8);
        #pragma unroll
        for (int c = 0; c < 8; ++c) {
            bf16x8 bh = *reinterpret_cast<const bf16x8*>(U1h + (size_t)((c * 8 + s) * 64 + l) * 8);
            bf16x8 bl = *reinterpret_cast<const bf16x8*>(U1l + (size_t)((c * 8 + s) * 64 + l) * 8);
            acc[c] = MFMA16(ah, bl, acc[c]);
            acc[c] = MFMA16(ah, bh, acc[c]);
        }
    }
    #pragma unroll
    for (int c = 0; c < 8; ++c) {
        #pragma unroll
        for (int i = 0; i < 4; ++i) {
            float yv = gelu_f(acc[c][i] + c1v[c]);
            Yh[(w * 16 + lg * 4 + i) * YLD + c * 16 + lr] = f2bf_rn(yv);
        }
    }

    // ---- update layer 2: K=128, A = bf16 Y from LDS, 2 MFMAs ----
    #pragma unroll
    for (int c = 0; c < 8; ++c) acc[c] = (f32x4)(0.f);
    const ushort* yr = Yh + (w * 16 + lr) * YLD;
    #pragma unroll
    for (int s = 0; s < 4; ++s) {
        bf16x8 ah = *reinterpret_cast<const bf16x8*>(yr + s * 32 + lg * 8);
        #pragma unroll
        for (int c = 0; c < 8; ++c) {
            bf16x8 bh = *reinterpret_cast<const bf16x8*>(U2h + (size_t)((c * 4 + s) * 64 + l) * 8);
            bf16x8 bl = *reinterpret_cast<const bf16x8*>(U2l + (size_t)((c * 4 + s) * 64 + l) * 8);
            acc[c] = MFMA16(ah, bl, acc[c]);
            acc[c] = MFMA16(ah, bh, acc[c]);
        }
    }

    // ---- bias + GELU + L2 normalize + store ----
    float ssq[4] = {0.f, 0.f, 0.f, 0.f};
    #pragma unroll
    for (int c = 0; c < 8; ++c) {
        #pragma unroll
        for (int i = 0; i < 4; ++i) {
            float vv = gelu_f(acc[c][i] + c2v[c]);
            acc[c][i] = vv;
            ssq[i] = fmaf(vv, vv, ssq[i]);
        }
    }
    // row r = w*16 + lg*4 + i lives in the 16 lanes of group lg, reg i
    #pragma unroll
    for (int i = 0; i < 4; ++i) {
        #pragma unroll
        for (int msk = 1; msk < 16; msk <<= 1) ssq[i] += __shfl_xor(ssq[i], msk);
        ssq[i] = rsqrtf(fmaxf(ssq[i], 1e-12f));
    }
    const int nrow = n0 + w * 16 + lg * 4;
    #pragma unroll
    for (int i = 0; i < 4; ++i) {
        if (nrow + i < NN) {
            #pragma unroll
            for (int c = 0; c < 8; ++c)
                out[(size_t)(nrow + i) * DD + c * 16 + lr] = acc[c][i] * ssq[i];
        }
    }
}

// ---------------- launch ----------------
extern "C" void kernel_launch(void* const* d_in, const int* in_sizes, int n_in,
                              void* d_out, int out_size, void* d_ws, size_t ws_size,
                              hipStream_t stream)
{
    const float* reps = (const float*)d_in[0];
    const int*   edges = (const int*)d_in[1];
    const float* ew   = (const float*)d_in[2];
    const float* bn1g = (const float*)d_in[3];
    const float* bn1b = (const float*)d_in[4];
    const float* bn1m = (const float*)d_in[5];
    const float* bn1v = (const float*)d_in[6];
    const float* w1   = (const float*)d_in[7];
    const float* b1   = (const float*)d_in[8];
    const float* bn2g = (const float*)d_in[9];
    const float* bn2b = (const float*)d_in[10];
    const float* bn2m = (const float*)d_in[11];
    const float* bn2v = (const float*)d_in[12];
    const float* w2   = (const float*)d_in[13];
    const float* b2   = (const float*)d_in[14];
    const float* ubn1g = (const float*)d_in[15];
    const float* ubn1b = (const float*)d_in[16];
    const float* ubn1m = (const float*)d_in[17];
    const float* ubn1v = (const float*)d_in[18];
    const float* u1    = (const float*)d_in[19];
    const float* ub1   = (const float*)d_in[20];
    const float* ubn2g = (const float*)d_in[21];
    const float* ubn2b = (const float*)d_in[22];
    const float* ubn2m = (const float*)d_in[23];
    const float* ubn2v = (const float*)d_in[24];
    const float* u2    = (const float*)d_in[25];
    const float* ub2   = (const float*)d_in[26];

    // workspace layout
    ushort* aggb = (ushort*)d_ws;           // 6,400,000 bf16 = 12.8 MB
    float* fs   = (float*)(aggb + 6400000); // 4-byte aligned
    float* B1f = fs;                        // 128
    float* B2f = B1f + 128;
    float* C1f = B2f + 128;
    float* C2f = C1f + 128;
    ushort* up  = (ushort*)(C2f + 128);     // 16B-aligned region for packed weights
    ushort* W1h = up;                       // 16384 each
    ushort* W1l = W1h + 16384;
    ushort* W2h = W1l + 16384;
    ushort* W2l = W2h + 16384;
    ushort* U1h = W2l + 16384;              // 32768 each
    ushort* U1l = U1h + 32768;
    ushort* U2h = U1l + 32768;              // 16384 each
    ushort* U2l = U2h + 16384;
    if (ws_size < (size_t)6400000 * 2 + 512 * 4 + (size_t)163840 * 2) return;

    pack_w<<<64,  256, 0, stream>>>(w1, bn1g, bn1v, W1h, W1l, 128);
    fold_b<<<1,   128, 0, stream>>>(w1, bn1g, bn1b, bn1m, bn1v, b1, B1f, 128);
    pack_w<<<64,  256, 0, stream>>>(w2, bn2g, bn2v, W2h, W2l, 128);
    fold_b<<<1,   128, 0, stream>>>(w2, bn2g, bn2b, bn2m, bn2v, b2, B2f, 128);
    pack_w<<<128, 256, 0, stream>>>(u1, ubn1g, ubn1v, U1h, U1l, 256);
    fold_b<<<1,   128, 0, stream>>>(u1, ubn1g, ubn1b, ubn1m, ubn1v, ub1, C1f, 256);
    pack_w<<<64,  256, 0, stream>>>(u2, ubn2g, ubn2v, U2h, U2l, 128);
    fold_b<<<1,   128, 0, stream>>>(u2, ubn2g, ubn2b, ubn2m, ubn2v, ub2, C2f, 128);

    (void)hipMemsetAsync(aggb, 0, (size_t)NN * DD * sizeof(ushort), stream);

    edge_kernel<<<EE / 128, 512, 0, stream>>>(reps, edges, ew, W1h, W1l, B1f,
                                              W2h, W2l, B2f, aggb);
    node_kernel<<<(NN + 63) / 64, 256, 0, stream>>>(reps, aggb, U1h, U1l, C1f,
                                                    U2h, U2l, C2f, (float*)d_out);
}

// Round 9
// 443.188 us; speedup vs baseline: 1.4648x; 1.4648x over previous
//
#include <hip/hip_runtime.h>
#include <hip/hip_bf16.h>
#include <math.h>

#define NN 50000
#define DD 128
#define EE 800000

static constexpr float BN_EPS = 1e-3f;

typedef __attribute__((ext_vector_type(8))) short bf16x8;
typedef __attribute__((ext_vector_type(4))) float f32x4;

#define MFMA16(a, b, c) __builtin_amdgcn_mfma_f32_16x16x32_bf16((a), (b), (c), 0, 0, 0)

// fast exact-grade GELU: Abramowitz-Stegun 7.1.26 erf (abs err 1.5e-7)
__device__ __forceinline__ float gelu_f(float x) {
    float ax = fabsf(x) * 0.7071067811865475f;
    float t = __builtin_amdgcn_rcpf(fmaf(0.3275911f, ax, 1.0f));
    float p = t * fmaf(t, fmaf(t, fmaf(t, fmaf(t, 1.061405429f, -1.453152027f),
                                       1.421413741f), -0.284496736f), 0.254829592f);
    float e = __expf(-ax * ax);
    float er = fmaf(-p, e, 1.0f);        // erf(|x|/sqrt2) for ax>=0
    float s = copysignf(er, x);
    return 0.5f * x * (1.0f + s);
}

__device__ __forceinline__ ushort f2bf_rn(float f) {
    uint u = __float_as_uint(f);
    return (ushort)((u + 0x7FFFu + ((u >> 16) & 1u)) >> 16);
}
__device__ __forceinline__ float bf2f(ushort h) {
    return __uint_as_float(((uint)h) << 16);
}

// packed pair f32->bf16 RNE (compiler emits v_cvt_pk_bf16_f32); low16=a, high16=b
__device__ __forceinline__ uint pk2(float a, float b) {
    __hip_bfloat162 t = __float22bfloat162_rn(make_float2(a, b));
    uint r;
    __builtin_memcpy(&r, &t, 4);
    return r;
}

// split f32x8 -> bf16 hi + bf16 lo fragments (f ~= hi + lo, |resid| ~ 2^-17|f|)
__device__ __forceinline__ void cvt_hilo(float4 x0, float4 x1, bf16x8& h, bf16x8& l) {
    float f[8] = {x0.x, x0.y, x0.z, x0.w, x1.x, x1.y, x1.z, x1.w};
    union U { uint u[4]; bf16x8 v; } uh, ul;
    #pragma unroll
    for (int j = 0; j < 4; ++j) {
        uint p = pk2(f[2 * j], f[2 * j + 1]);
        uh.u[j] = p;
        float h0 = __uint_as_float(p << 16);
        float h1 = __uint_as_float(p & 0xFFFF0000u);
        ul.u[j] = pk2(f[2 * j] - h0, f[2 * j + 1] - h1);
    }
    h = uh.v;
    l = ul.v;
}

// ---------------- fold + pack kernels ----------------
__global__ void pack_w(const float* __restrict__ W, const float* __restrict__ g,
                       const float* __restrict__ v, ushort* __restrict__ hi,
                       ushort* __restrict__ lo, int K) {
    int idx = blockIdx.x * 256 + threadIdx.x;
    if (idx >= K * DD) return;
    int k = idx >> 7, col = idx & 127;
    float s = g[k] * rsqrtf(v[k] + BN_EPS);
    float f = s * W[idx];
    int S = K >> 5;
    int st = k >> 5, gq = (k >> 3) & 3, j = k & 7;
    int c = col >> 4, ln = (gq << 4) | (col & 15);
    int o = ((c * S + st) * 64 + ln) * 8 + j;
    ushort hb = f2bf_rn(f);
    hi[o] = hb;
    lo[o] = f2bf_rn(f - bf2f(hb));
}

__global__ void fold_b(const float* __restrict__ W, const float* __restrict__ g,
                       const float* __restrict__ bb, const float* __restrict__ m,
                       const float* __restrict__ v, const float* __restrict__ bias,
                       float* __restrict__ bf, int K) {
    int j = threadIdx.x;  // 128 threads
    float acc = 0.f;
    for (int k = 0; k < K; ++k) {
        float s = g[k] * rsqrtf(v[k] + BN_EPS);
        float t = bb[k] - m[k] * s;
        acc = fmaf(t, W[k * DD + j], acc);
    }
    bf[j] = bias[j] + acc;
}

#define YLD 136

// ---------------- prep kernel: per-NODE FFN_pre -> msgN bf16 [NN][128] ----------------
// 128 nodes/block, 8 waves x 16 rows. Coalesced row reads (consecutive nodes).
__global__ __launch_bounds__(512, 4) void prep_kernel(
    const float* __restrict__ reps,
    const ushort* __restrict__ W1h, const ushort* __restrict__ W1l, const float* __restrict__ B1,
    const ushort* __restrict__ W2h, const ushort* __restrict__ W2l, const float* __restrict__ B2,
    ushort* __restrict__ msgN)
{
    __shared__ ushort Yh[128 * YLD];
    const int t = threadIdx.x;
    const int w = t >> 6, l = t & 63, lg = l >> 4, lr = l & 15;
    const int n0 = blockIdx.x * 128;
    int n = n0 + w * 16 + lr;
    int nc = n < NN ? n : NN - 1;
    const float* src = reps + (size_t)nc * DD;

    float b1v[8], b2v[8];
    #pragma unroll
    for (int c = 0; c < 8; ++c) { b1v[c] = B1[c * 16 + lr]; b2v[c] = B2[c * 16 + lr]; }

    f32x4 acc[8];
    #pragma unroll
    for (int c = 0; c < 8; ++c) acc[c] = (f32x4)(0.f);

    // ---- layer 1 (A hi+lo, 3 MFMAs) ----
    #pragma unroll
    for (int s = 0; s < 4; ++s) {
        float4 x0 = *reinterpret_cast<const float4*>(src + s * 32 + lg * 8);
        float4 x1 = *reinterpret_cast<const float4*>(src + s * 32 + lg * 8 + 4);
        bf16x8 ah, al;
        cvt_hilo(x0, x1, ah, al);
        #pragma unroll
        for (int c = 0; c < 8; ++c) {
            bf16x8 bh = *reinterpret_cast<const bf16x8*>(W1h + (size_t)((c * 4 + s) * 64 + l) * 8);
            bf16x8 bl = *reinterpret_cast<const bf16x8*>(W1l + (size_t)((c * 4 + s) * 64 + l) * 8);
            acc[c] = MFMA16(al, bh, acc[c]);
            acc[c] = MFMA16(ah, bl, acc[c]);
            acc[c] = MFMA16(ah, bh, acc[c]);
        }
    }
    #pragma unroll
    for (int c = 0; c < 8; ++c) {
        #pragma unroll
        for (int i = 0; i < 4; ++i) {
            float yv = gelu_f(acc[c][i] + b1v[c]);
            Yh[(w * 16 + lg * 4 + i) * YLD + c * 16 + lr] = f2bf_rn(yv);
        }
    }

    // ---- layer 2 (A = bf16 Y from LDS; B hi/lo -> 2 MFMAs) ----
    #pragma unroll
    for (int c = 0; c < 8; ++c) acc[c] = (f32x4)(0.f);
    const ushort* yr = Yh + (w * 16 + lr) * YLD;
    #pragma unroll
    for (int s = 0; s < 4; ++s) {
        bf16x8 ah = *reinterpret_cast<const bf16x8*>(yr + s * 32 + lg * 8);
        #pragma unroll
        for (int c = 0; c < 8; ++c) {
            bf16x8 bh = *reinterpret_cast<const bf16x8*>(W2h + (size_t)((c * 4 + s) * 64 + l) * 8);
            bf16x8 bl = *reinterpret_cast<const bf16x8*>(W2l + (size_t)((c * 4 + s) * 64 + l) * 8);
            acc[c] = MFMA16(ah, bl, acc[c]);
            acc[c] = MFMA16(ah, bh, acc[c]);
        }
    }

    // ---- bias + GELU -> msgN bf16 (D layout: row=w*16+lg*4+i, col=c*16+lr) ----
    const int nrow = n0 + w * 16 + lg * 4;
    #pragma unroll
    for (int i = 0; i < 4; ++i) {
        if (nrow + i < NN) {
            #pragma unroll
            for (int c = 0; c < 8; ++c)
                msgN[(size_t)(nrow + i) * DD + c * 16 + lr] = f2bf_rn(gelu_f(acc[c][i] + b2v[c]));
        }
    }
}

// ---------------- CSR build: histogram -> scan -> fill ----------------
__global__ void hist_kernel(const int* __restrict__ edges, int* __restrict__ cnt) {
    int e = blockIdx.x * 256 + threadIdx.x;
    if (e < EE) atomicAdd(&cnt[edges[e]], 1);
}

// single-block exclusive scan over 50000 counts (1024 thr x 49 elems + Hillis-Steele)
__global__ __launch_bounds__(1024) void scan_kernel(const int* __restrict__ cnt,
                                                    int* __restrict__ starts) {
    __shared__ int S[1024];
    const int t = threadIdx.x;
    const int b = t * 49;
    int s = 0;
    for (int j = 0; j < 49; ++j) { int i = b + j; if (i < NN) s += cnt[i]; }
    S[t] = s;
    __syncthreads();
    for (int off = 1; off < 1024; off <<= 1) {
        int v = (t >= off) ? S[t - off] : 0;
        __syncthreads();
        S[t] += v;
        __syncthreads();
    }
    int run = (t == 0) ? 0 : S[t - 1];
    for (int j = 0; j < 49; ++j) {
        int i = b + j;
        if (i < NN) { starts[i] = run; run += cnt[i]; }
    }
    if (b <= NN && NN < b + 49) starts[NN] = run;
}

__global__ void fill_kernel(const int* __restrict__ edges, const float* __restrict__ ew,
                            const int* __restrict__ starts, int* __restrict__ cursor,
                            uint2* __restrict__ payload) {
    int e = blockIdx.x * 256 + threadIdx.x;
    if (e >= EE) return;
    int dst = edges[e];
    int slot = atomicAdd(&cursor[dst], 1);
    payload[starts[dst] + slot] = make_uint2((uint)edges[EE + e], __float_as_uint(ew[e]));
}

// ---------------- agg kernel: per-dst weighted sum of msgN rows (NO atomics) ----------
// 16 lanes per node, 16 nodes/block (256 thr), 3125 blocks. f32 accumulate, bf16 out.
__global__ __launch_bounds__(256, 8) void agg_kernel(
    const uint2* __restrict__ payload, const int* __restrict__ starts,
    const ushort* __restrict__ msgN, ushort* __restrict__ aggb)
{
    const int t = threadIdx.x;
    const int node = blockIdx.x * 16 + (t >> 4);
    const int la = t & 15;
    const int beg = starts[node], end = starts[node + 1];
    const ushort* base = msgN + la * 8;

    float acc[8] = {0.f, 0.f, 0.f, 0.f, 0.f, 0.f, 0.f, 0.f};
    int k = beg;
    for (; k + 1 < end; k += 2) {           // 2-way unroll for load ILP
        uint2 p0 = payload[k], p1 = payload[k + 1];
        bf16x8 m0 = *reinterpret_cast<const bf16x8*>(base + (size_t)p0.x * DD);
        bf16x8 m1 = *reinterpret_cast<const bf16x8*>(base + (size_t)p1.x * DD);
        float w0 = __uint_as_float(p0.y), w1 = __uint_as_float(p1.y);
        #pragma unroll
        for (int j = 0; j < 8; ++j) {
            acc[j] = fmaf(w0, bf2f((ushort)m0[j]), acc[j]);
            acc[j] = fmaf(w1, bf2f((ushort)m1[j]), acc[j]);
        }
    }
    if (k < end) {
        uint2 p0 = payload[k];
        bf16x8 m0 = *reinterpret_cast<const bf16x8*>(base + (size_t)p0.x * DD);
        float w0 = __uint_as_float(p0.y);
        #pragma unroll
        for (int j = 0; j < 8; ++j) acc[j] = fmaf(w0, bf2f((ushort)m0[j]), acc[j]);
    }
    uint4 o;
    o.x = pk2(acc[0], acc[1]);
    o.y = pk2(acc[2], acc[3]);
    o.z = pk2(acc[4], acc[5]);
    o.w = pk2(acc[6], acc[7]);
    *reinterpret_cast<uint4*>(aggb + (size_t)node * DD + la * 8) = o;
}

// ---------------- node kernel: concat -> MFMA FFN(2 layers) -> L2 normalize ----------
__global__ __launch_bounds__(256, 4) void node_kernel(
    const float* __restrict__ reps, const ushort* __restrict__ aggb,
    const ushort* __restrict__ U1h, const ushort* __restrict__ U1l, const float* __restrict__ C1,
    const ushort* __restrict__ U2h, const ushort* __restrict__ U2l, const float* __restrict__ C2,
    float* __restrict__ out)
{
    __shared__ ushort Yh[64 * YLD];
    const int t = threadIdx.x;
    const int w = t >> 6, l = t & 63, lg = l >> 4, lr = l & 15;
    const int n0 = blockIdx.x * 64;
    int n = n0 + w * 16 + lr;
    int nc = n < NN ? n : NN - 1;

    float c1v[8], c2v[8];
    #pragma unroll
    for (int c = 0; c < 8; ++c) { c1v[c] = C1[c * 16 + lr]; c2v[c] = C2[c * 16 + lr]; }

    f32x4 acc[8];
    #pragma unroll
    for (int c = 0; c < 8; ++c) acc[c] = (f32x4)(0.f);

    // ---- update layer 1, reps half (k=0..127): f32 A hi+lo, 3 MFMAs ----
    #pragma unroll
    for (int s = 0; s < 4; ++s) {
        const float* sp = reps + (size_t)nc * DD + s * 32 + lg * 8;
        float4 x0 = *reinterpret_cast<const float4*>(sp);
        float4 x1 = *reinterpret_cast<const float4*>(sp + 4);
        bf16x8 ah, al;
        cvt_hilo(x0, x1, ah, al);
        #pragma unroll
        for (int c = 0; c < 8; ++c) {
            bf16x8 bh = *reinterpret_cast<const bf16x8*>(U1h + (size_t)((c * 8 + s) * 64 + l) * 8);
            bf16x8 bl = *reinterpret_cast<const bf16x8*>(U1l + (size_t)((c * 8 + s) * 64 + l) * 8);
            acc[c] = MFMA16(al, bh, acc[c]);
            acc[c] = MFMA16(ah, bl, acc[c]);
            acc[c] = MFMA16(ah, bh, acc[c]);
        }
    }
    // ---- update layer 1, agg half (k=128..255): bf16 A direct, 2 MFMAs ----
    #pragma unroll
    for (int s = 4; s < 8; ++s) {
        bf16x8 ah = *reinterpret_cast<const bf16x8*>(aggb + (size_t)nc * DD + (s - 4) * 32 + lg * 8);
        #pragma unroll
        for (int c = 0; c < 8; ++c) {
            bf16x8 bh = *reinterpret_cast<const bf16x8*>(U1h + (size_t)((c * 8 + s) * 64 + l) * 8);
            bf16x8 bl = *reinterpret_cast<const bf16x8*>(U1l + (size_t)((c * 8 + s) * 64 + l) * 8);
            acc[c] = MFMA16(ah, bl, acc[c]);
            acc[c] = MFMA16(ah, bh, acc[c]);
        }
    }
    #pragma unroll
    for (int c = 0; c < 8; ++c) {
        #pragma unroll
        for (int i = 0; i < 4; ++i) {
            float yv = gelu_f(acc[c][i] + c1v[c]);
            Yh[(w * 16 + lg * 4 + i) * YLD + c * 16 + lr] = f2bf_rn(yv);
        }
    }

    // ---- update layer 2: K=128, A = bf16 Y from LDS, 2 MFMAs ----
    #pragma unroll
    for (int c = 0; c < 8; ++c) acc[c] = (f32x4)(0.f);
    const ushort* yr = Yh + (w * 16 + lr) * YLD;
    #pragma unroll
    for (int s = 0; s < 4; ++s) {
        bf16x8 ah = *reinterpret_cast<const bf16x8*>(yr + s * 32 + lg * 8);
        #pragma unroll
        for (int c = 0; c < 8; ++c) {
            bf16x8 bh = *reinterpret_cast<const bf16x8*>(U2h + (size_t)((c * 4 + s) * 64 + l) * 8);
            bf16x8 bl = *reinterpret_cast<const bf16x8*>(U2l + (size_t)((c * 4 + s) * 64 + l) * 8);
            acc[c] = MFMA16(ah, bl, acc[c]);
            acc[c] = MFMA16(ah, bh, acc[c]);
        }
    }

    // ---- bias + GELU + L2 normalize + store ----
    float ssq[4] = {0.f, 0.f, 0.f, 0.f};
    #pragma unroll
    for (int c = 0; c < 8; ++c) {
        #pragma unroll
        for (int i = 0; i < 4; ++i) {
            float vv = gelu_f(acc[c][i] + c2v[c]);
            acc[c][i] = vv;
            ssq[i] = fmaf(vv, vv, ssq[i]);
        }
    }
    #pragma unroll
    for (int i = 0; i < 4; ++i) {
        #pragma unroll
        for (int msk = 1; msk < 16; msk <<= 1) ssq[i] += __shfl_xor(ssq[i], msk);
        ssq[i] = rsqrtf(fmaxf(ssq[i], 1e-12f));
    }
    const int nrow = n0 + w * 16 + lg * 4;
    #pragma unroll
    for (int i = 0; i < 4; ++i) {
        if (nrow + i < NN) {
            #pragma unroll
            for (int c = 0; c < 8; ++c)
                out[(size_t)(nrow + i) * DD + c * 16 + lr] = acc[c][i] * ssq[i];
        }
    }
}

// ---------------- launch ----------------
extern "C" void kernel_launch(void* const* d_in, const int* in_sizes, int n_in,
                              void* d_out, int out_size, void* d_ws, size_t ws_size,
                              hipStream_t stream)
{
    const float* reps = (const float*)d_in[0];
    const int*   edges = (const int*)d_in[1];
    const float* ew   = (const float*)d_in[2];
    const float* bn1g = (const float*)d_in[3];
    const float* bn1b = (const float*)d_in[4];
    const float* bn1m = (const float*)d_in[5];
    const float* bn1v = (const float*)d_in[6];
    const float* w1   = (const float*)d_in[7];
    const float* b1   = (const float*)d_in[8];
    const float* bn2g = (const float*)d_in[9];
    const float* bn2b = (const float*)d_in[10];
    const float* bn2m = (const float*)d_in[11];
    const float* bn2v = (const float*)d_in[12];
    const float* w2   = (const float*)d_in[13];
    const float* b2   = (const float*)d_in[14];
    const float* ubn1g = (const float*)d_in[15];
    const float* ubn1b = (const float*)d_in[16];
    const float* ubn1m = (const float*)d_in[17];
    const float* ubn1v = (const float*)d_in[18];
    const float* u1    = (const float*)d_in[19];
    const float* ub1   = (const float*)d_in[20];
    const float* ubn2g = (const float*)d_in[21];
    const float* ubn2b = (const float*)d_in[22];
    const float* ubn2m = (const float*)d_in[23];
    const float* ubn2v = (const float*)d_in[24];
    const float* u2    = (const float*)d_in[25];
    const float* ub2   = (const float*)d_in[26];

    // workspace layout (bytes)
    char* wsb = (char*)d_ws;
    uint2*  payload = (uint2*)wsb;                       // 6,400,000 B
    ushort* aggb    = (ushort*)(wsb + 6400000);          // 12,800,000 B
    int*    cnt     = (int*)(wsb + 19200000);            // 200,000 B
    int*    cursor  = (int*)(wsb + 19400000);            // 200,000 B
    int*    starts  = (int*)(wsb + 19600000);            // 200,004 B
    float*  B1f     = (float*)(wsb + 19800016);          // 128 f32 each, 16B aligned
    float*  B2f     = B1f + 128;
    float*  C1f     = B2f + 128;
    float*  C2f     = C1f + 128;
    ushort* up      = (ushort*)(C2f + 128);
    ushort* W1h = up;                                    // 16384 each
    ushort* W1l = W1h + 16384;
    ushort* W2h = W1l + 16384;
    ushort* W2l = W2h + 16384;
    ushort* U1h = W2l + 16384;                           // 32768 each
    ushort* U1l = U1h + 32768;
    ushort* U2h = U1l + 32768;                           // 16384 each
    ushort* U2l = U2h + 16384;
    if (ws_size < 20200000) return;

    // msgN (bf16, 12.8 MB) lives in d_out: dead before node_kernel overwrites d_out.
    ushort* msgN = (ushort*)d_out;

    pack_w<<<64,  256, 0, stream>>>(w1, bn1g, bn1v, W1h, W1l, 128);
    fold_b<<<1,   128, 0, stream>>>(w1, bn1g, bn1b, bn1m, bn1v, b1, B1f, 128);
    pack_w<<<64,  256, 0, stream>>>(w2, bn2g, bn2v, W2h, W2l, 128);
    fold_b<<<1,   128, 0, stream>>>(w2, bn2g, bn2b, bn2m, bn2v, b2, B2f, 128);
    pack_w<<<128, 256, 0, stream>>>(u1, ubn1g, ubn1v, U1h, U1l, 256);
    fold_b<<<1,   128, 0, stream>>>(u1, ubn1g, ubn1b, ubn1m, ubn1v, ub1, C1f, 256);
    pack_w<<<64,  256, 0, stream>>>(u2, ubn2g, ubn2v, U2h, U2l, 128);
    fold_b<<<1,   128, 0, stream>>>(u2, ubn2g, ubn2b, ubn2m, ubn2v, ub2, C2f, 128);

    (void)hipMemsetAsync(cnt, 0, 400000, stream);  // cnt + cursor (adjacent)

    prep_kernel<<<(NN + 127) / 128, 512, 0, stream>>>(reps, W1h, W1l, B1f,
                                                      W2h, W2l, B2f, msgN);
    hist_kernel<<<(EE + 255) / 256, 256, 0, stream>>>(edges, cnt);
    scan_kernel<<<1, 1024, 0, stream>>>(cnt, starts);
    fill_kernel<<<(EE + 255) / 256, 256, 0, stream>>>(edges, ew, starts, cursor, payload);
    agg_kernel<<<NN / 16, 256, 0, stream>>>(payload, starts, msgN, aggb);
    node_kernel<<<(NN + 63) / 64, 256, 0, stream>>>(reps, aggb, U1h, U1l, C1f,
                                                    U2h, U2l, C2f, (float*)d_out);
}

// Round 10
// 358.277 us; speedup vs baseline: 1.8119x; 1.2370x over previous
//
#include <hip/hip_runtime.h>
#include <hip/hip_bf16.h>
#include <math.h>

#define NN 50000
#define DD 128
#define EE 800000

static constexpr float BN_EPS = 1e-3f;

typedef __attribute__((ext_vector_type(8))) short bf16x8;
typedef __attribute__((ext_vector_type(4))) float f32x4;

#define MFMA16(a, b, c) __builtin_amdgcn_mfma_f32_16x16x32_bf16((a), (b), (c), 0, 0, 0)

// fast exact-grade GELU: Abramowitz-Stegun 7.1.26 erf (abs err 1.5e-7)
__device__ __forceinline__ float gelu_f(float x) {
    float ax = fabsf(x) * 0.7071067811865475f;
    float t = __builtin_amdgcn_rcpf(fmaf(0.3275911f, ax, 1.0f));
    float p = t * fmaf(t, fmaf(t, fmaf(t, fmaf(t, 1.061405429f, -1.453152027f),
                                       1.421413741f), -0.284496736f), 0.254829592f);
    float e = __expf(-ax * ax);
    float er = fmaf(-p, e, 1.0f);        // erf(|x|/sqrt2) for ax>=0
    float s = copysignf(er, x);
    return 0.5f * x * (1.0f + s);
}

__device__ __forceinline__ ushort f2bf_rn(float f) {
    uint u = __float_as_uint(f);
    return (ushort)((u + 0x7FFFu + ((u >> 16) & 1u)) >> 16);
}
__device__ __forceinline__ float bf2f(ushort h) {
    return __uint_as_float(((uint)h) << 16);
}

// packed pair f32->bf16 RNE (compiler emits v_cvt_pk_bf16_f32); low16=a, high16=b
__device__ __forceinline__ uint pk2(float a, float b) {
    __hip_bfloat162 t = __float22bfloat162_rn(make_float2(a, b));
    uint r;
    __builtin_memcpy(&r, &t, 4);
    return r;
}

// split f32x8 -> bf16 hi + bf16 lo fragments (f ~= hi + lo, |resid| ~ 2^-17|f|)
__device__ __forceinline__ void cvt_hilo(float4 x0, float4 x1, bf16x8& h, bf16x8& l) {
    float f[8] = {x0.x, x0.y, x0.z, x0.w, x1.x, x1.y, x1.z, x1.w};
    union U { uint u[4]; bf16x8 v; } uh, ul;
    #pragma unroll
    for (int j = 0; j < 4; ++j) {
        uint p = pk2(f[2 * j], f[2 * j + 1]);
        uh.u[j] = p;
        float h0 = __uint_as_float(p << 16);
        float h1 = __uint_as_float(p & 0xFFFF0000u);
        ul.u[j] = pk2(f[2 * j] - h0, f[2 * j + 1] - h1);
    }
    h = uh.v;
    l = ul.v;
}

// ---------------- fold + pack kernels ----------------
__global__ void pack_w(const float* __restrict__ W, const float* __restrict__ g,
                       const float* __restrict__ v, ushort* __restrict__ hi,
                       ushort* __restrict__ lo, int K) {
    int idx = blockIdx.x * 256 + threadIdx.x;
    if (idx >= K * DD) return;
    int k = idx >> 7, col = idx & 127;
    float s = g[k] * rsqrtf(v[k] + BN_EPS);
    float f = s * W[idx];
    int S = K >> 5;
    int st = k >> 5, gq = (k >> 3) & 3, j = k & 7;
    int c = col >> 4, ln = (gq << 4) | (col & 15);
    int o = ((c * S + st) * 64 + ln) * 8 + j;
    ushort hb = f2bf_rn(f);
    hi[o] = hb;
    lo[o] = f2bf_rn(f - bf2f(hb));
}

__global__ void fold_b(const float* __restrict__ W, const float* __restrict__ g,
                       const float* __restrict__ bb, const float* __restrict__ m,
                       const float* __restrict__ v, const float* __restrict__ bias,
                       float* __restrict__ bf, int K) {
    int j = threadIdx.x;  // 128 threads
    float acc = 0.f;
    for (int k = 0; k < K; ++k) {
        float s = g[k] * rsqrtf(v[k] + BN_EPS);
        float t = bb[k] - m[k] * s;
        acc = fmaf(t, W[k * DD + j], acc);
    }
    bf[j] = bias[j] + acc;
}

#define YLD 136

// ---------------- prep kernel: per-NODE FFN_pre -> msgN bf16 [NN][128] ----------------
__global__ __launch_bounds__(512, 4) void prep_kernel(
    const float* __restrict__ reps,
    const ushort* __restrict__ W1h, const ushort* __restrict__ W1l, const float* __restrict__ B1,
    const ushort* __restrict__ W2h, const ushort* __restrict__ W2l, const float* __restrict__ B2,
    ushort* __restrict__ msgN)
{
    __shared__ ushort Yh[128 * YLD];
    const int t = threadIdx.x;
    const int w = t >> 6, l = t & 63, lg = l >> 4, lr = l & 15;
    const int n0 = blockIdx.x * 128;
    int n = n0 + w * 16 + lr;
    int nc = n < NN ? n : NN - 1;
    const float* src = reps + (size_t)nc * DD;

    float b1v[8], b2v[8];
    #pragma unroll
    for (int c = 0; c < 8; ++c) { b1v[c] = B1[c * 16 + lr]; b2v[c] = B2[c * 16 + lr]; }

    f32x4 acc[8];
    #pragma unroll
    for (int c = 0; c < 8; ++c) acc[c] = (f32x4)(0.f);

    // ---- layer 1 (A hi+lo, 3 MFMAs) ----
    #pragma unroll
    for (int s = 0; s < 4; ++s) {
        float4 x0 = *reinterpret_cast<const float4*>(src + s * 32 + lg * 8);
        float4 x1 = *reinterpret_cast<const float4*>(src + s * 32 + lg * 8 + 4);
        bf16x8 ah, al;
        cvt_hilo(x0, x1, ah, al);
        #pragma unroll
        for (int c = 0; c < 8; ++c) {
            bf16x8 bh = *reinterpret_cast<const bf16x8*>(W1h + (size_t)((c * 4 + s) * 64 + l) * 8);
            bf16x8 bl = *reinterpret_cast<const bf16x8*>(W1l + (size_t)((c * 4 + s) * 64 + l) * 8);
            acc[c] = MFMA16(al, bh, acc[c]);
            acc[c] = MFMA16(ah, bl, acc[c]);
            acc[c] = MFMA16(ah, bh, acc[c]);
        }
    }
    #pragma unroll
    for (int c = 0; c < 8; ++c) {
        #pragma unroll
        for (int i = 0; i < 4; ++i) {
            float yv = gelu_f(acc[c][i] + b1v[c]);
            Yh[(w * 16 + lg * 4 + i) * YLD + c * 16 + lr] = f2bf_rn(yv);
        }
    }

    // ---- layer 2 (A = bf16 Y from LDS; B hi/lo -> 2 MFMAs) ----
    #pragma unroll
    for (int c = 0; c < 8; ++c) acc[c] = (f32x4)(0.f);
    const ushort* yr = Yh + (w * 16 + lr) * YLD;
    #pragma unroll
    for (int s = 0; s < 4; ++s) {
        bf16x8 ah = *reinterpret_cast<const bf16x8*>(yr + s * 32 + lg * 8);
        #pragma unroll
        for (int c = 0; c < 8; ++c) {
            bf16x8 bh = *reinterpret_cast<const bf16x8*>(W2h + (size_t)((c * 4 + s) * 64 + l) * 8);
            bf16x8 bl = *reinterpret_cast<const bf16x8*>(W2l + (size_t)((c * 4 + s) * 64 + l) * 8);
            acc[c] = MFMA16(ah, bl, acc[c]);
            acc[c] = MFMA16(ah, bh, acc[c]);
        }
    }

    // ---- bias + GELU -> msgN bf16 ----
    const int nrow = n0 + w * 16 + lg * 4;
    #pragma unroll
    for (int i = 0; i < 4; ++i) {
        if (nrow + i < NN) {
            #pragma unroll
            for (int c = 0; c < 8; ++c)
                msgN[(size_t)(nrow + i) * DD + c * 16 + lr] = f2bf_rn(gelu_f(acc[c][i] + b2v[c]));
        }
    }
}

// ---------------- CSR build: histogram -> 3-phase multi-block scan -> fill ----------
__global__ void hist_kernel(const int* __restrict__ edges, int* __restrict__ cnt) {
    int e = blockIdx.x * 256 + threadIdx.x;
    if (e < EE) atomicAdd(&cnt[edges[e]], 1);
}

#define NB 196  // ceil(NN/256)

// phase 1: per-block sums of 256 counts
__global__ void bsum_kernel(const int* __restrict__ cnt, int* __restrict__ bsum) {
    int i = blockIdx.x * 256 + threadIdx.x;
    int v = (i < NN) ? cnt[i] : 0;
    #pragma unroll
    for (int m = 1; m < 64; m <<= 1) v += __shfl_xor(v, m);
    __shared__ int S[4];
    if ((threadIdx.x & 63) == 0) S[threadIdx.x >> 6] = v;
    __syncthreads();
    if (threadIdx.x == 0) bsum[blockIdx.x] = S[0] + S[1] + S[2] + S[3];
}

// phase 2: exclusive scan of NB block sums (single tiny block)
__global__ void bscan_kernel(const int* __restrict__ bsum, int* __restrict__ boff) {
    __shared__ int S[256];
    int t = threadIdx.x;
    int v = (t < NB) ? bsum[t] : 0;
    S[t] = v;
    __syncthreads();
    for (int off = 1; off < 256; off <<= 1) {
        int u = (t >= off) ? S[t - off] : 0;
        __syncthreads();
        S[t] += u;
        __syncthreads();
    }
    if (t < NB) boff[t] = S[t] - v;  // exclusive
}

// phase 3: in-block exclusive scan + block offset -> starts
__global__ void starts_kernel(const int* __restrict__ cnt, const int* __restrict__ boff,
                              int* __restrict__ starts) {
    __shared__ int S[256];
    int t = threadIdx.x, i = blockIdx.x * 256 + t;
    int v = (i < NN) ? cnt[i] : 0;
    S[t] = v;
    __syncthreads();
    for (int off = 1; off < 256; off <<= 1) {
        int u = (t >= off) ? S[t - off] : 0;
        __syncthreads();
        S[t] += u;
        __syncthreads();
    }
    if (i < NN) starts[i] = boff[blockIdx.x] + S[t] - v;
    if (i == 0) starts[NN] = EE;  // exact: every edge has a dst
}

__global__ void fill_kernel(const int* __restrict__ edges, const float* __restrict__ ew,
                            const int* __restrict__ starts, int* __restrict__ cursor,
                            uint2* __restrict__ payload) {
    int e = blockIdx.x * 256 + threadIdx.x;
    if (e >= EE) return;
    int dst = edges[e];
    int slot = atomicAdd(&cursor[dst], 1);
    payload[starts[dst] + slot] = make_uint2((uint)edges[EE + e], __float_as_uint(ew[e]));
}

// ---------------- agg kernel: per-dst weighted sum of msgN rows (NO atomics) ----------
__global__ __launch_bounds__(256, 8) void agg_kernel(
    const uint2* __restrict__ payload, const int* __restrict__ starts,
    const ushort* __restrict__ msgN, ushort* __restrict__ aggb)
{
    const int t = threadIdx.x;
    const int node = blockIdx.x * 16 + (t >> 4);
    const int la = t & 15;
    const int beg = starts[node], end = starts[node + 1];
    const ushort* base = msgN + la * 8;

    float acc[8] = {0.f, 0.f, 0.f, 0.f, 0.f, 0.f, 0.f, 0.f};
    int k = beg;
    for (; k + 1 < end; k += 2) {           // 2-way unroll for load ILP
        uint2 p0 = payload[k], p1 = payload[k + 1];
        bf16x8 m0 = *reinterpret_cast<const bf16x8*>(base + (size_t)p0.x * DD);
        bf16x8 m1 = *reinterpret_cast<const bf16x8*>(base + (size_t)p1.x * DD);
        float w0 = __uint_as_float(p0.y), w1 = __uint_as_float(p1.y);
        #pragma unroll
        for (int j = 0; j < 8; ++j) {
            acc[j] = fmaf(w0, bf2f((ushort)m0[j]), acc[j]);
            acc[j] = fmaf(w1, bf2f((ushort)m1[j]), acc[j]);
        }
    }
    if (k < end) {
        uint2 p0 = payload[k];
        bf16x8 m0 = *reinterpret_cast<const bf16x8*>(base + (size_t)p0.x * DD);
        float w0 = __uint_as_float(p0.y);
        #pragma unroll
        for (int j = 0; j < 8; ++j) acc[j] = fmaf(w0, bf2f((ushort)m0[j]), acc[j]);
    }
    uint4 o;
    o.x = pk2(acc[0], acc[1]);
    o.y = pk2(acc[2], acc[3]);
    o.z = pk2(acc[4], acc[5]);
    o.w = pk2(acc[6], acc[7]);
    *reinterpret_cast<uint4*>(aggb + (size_t)node * DD + la * 8) = o;
}

// ---------------- node kernel: concat -> MFMA FFN(2 layers) -> L2 normalize ----------
__global__ __launch_bounds__(256, 4) void node_kernel(
    const float* __restrict__ reps, const ushort* __restrict__ aggb,
    const ushort* __restrict__ U1h, const ushort* __restrict__ U1l, const float* __restrict__ C1,
    const ushort* __restrict__ U2h, const ushort* __restrict__ U2l, const float* __restrict__ C2,
    float* __restrict__ out)
{
    __shared__ ushort Yh[64 * YLD];
    const int t = threadIdx.x;
    const int w = t >> 6, l = t & 63, lg = l >> 4, lr = l & 15;
    const int n0 = blockIdx.x * 64;
    int n = n0 + w * 16 + lr;
    int nc = n < NN ? n : NN - 1;

    float c1v[8], c2v[8];
    #pragma unroll
    for (int c = 0; c < 8; ++c) { c1v[c] = C1[c * 16 + lr]; c2v[c] = C2[c * 16 + lr]; }

    f32x4 acc[8];
    #pragma unroll
    for (int c = 0; c < 8; ++c) acc[c] = (f32x4)(0.f);

    // ---- update layer 1, reps half (k=0..127): f32 A hi+lo, 3 MFMAs ----
    #pragma unroll
    for (int s = 0; s < 4; ++s) {
        const float* sp = reps + (size_t)nc * DD + s * 32 + lg * 8;
        float4 x0 = *reinterpret_cast<const float4*>(sp);
        float4 x1 = *reinterpret_cast<const float4*>(sp + 4);
        bf16x8 ah, al;
        cvt_hilo(x0, x1, ah, al);
        #pragma unroll
        for (int c = 0; c < 8; ++c) {
            bf16x8 bh = *reinterpret_cast<const bf16x8*>(U1h + (size_t)((c * 8 + s) * 64 + l) * 8);
            bf16x8 bl = *reinterpret_cast<const bf16x8*>(U1l + (size_t)((c * 8 + s) * 64 + l) * 8);
            acc[c] = MFMA16(al, bh, acc[c]);
            acc[c] = MFMA16(ah, bl, acc[c]);
            acc[c] = MFMA16(ah, bh, acc[c]);
        }
    }
    // ---- update layer 1, agg half (k=128..255): bf16 A direct, 2 MFMAs ----
    #pragma unroll
    for (int s = 4; s < 8; ++s) {
        bf16x8 ah = *reinterpret_cast<const bf16x8*>(aggb + (size_t)nc * DD + (s - 4) * 32 + lg * 8);
        #pragma unroll
        for (int c = 0; c < 8; ++c) {
            bf16x8 bh = *reinterpret_cast<const bf16x8*>(U1h + (size_t)((c * 8 + s) * 64 + l) * 8);
            bf16x8 bl = *reinterpret_cast<const bf16x8*>(U1l + (size_t)((c * 8 + s) * 64 + l) * 8);
            acc[c] = MFMA16(ah, bl, acc[c]);
            acc[c] = MFMA16(ah, bh, acc[c]);
        }
    }
    #pragma unroll
    for (int c = 0; c < 8; ++c) {
        #pragma unroll
        for (int i = 0; i < 4; ++i) {
            float yv = gelu_f(acc[c][i] + c1v[c]);
            Yh[(w * 16 + lg * 4 + i) * YLD + c * 16 + lr] = f2bf_rn(yv);
        }
    }

    // ---- update layer 2: K=128, A = bf16 Y from LDS, 2 MFMAs ----
    #pragma unroll
    for (int c = 0; c < 8; ++c) acc[c] = (f32x4)(0.f);
    const ushort* yr = Yh + (w * 16 + lr) * YLD;
    #pragma unroll
    for (int s = 0; s < 4; ++s) {
        bf16x8 ah = *reinterpret_cast<const bf16x8*>(yr + s * 32 + lg * 8);
        #pragma unroll
        for (int c = 0; c < 8; ++c) {
            bf16x8 bh = *reinterpret_cast<const bf16x8*>(U2h + (size_t)((c * 4 + s) * 64 + l) * 8);
            bf16x8 bl = *reinterpret_cast<const bf16x8*>(U2l + (size_t)((c * 4 + s) * 64 + l) * 8);
            acc[c] = MFMA16(ah, bl, acc[c]);
            acc[c] = MFMA16(ah, bh, acc[c]);
        }
    }

    // ---- bias + GELU + L2 normalize + store ----
    float ssq[4] = {0.f, 0.f, 0.f, 0.f};
    #pragma unroll
    for (int c = 0; c < 8; ++c) {
        #pragma unroll
        for (int i = 0; i < 4; ++i) {
            float vv = gelu_f(acc[c][i] + c2v[c]);
            acc[c][i] = vv;
            ssq[i] = fmaf(vv, vv, ssq[i]);
        }
    }
    #pragma unroll
    for (int i = 0; i < 4; ++i) {
        #pragma unroll
        for (int msk = 1; msk < 16; msk <<= 1) ssq[i] += __shfl_xor(ssq[i], msk);
        ssq[i] = rsqrtf(fmaxf(ssq[i], 1e-12f));
    }
    const int nrow = n0 + w * 16 + lg * 4;
    #pragma unroll
    for (int i = 0; i < 4; ++i) {
        if (nrow + i < NN) {
            #pragma unroll
            for (int c = 0; c < 8; ++c)
                out[(size_t)(nrow + i) * DD + c * 16 + lr] = acc[c][i] * ssq[i];
        }
    }
}

// ---------------- launch ----------------
extern "C" void kernel_launch(void* const* d_in, const int* in_sizes, int n_in,
                              void* d_out, int out_size, void* d_ws, size_t ws_size,
                              hipStream_t stream)
{
    const float* reps = (const float*)d_in[0];
    const int*   edges = (const int*)d_in[1];
    const float* ew   = (const float*)d_in[2];
    const float* bn1g = (const float*)d_in[3];
    const float* bn1b = (const float*)d_in[4];
    const float* bn1m = (const float*)d_in[5];
    const float* bn1v = (const float*)d_in[6];
    const float* w1   = (const float*)d_in[7];
    const float* b1   = (const float*)d_in[8];
    const float* bn2g = (const float*)d_in[9];
    const float* bn2b = (const float*)d_in[10];
    const float* bn2m = (const float*)d_in[11];
    const float* bn2v = (const float*)d_in[12];
    const float* w2   = (const float*)d_in[13];
    const float* b2   = (const float*)d_in[14];
    const float* ubn1g = (const float*)d_in[15];
    const float* ubn1b = (const float*)d_in[16];
    const float* ubn1m = (const float*)d_in[17];
    const float* ubn1v = (const float*)d_in[18];
    const float* u1    = (const float*)d_in[19];
    const float* ub1   = (const float*)d_in[20];
    const float* ubn2g = (const float*)d_in[21];
    const float* ubn2b = (const float*)d_in[22];
    const float* ubn2m = (const float*)d_in[23];
    const float* ubn2v = (const float*)d_in[24];
    const float* u2    = (const float*)d_in[25];
    const float* ub2   = (const float*)d_in[26];

    // workspace layout (bytes)
    char* wsb = (char*)d_ws;
    uint2*  payload = (uint2*)wsb;                       // 6,400,000 B
    ushort* aggb    = (ushort*)(wsb + 6400000);          // 12,800,000 B
    int*    cnt     = (int*)(wsb + 19200000);            // 200,000 B
    int*    cursor  = (int*)(wsb + 19400000);            // 200,000 B
    int*    starts  = (int*)(wsb + 19600000);            // 200,004 B
    int*    bsum    = (int*)(wsb + 19800016);            // 784 B
    int*    boff    = (int*)(wsb + 19801040);            // 784 B
    float*  B1f     = (float*)(wsb + 19802064);          // 128 f32 each, 16B aligned
    float*  B2f     = B1f + 128;
    float*  C1f     = B2f + 128;
    float*  C2f     = C1f + 128;
    ushort* up      = (ushort*)(C2f + 128);
    ushort* W1h = up;                                    // 16384 each
    ushort* W1l = W1h + 16384;
    ushort* W2h = W1l + 16384;
    ushort* W2l = W2h + 16384;
    ushort* U1h = W2l + 16384;                           // 32768 each
    ushort* U1l = U1h + 32768;
    ushort* U2h = U1l + 32768;                           // 16384 each
    ushort* U2l = U2h + 16384;
    if (ws_size < 20300000) return;

    // msgN (bf16, 12.8 MB) lives in d_out: dead before node_kernel overwrites d_out.
    ushort* msgN = (ushort*)d_out;

    pack_w<<<64,  256, 0, stream>>>(w1, bn1g, bn1v, W1h, W1l, 128);
    fold_b<<<1,   128, 0, stream>>>(w1, bn1g, bn1b, bn1m, bn1v, b1, B1f, 128);
    pack_w<<<64,  256, 0, stream>>>(w2, bn2g, bn2v, W2h, W2l, 128);
    fold_b<<<1,   128, 0, stream>>>(w2, bn2g, bn2b, bn2m, bn2v, b2, B2f, 128);
    pack_w<<<128, 256, 0, stream>>>(u1, ubn1g, ubn1v, U1h, U1l, 256);
    fold_b<<<1,   128, 0, stream>>>(u1, ubn1g, ubn1b, ubn1m, ubn1v, ub1, C1f, 256);
    pack_w<<<64,  256, 0, stream>>>(u2, ubn2g, ubn2v, U2h, U2l, 128);
    fold_b<<<1,   128, 0, stream>>>(u2, ubn2g, ubn2b, ubn2m, ubn2v, ub2, C2f, 128);

    (void)hipMemsetAsync(cnt, 0, 400000, stream);  // cnt + cursor (adjacent)

    prep_kernel<<<(NN + 127) / 128, 512, 0, stream>>>(reps, W1h, W1l, B1f,
                                                      W2h, W2l, B2f, msgN);
    hist_kernel<<<(EE + 255) / 256, 256, 0, stream>>>(edges, cnt);
    bsum_kernel<<<NB, 256, 0, stream>>>(cnt, bsum);
    bscan_kernel<<<1, 256, 0, stream>>>(bsum, boff);
    starts_kernel<<<NB, 256, 0, stream>>>(cnt, boff, starts);
    fill_kernel<<<(EE + 255) / 256, 256, 0, stream>>>(edges, ew, starts, cursor, payload);
    agg_kernel<<<NN / 16, 256, 0, stream>>>(payload, starts, msgN, aggb);
    node_kernel<<<(NN + 63) / 64, 256, 0, stream>>>(reps, aggb, U1h, U1l, C1f,
                                                    U2h, U2l, C2f, (float*)d_out);
}

// Round 13
// 214.384 us; speedup vs baseline: 3.0281x; 1.6712x over previous
//
#include <hip/hip_runtime.h>
#include <hip/hip_bf16.h>
#include <math.h>

#define NN 50000
#define DD 128
#define EE 800000

static constexpr float BN_EPS = 1e-3f;

typedef __attribute__((ext_vector_type(8))) short bf16x8;
typedef __attribute__((ext_vector_type(4))) float f32x4;

#define MFMA16(a, b, c) __builtin_amdgcn_mfma_f32_16x16x32_bf16((a), (b), (c), 0, 0, 0)

// fast exact-grade GELU: Abramowitz-Stegun 7.1.26 erf (abs err 1.5e-7)
__device__ __forceinline__ float gelu_f(float x) {
    float ax = fabsf(x) * 0.7071067811865475f;
    float t = __builtin_amdgcn_rcpf(fmaf(0.3275911f, ax, 1.0f));
    float p = t * fmaf(t, fmaf(t, fmaf(t, fmaf(t, 1.061405429f, -1.453152027f),
                                       1.421413741f), -0.284496736f), 0.254829592f);
    float e = __expf(-ax * ax);
    float er = fmaf(-p, e, 1.0f);        // erf(|x|/sqrt2) for ax>=0
    float s = copysignf(er, x);
    return 0.5f * x * (1.0f + s);
}

__device__ __forceinline__ ushort f2bf_rn(float f) {
    uint u = __float_as_uint(f);
    return (ushort)((u + 0x7FFFu + ((u >> 16) & 1u)) >> 16);
}
__device__ __forceinline__ float bf2f(ushort h) {
    return __uint_as_float(((uint)h) << 16);
}

// packed pair f32->bf16 RNE (compiler emits v_cvt_pk_bf16_f32); low16=a, high16=b
__device__ __forceinline__ uint pk2(float a, float b) {
    __hip_bfloat162 t = __float22bfloat162_rn(make_float2(a, b));
    uint r;
    __builtin_memcpy(&r, &t, 4);
    return r;
}

// split f32x8 -> bf16 hi + bf16 lo fragments (f ~= hi + lo, |resid| ~ 2^-17|f|)
__device__ __forceinline__ void cvt_hilo(float4 x0, float4 x1, bf16x8& h, bf16x8& l) {
    float f[8] = {x0.x, x0.y, x0.z, x0.w, x1.x, x1.y, x1.z, x1.w};
    union U { uint u[4]; bf16x8 v; } uh, ul;
    #pragma unroll
    for (int j = 0; j < 4; ++j) {
        uint p = pk2(f[2 * j], f[2 * j + 1]);
        uh.u[j] = p;
        float h0 = __uint_as_float(p << 16);
        float h1 = __uint_as_float(p & 0xFFFF0000u);
        ul.u[j] = pk2(f[2 * j] - h0, f[2 * j + 1] - h1);
    }
    h = uh.v;
    l = ul.v;
}

// ---------------- fused weight-prep kernels ----------------
// pack element (k,col) of folded W -> plane offset ((c*(K/32)+st)*64+ln)*8+j (see r1 notes)
__device__ __forceinline__ void pack_one(const float* __restrict__ W, const float* __restrict__ g,
                                         const float* __restrict__ v, ushort* __restrict__ hi,
                                         ushort* __restrict__ lo, int K, int idx) {
    int k = idx >> 7, col = idx & 127;
    float s = g[k] * rsqrtf(v[k] + BN_EPS);
    float f = s * W[idx];
    int S = K >> 5;
    int st = k >> 5, gq = (k >> 3) & 3, j = k & 7;
    int c = col >> 4, ln = (gq << 4) | (col & 15);
    int o = ((c * S + st) * 64 + ln) * 8 + j;
    ushort hb = f2bf_rn(f);
    hi[o] = hb;
    lo[o] = f2bf_rn(f - bf2f(hb));
}

// all 4 matrices in one launch; segment boundaries are multiples of 256 -> no straddle
__global__ void pack_all(
    const float* __restrict__ w1, const float* __restrict__ g1, const float* __restrict__ v1,
    ushort* __restrict__ W1h, ushort* __restrict__ W1l,
    const float* __restrict__ w2, const float* __restrict__ g2, const float* __restrict__ v2,
    ushort* __restrict__ W2h, ushort* __restrict__ W2l,
    const float* __restrict__ u1, const float* __restrict__ g3, const float* __restrict__ v3,
    ushort* __restrict__ U1h, ushort* __restrict__ U1l,
    const float* __restrict__ u2, const float* __restrict__ g4, const float* __restrict__ v4,
    ushort* __restrict__ U2h, ushort* __restrict__ U2l)
{
    int idx = blockIdx.x * 256 + threadIdx.x;       // 0..81919
    if (idx < 16384)       pack_one(w1, g1, v1, W1h, W1l, 128, idx);
    else if (idx < 32768)  pack_one(w2, g2, v2, W2h, W2l, 128, idx - 16384);
    else if (idx < 65536)  pack_one(u1, g3, v3, U1h, U1l, 256, idx - 32768);
    else                   pack_one(u2, g4, v4, U2h, U2l, 128, idx - 65536);
}

// bf[j] = bias[j]  (fresh each call -> fold_all atomics never double-accumulate)
__global__ void init_bias(const float* __restrict__ b1, const float* __restrict__ b2,
                          const float* __restrict__ ub1, const float* __restrict__ ub2,
                          float* __restrict__ B1f, float* __restrict__ B2f,
                          float* __restrict__ C1f, float* __restrict__ C2f) {
    int t = threadIdx.x;  // 128
    B1f[t] = b1[t]; B2f[t] = b2[t]; C1f[t] = ub1[t]; C2f[t] = ub2[t];
}

// fused BN-bias fold: 20 blocks x 32 k-rows; coalesced loads, LDS reduce, 1 atomic/col.
// global row r in [0,640): [0,128)=W1, [128,256)=W2, [256,512)=U1, [512,640)=U2.
__global__ __launch_bounds__(256) void fold_all(
    const float* __restrict__ w1, const float* __restrict__ g1, const float* __restrict__ b1,
    const float* __restrict__ m1, const float* __restrict__ v1, float* __restrict__ B1f,
    const float* __restrict__ w2, const float* __restrict__ g2, const float* __restrict__ b2,
    const float* __restrict__ m2, const float* __restrict__ v2, float* __restrict__ B2f,
    const float* __restrict__ u1, const float* __restrict__ g3, const float* __restrict__ b3,
    const float* __restrict__ m3, const float* __restrict__ v3, float* __restrict__ C1f,
    const float* __restrict__ u2, const float* __restrict__ g4, const float* __restrict__ b4,
    const float* __restrict__ m4, const float* __restrict__ v4, float* __restrict__ C2f)
{
    const int rs = blockIdx.x * 32;
    const float *W, *g, *bb, *m, *v;
    float* bf;
    int k0;
    if (rs < 128)      { W = w1; g = g1; bb = b1; m = m1; v = v1; bf = B1f; k0 = rs; }
    else if (rs < 256) { W = w2; g = g2; bb = b2; m = m2; v = v2; bf = B2f; k0 = rs - 128; }
    else if (rs < 512) { W = u1; g = g3; bb = b3; m = m3; v = v3; bf = C1f; k0 = rs - 256; }
    else               { W = u2; g = g4; bb = b4; m = m4; v = v4; bf = C2f; k0 = rs - 512; }

    const int t = threadIdx.x, j = t & 127, h = t >> 7;
    float acc = 0.f;
    #pragma unroll
    for (int kk = 0; kk < 16; ++kk) {
        int k = k0 + h * 16 + kk;
        float s = g[k] * rsqrtf(v[k] + BN_EPS);
        float tt = bb[k] - m[k] * s;
        acc = fmaf(tt, W[k * DD + j], acc);
    }
    __shared__ float S[256];
    S[t] = acc;
    __syncthreads();
    if (h == 0) atomicAdd(&bf[j], S[j] + S[128 + j]);
}

#define YLD 136

// ---------------- prep kernel: per-NODE FFN_pre -> msgN bf16 [NN][128] ----------------
__global__ __launch_bounds__(512, 4) void prep_kernel(
    const float* __restrict__ reps,
    const ushort* __restrict__ W1h, const ushort* __restrict__ W1l, const float* __restrict__ B1,
    const ushort* __restrict__ W2h, const ushort* __restrict__ W2l, const float* __restrict__ B2,
    ushort* __restrict__ msgN)
{
    __shared__ ushort Yh[128 * YLD];
    const int t = threadIdx.x;
    const int w = t >> 6, l = t & 63, lg = l >> 4, lr = l & 15;
    const int n0 = blockIdx.x * 128;
    int n = n0 + w * 16 + lr;
    int nc = n < NN ? n : NN - 1;
    const float* src = reps + (size_t)nc * DD;

    float b1v[8], b2v[8];
    #pragma unroll
    for (int c = 0; c < 8; ++c) { b1v[c] = B1[c * 16 + lr]; b2v[c] = B2[c * 16 + lr]; }

    f32x4 acc[8];
    #pragma unroll
    for (int c = 0; c < 8; ++c) acc[c] = (f32x4)(0.f);

    // ---- layer 1 (A hi+lo, 3 MFMAs) ----
    #pragma unroll
    for (int s = 0; s < 4; ++s) {
        float4 x0 = *reinterpret_cast<const float4*>(src + s * 32 + lg * 8);
        float4 x1 = *reinterpret_cast<const float4*>(src + s * 32 + lg * 8 + 4);
        bf16x8 ah, al;
        cvt_hilo(x0, x1, ah, al);
        #pragma unroll
        for (int c = 0; c < 8; ++c) {
            bf16x8 bh = *reinterpret_cast<const bf16x8*>(W1h + (size_t)((c * 4 + s) * 64 + l) * 8);
            bf16x8 bl = *reinterpret_cast<const bf16x8*>(W1l + (size_t)((c * 4 + s) * 64 + l) * 8);
            acc[c] = MFMA16(al, bh, acc[c]);
            acc[c] = MFMA16(ah, bl, acc[c]);
            acc[c] = MFMA16(ah, bh, acc[c]);
        }
    }
    #pragma unroll
    for (int c = 0; c < 8; ++c) {
        #pragma unroll
        for (int i = 0; i < 4; ++i) {
            float yv = gelu_f(acc[c][i] + b1v[c]);
            Yh[(w * 16 + lg * 4 + i) * YLD + c * 16 + lr] = f2bf_rn(yv);
        }
    }

    // ---- layer 2 (A = bf16 Y from LDS; B hi/lo -> 2 MFMAs) ----
    #pragma unroll
    for (int c = 0; c < 8; ++c) acc[c] = (f32x4)(0.f);
    const ushort* yr = Yh + (w * 16 + lr) * YLD;
    #pragma unroll
    for (int s = 0; s < 4; ++s) {
        bf16x8 ah = *reinterpret_cast<const bf16x8*>(yr + s * 32 + lg * 8);
        #pragma unroll
        for (int c = 0; c < 8; ++c) {
            bf16x8 bh = *reinterpret_cast<const bf16x8*>(W2h + (size_t)((c * 4 + s) * 64 + l) * 8);
            bf16x8 bl = *reinterpret_cast<const bf16x8*>(W2l + (size_t)((c * 4 + s) * 64 + l) * 8);
            acc[c] = MFMA16(ah, bl, acc[c]);
            acc[c] = MFMA16(ah, bh, acc[c]);
        }
    }

    // ---- bias + GELU -> msgN bf16 ----
    const int nrow = n0 + w * 16 + lg * 4;
    #pragma unroll
    for (int i = 0; i < 4; ++i) {
        if (nrow + i < NN) {
            #pragma unroll
            for (int c = 0; c < 8; ++c)
                msgN[(size_t)(nrow + i) * DD + c * 16 + lr] = f2bf_rn(gelu_f(acc[c][i] + b2v[c]));
        }
    }
}

// ---------------- CSR build: histogram -> 3-phase multi-block scan -> fill ----------
__global__ void hist_kernel(const int* __restrict__ edges, int* __restrict__ cnt) {
    int e = blockIdx.x * 256 + threadIdx.x;
    if (e < EE) atomicAdd(&cnt[edges[e]], 1);
}

#define NB 196  // ceil(NN/256)

__global__ void bsum_kernel(const int* __restrict__ cnt, int* __restrict__ bsum) {
    int i = blockIdx.x * 256 + threadIdx.x;
    int v = (i < NN) ? cnt[i] : 0;
    #pragma unroll
    for (int m = 1; m < 64; m <<= 1) v += __shfl_xor(v, m);
    __shared__ int S[4];
    if ((threadIdx.x & 63) == 0) S[threadIdx.x >> 6] = v;
    __syncthreads();
    if (threadIdx.x == 0) bsum[blockIdx.x] = S[0] + S[1] + S[2] + S[3];
}

__global__ void bscan_kernel(const int* __restrict__ bsum, int* __restrict__ boff) {
    __shared__ int S[256];
    int t = threadIdx.x;
    int v = (t < NB) ? bsum[t] : 0;
    S[t] = v;
    __syncthreads();
    for (int off = 1; off < 256; off <<= 1) {
        int u = (t >= off) ? S[t - off] : 0;
        __syncthreads();
        S[t] += u;
        __syncthreads();
    }
    if (t < NB) boff[t] = S[t] - v;  // exclusive
}

__global__ void starts_kernel(const int* __restrict__ cnt, const int* __restrict__ boff,
                              int* __restrict__ starts) {
    __shared__ int S[256];
    int t = threadIdx.x, i = blockIdx.x * 256 + t;
    int v = (i < NN) ? cnt[i] : 0;
    S[t] = v;
    __syncthreads();
    for (int off = 1; off < 256; off <<= 1) {
        int u = (t >= off) ? S[t - off] : 0;
        __syncthreads();
        S[t] += u;
        __syncthreads();
    }
    if (i < NN) starts[i] = boff[blockIdx.x] + S[t] - v;
    if (i == 0) starts[NN] = EE;  // exact: every edge has a dst
}

__global__ void fill_kernel(const int* __restrict__ edges, const float* __restrict__ ew,
                            const int* __restrict__ starts, int* __restrict__ cursor,
                            uint2* __restrict__ payload) {
    int e = blockIdx.x * 256 + threadIdx.x;
    if (e >= EE) return;
    int dst = edges[e];
    int slot = atomicAdd(&cursor[dst], 1);
    payload[starts[dst] + slot] = make_uint2((uint)edges[EE + e], __float_as_uint(ew[e]));
}

// ---------------- agg kernel: per-dst weighted sum of msgN rows (NO atomics) ----------
__global__ __launch_bounds__(256, 8) void agg_kernel(
    const uint2* __restrict__ payload, const int* __restrict__ starts,
    const ushort* __restrict__ msgN, ushort* __restrict__ aggb)
{
    const int t = threadIdx.x;
    const int node = blockIdx.x * 16 + (t >> 4);
    const int la = t & 15;
    const int beg = starts[node], end = starts[node + 1];
    const ushort* base = msgN + la * 8;

    float acc[8] = {0.f, 0.f, 0.f, 0.f, 0.f, 0.f, 0.f, 0.f};
    int k = beg;
    for (; k + 1 < end; k += 2) {           // 2-way unroll for load ILP
        uint2 p0 = payload[k], p1 = payload[k + 1];
        bf16x8 m0 = *reinterpret_cast<const bf16x8*>(base + (size_t)p0.x * DD);
        bf16x8 m1 = *reinterpret_cast<const bf16x8*>(base + (size_t)p1.x * DD);
        float w0 = __uint_as_float(p0.y), w1 = __uint_as_float(p1.y);
        #pragma unroll
        for (int j = 0; j < 8; ++j) {
            acc[j] = fmaf(w0, bf2f((ushort)m0[j]), acc[j]);
            acc[j] = fmaf(w1, bf2f((ushort)m1[j]), acc[j]);
        }
    }
    if (k < end) {
        uint2 p0 = payload[k];
        bf16x8 m0 = *reinterpret_cast<const bf16x8*>(base + (size_t)p0.x * DD);
        float w0 = __uint_as_float(p0.y);
        #pragma unroll
        for (int j = 0; j < 8; ++j) acc[j] = fmaf(w0, bf2f((ushort)m0[j]), acc[j]);
    }
    uint4 o;
    o.x = pk2(acc[0], acc[1]);
    o.y = pk2(acc[2], acc[3]);
    o.z = pk2(acc[4], acc[5]);
    o.w = pk2(acc[6], acc[7]);
    *reinterpret_cast<uint4*>(aggb + (size_t)node * DD + la * 8) = o;
}

// ---------------- node kernel: concat -> MFMA FFN(2 layers) -> L2 normalize ----------
__global__ __launch_bounds__(256, 4) void node_kernel(
    const float* __restrict__ reps, const ushort* __restrict__ aggb,
    const ushort* __restrict__ U1h, const ushort* __restrict__ U1l, const float* __restrict__ C1,
    const ushort* __restrict__ U2h, const ushort* __restrict__ U2l, const float* __restrict__ C2,
    float* __restrict__ out)
{
    __shared__ ushort Yh[64 * YLD];
    const int t = threadIdx.x;
    const int w = t >> 6, l = t & 63, lg = l >> 4, lr = l & 15;
    const int n0 = blockIdx.x * 64;
    int n = n0 + w * 16 + lr;
    int nc = n < NN ? n : NN - 1;

    float c1v[8], c2v[8];
    #pragma unroll
    for (int c = 0; c < 8; ++c) { c1v[c] = C1[c * 16 + lr]; c2v[c] = C2[c * 16 + lr]; }

    f32x4 acc[8];
    #pragma unroll
    for (int c = 0; c < 8; ++c) acc[c] = (f32x4)(0.f);

    // ---- update layer 1, reps half (k=0..127): f32 A hi+lo, 3 MFMAs ----
    #pragma unroll
    for (int s = 0; s < 4; ++s) {
        const float* sp = reps + (size_t)nc * DD + s * 32 + lg * 8;
        float4 x0 = *reinterpret_cast<const float4*>(sp);
        float4 x1 = *reinterpret_cast<const float4*>(sp + 4);
        bf16x8 ah, al;
        cvt_hilo(x0, x1, ah, al);
        #pragma unroll
        for (int c = 0; c < 8; ++c) {
            bf16x8 bh = *reinterpret_cast<const bf16x8*>(U1h + (size_t)((c * 8 + s) * 64 + l) * 8);
            bf16x8 bl = *reinterpret_cast<const bf16x8*>(U1l + (size_t)((c * 8 + s) * 64 + l) * 8);
            acc[c] = MFMA16(al, bh, acc[c]);
            acc[c] = MFMA16(ah, bl, acc[c]);
            acc[c] = MFMA16(ah, bh, acc[c]);
        }
    }
    // ---- update layer 1, agg half (k=128..255): bf16 A direct, 2 MFMAs ----
    #pragma unroll
    for (int s = 4; s < 8; ++s) {
        bf16x8 ah = *reinterpret_cast<const bf16x8*>(aggb + (size_t)nc * DD + (s - 4) * 32 + lg * 8);
        #pragma unroll
        for (int c = 0; c < 8; ++c) {
            bf16x8 bh = *reinterpret_cast<const bf16x8*>(U1h + (size_t)((c * 8 + s) * 64 + l) * 8);
            bf16x8 bl = *reinterpret_cast<const bf16x8*>(U1l + (size_t)((c * 8 + s) * 64 + l) * 8);
            acc[c] = MFMA16(ah, bl, acc[c]);
            acc[c] = MFMA16(ah, bh, acc[c]);
        }
    }
    #pragma unroll
    for (int c = 0; c < 8; ++c) {
        #pragma unroll
        for (int i = 0; i < 4; ++i) {
            float yv = gelu_f(acc[c][i] + c1v[c]);
            Yh[(w * 16 + lg * 4 + i) * YLD + c * 16 + lr] = f2bf_rn(yv);
        }
    }

    // ---- update layer 2: K=128, A = bf16 Y from LDS, 2 MFMAs ----
    #pragma unroll
    for (int c = 0; c < 8; ++c) acc[c] = (f32x4)(0.f);
    const ushort* yr = Yh + (w * 16 + lr) * YLD;
    #pragma unroll
    for (int s = 0; s < 4; ++s) {
        bf16x8 ah = *reinterpret_cast<const bf16x8*>(yr + s * 32 + lg * 8);
        #pragma unroll
        for (int c = 0; c < 8; ++c) {
            bf16x8 bh = *reinterpret_cast<const bf16x8*>(U2h + (size_t)((c * 4 + s) * 64 + l) * 8);
            bf16x8 bl = *reinterpret_cast<const bf16x8*>(U2l + (size_t)((c * 4 + s) * 64 + l) * 8);
            acc[c] = MFMA16(ah, bl, acc[c]);
            acc[c] = MFMA16(ah, bh, acc[c]);
        }
    }

    // ---- bias + GELU + L2 normalize + store ----
    float ssq[4] = {0.f, 0.f, 0.f, 0.f};
    #pragma unroll
    for (int c = 0; c < 8; ++c) {
        #pragma unroll
        for (int i = 0; i < 4; ++i) {
            float vv = gelu_f(acc[c][i] + c2v[c]);
            acc[c][i] = vv;
            ssq[i] = fmaf(vv, vv, ssq[i]);
        }
    }
    #pragma unroll
    for (int i = 0; i < 4; ++i) {
        #pragma unroll
        for (int msk = 1; msk < 16; msk <<= 1) ssq[i] += __shfl_xor(ssq[i], msk);
        ssq[i] = rsqrtf(fmaxf(ssq[i], 1e-12f));
    }
    const int nrow = n0 + w * 16 + lg * 4;
    #pragma unroll
    for (int i = 0; i < 4; ++i) {
        if (nrow + i < NN) {
            #pragma unroll
            for (int c = 0; c < 8; ++c)
                out[(size_t)(nrow + i) * DD + c * 16 + lr] = acc[c][i] * ssq[i];
        }
    }
}

// ---------------- launch ----------------
extern "C" void kernel_launch(void* const* d_in, const int* in_sizes, int n_in,
                              void* d_out, int out_size, void* d_ws, size_t ws_size,
                              hipStream_t stream)
{
    const float* reps = (const float*)d_in[0];
    const int*   edges = (const int*)d_in[1];
    const float* ew   = (const float*)d_in[2];
    const float* bn1g = (const float*)d_in[3];
    const float* bn1b = (const float*)d_in[4];
    const float* bn1m = (const float*)d_in[5];
    const float* bn1v = (const float*)d_in[6];
    const float* w1   = (const float*)d_in[7];
    const float* b1   = (const float*)d_in[8];
    const float* bn2g = (const float*)d_in[9];
    const float* bn2b = (const float*)d_in[10];
    const float* bn2m = (const float*)d_in[11];
    const float* bn2v = (const float*)d_in[12];
    const float* w2   = (const float*)d_in[13];
    const float* b2   = (const float*)d_in[14];
    const float* ubn1g = (const float*)d_in[15];
    const float* ubn1b = (const float*)d_in[16];
    const float* ubn1m = (const float*)d_in[17];
    const float* ubn1v = (const float*)d_in[18];
    const float* u1    = (const float*)d_in[19];
    const float* ub1   = (const float*)d_in[20];
    const float* ubn2g = (const float*)d_in[21];
    const float* ubn2b = (const float*)d_in[22];
    const float* ubn2m = (const float*)d_in[23];
    const float* ubn2v = (const float*)d_in[24];
    const float* u2    = (const float*)d_in[25];
    const float* ub2   = (const float*)d_in[26];

    // workspace layout (bytes)
    char* wsb = (char*)d_ws;
    uint2*  payload = (uint2*)wsb;                       // 6,400,000 B
    ushort* aggb    = (ushort*)(wsb + 6400000);          // 12,800,000 B
    int*    cnt     = (int*)(wsb + 19200000);            // 200,000 B
    int*    cursor  = (int*)(wsb + 19400000);            // 200,000 B
    int*    starts  = (int*)(wsb + 19600000);            // 200,004 B
    int*    bsum    = (int*)(wsb + 19800016);            // 784 B
    int*    boff    = (int*)(wsb + 19801040);            // 784 B
    float*  B1f     = (float*)(wsb + 19802064);          // 128 f32 each, 16B aligned
    float*  B2f     = B1f + 128;
    float*  C1f     = B2f + 128;
    float*  C2f     = C1f + 128;
    ushort* up      = (ushort*)(C2f + 128);
    ushort* W1h = up;                                    // 16384 each
    ushort* W1l = W1h + 16384;
    ushort* W2h = W1l + 16384;
    ushort* W2l = W2h + 16384;
    ushort* U1h = W2l + 16384;                           // 32768 each
    ushort* U1l = U1h + 32768;
    ushort* U2h = U1l + 32768;                           // 16384 each
    ushort* U2l = U2h + 16384;
    if (ws_size < 20300000) return;

    // msgN (bf16, 12.8 MB) lives in d_out: dead before node_kernel overwrites d_out.
    ushort* msgN = (ushort*)d_out;

    init_bias<<<1, 128, 0, stream>>>(b1, b2, ub1, ub2, B1f, B2f, C1f, C2f);
    pack_all<<<320, 256, 0, stream>>>(w1, bn1g, bn1v, W1h, W1l,
                                      w2, bn2g, bn2v, W2h, W2l,
                                      u1, ubn1g, ubn1v, U1h, U1l,
                                      u2, ubn2g, ubn2v, U2h, U2l);
    fold_all<<<20, 256, 0, stream>>>(w1, bn1g, bn1b, bn1m, bn1v, B1f,
                                     w2, bn2g, bn2b, bn2m, bn2v, B2f,
                                     u1, ubn1g, ubn1b, ubn1m, ubn1v, C1f,
                                     u2, ubn2g, ubn2b, ubn2m, ubn2v, C2f);

    (void)hipMemsetAsync(cnt, 0, 400000, stream);  // cnt + cursor (adjacent)

    prep_kernel<<<(NN + 127) / 128, 512, 0, stream>>>(reps, W1h, W1l, B1f,
                                                      W2h, W2l, B2f, msgN);
    hist_kernel<<<(EE + 255) / 256, 256, 0, stream>>>(edges, cnt);
    bsum_kernel<<<NB, 256, 0, stream>>>(cnt, bsum);
    bscan_kernel<<<1, 256, 0, stream>>>(bsum, boff);
    starts_kernel<<<NB, 256, 0, stream>>>(cnt, boff, starts);
    fill_kernel<<<(EE + 255) / 256, 256, 0, stream>>>(edges, ew, starts, cursor, payload);
    agg_kernel<<<NN / 16, 256, 0, stream>>>(payload, starts, msgN, aggb);
    node_kernel<<<(NN + 63) / 64, 256, 0, stream>>>(reps, aggb, U1h, U1l, C1f,
                                                    U2h, U2l, C2f, (float*)d_out);
}

// Round 14
// 197.989 us; speedup vs baseline: 3.2788x; 1.0828x over previous
//
#include <hip/hip_runtime.h>
#include <hip/hip_bf16.h>
#include <math.h>

#define NN 50000
#define DD 128
#define EE 800000

static constexpr float BN_EPS = 1e-3f;

typedef __attribute__((ext_vector_type(8))) short bf16x8;
typedef __attribute__((ext_vector_type(4))) float f32x4;

#define MFMA16(a, b, c) __builtin_amdgcn_mfma_f32_16x16x32_bf16((a), (b), (c), 0, 0, 0)

// fast exact-grade GELU: Abramowitz-Stegun 7.1.26 erf (abs err 1.5e-7)
__device__ __forceinline__ float gelu_f(float x) {
    float ax = fabsf(x) * 0.7071067811865475f;
    float t = __builtin_amdgcn_rcpf(fmaf(0.3275911f, ax, 1.0f));
    float p = t * fmaf(t, fmaf(t, fmaf(t, fmaf(t, 1.061405429f, -1.453152027f),
                                       1.421413741f), -0.284496736f), 0.254829592f);
    float e = __expf(-ax * ax);
    float er = fmaf(-p, e, 1.0f);        // erf(|x|/sqrt2) for ax>=0
    float s = copysignf(er, x);
    return 0.5f * x * (1.0f + s);
}

__device__ __forceinline__ ushort f2bf_rn(float f) {
    uint u = __float_as_uint(f);
    return (ushort)((u + 0x7FFFu + ((u >> 16) & 1u)) >> 16);
}
__device__ __forceinline__ float bf2f(ushort h) {
    return __uint_as_float(((uint)h) << 16);
}

// packed pair f32->bf16 RNE (compiler emits v_cvt_pk_bf16_f32); low16=a, high16=b
__device__ __forceinline__ uint pk2(float a, float b) {
    __hip_bfloat162 t = __float22bfloat162_rn(make_float2(a, b));
    uint r;
    __builtin_memcpy(&r, &t, 4);
    return r;
}

// packed bf16 atomic add (2 cols per op) — spill path only
__device__ __forceinline__ void atomic_pk_add_bf16(ushort* addr, uint val) {
    asm volatile("global_atomic_pk_add_bf16 %0, %1, off"
                 :: "v"((void*)addr), "v"(val) : "memory");
}

// split f32x8 -> bf16 hi + bf16 lo fragments (f ~= hi + lo, |resid| ~ 2^-17|f|)
__device__ __forceinline__ void cvt_hilo(float4 x0, float4 x1, bf16x8& h, bf16x8& l) {
    float f[8] = {x0.x, x0.y, x0.z, x0.w, x1.x, x1.y, x1.z, x1.w};
    union U { uint u[4]; bf16x8 v; } uh, ul;
    #pragma unroll
    for (int j = 0; j < 4; ++j) {
        uint p = pk2(f[2 * j], f[2 * j + 1]);
        uh.u[j] = p;
        float h0 = __uint_as_float(p << 16);
        float h1 = __uint_as_float(p & 0xFFFF0000u);
        ul.u[j] = pk2(f[2 * j] - h0, f[2 * j + 1] - h1);
    }
    h = uh.v;
    l = ul.v;
}

// ---------------- fused weight-prep kernels ----------------
__device__ __forceinline__ void pack_one(const float* __restrict__ W, const float* __restrict__ g,
                                         const float* __restrict__ v, ushort* __restrict__ hi,
                                         ushort* __restrict__ lo, int K, int idx) {
    int k = idx >> 7, col = idx & 127;
    float s = g[k] * rsqrtf(v[k] + BN_EPS);
    float f = s * W[idx];
    int S = K >> 5;
    int st = k >> 5, gq = (k >> 3) & 3, j = k & 7;
    int c = col >> 4, ln = (gq << 4) | (col & 15);
    int o = ((c * S + st) * 64 + ln) * 8 + j;
    ushort hb = f2bf_rn(f);
    hi[o] = hb;
    lo[o] = f2bf_rn(f - bf2f(hb));
}

__global__ void pack_all(
    const float* __restrict__ w1, const float* __restrict__ g1, const float* __restrict__ v1,
    ushort* __restrict__ W1h, ushort* __restrict__ W1l,
    const float* __restrict__ w2, const float* __restrict__ g2, const float* __restrict__ v2,
    ushort* __restrict__ W2h, ushort* __restrict__ W2l,
    const float* __restrict__ u1, const float* __restrict__ g3, const float* __restrict__ v3,
    ushort* __restrict__ U1h, ushort* __restrict__ U1l,
    const float* __restrict__ u2, const float* __restrict__ g4, const float* __restrict__ v4,
    ushort* __restrict__ U2h, ushort* __restrict__ U2l)
{
    int idx = blockIdx.x * 256 + threadIdx.x;       // 0..81919
    if (idx < 16384)       pack_one(w1, g1, v1, W1h, W1l, 128, idx);
    else if (idx < 32768)  pack_one(w2, g2, v2, W2h, W2l, 128, idx - 16384);
    else if (idx < 65536)  pack_one(u1, g3, v3, U1h, U1l, 256, idx - 32768);
    else                   pack_one(u2, g4, v4, U2h, U2l, 128, idx - 65536);
}

__global__ void init_bias(const float* __restrict__ b1, const float* __restrict__ b2,
                          const float* __restrict__ ub1, const float* __restrict__ ub2,
                          float* __restrict__ B1f, float* __restrict__ B2f,
                          float* __restrict__ C1f, float* __restrict__ C2f) {
    int t = threadIdx.x;  // 128
    B1f[t] = b1[t]; B2f[t] = b2[t]; C1f[t] = ub1[t]; C2f[t] = ub2[t];
}

// fused BN-bias fold: 20 blocks x 32 k-rows; coalesced loads, LDS reduce, 1 atomic/col.
__global__ __launch_bounds__(256) void fold_all(
    const float* __restrict__ w1, const float* __restrict__ g1, const float* __restrict__ b1,
    const float* __restrict__ m1, const float* __restrict__ v1, float* __restrict__ B1f,
    const float* __restrict__ w2, const float* __restrict__ g2, const float* __restrict__ b2,
    const float* __restrict__ m2, const float* __restrict__ v2, float* __restrict__ B2f,
    const float* __restrict__ u1, const float* __restrict__ g3, const float* __restrict__ b3,
    const float* __restrict__ m3, const float* __restrict__ v3, float* __restrict__ C1f,
    const float* __restrict__ u2, const float* __restrict__ g4, const float* __restrict__ b4,
    const float* __restrict__ m4, const float* __restrict__ v4, float* __restrict__ C2f)
{
    const int rs = blockIdx.x * 32;
    const float *W, *g, *bb, *m, *v;
    float* bf;
    int k0;
    if (rs < 128)      { W = w1; g = g1; bb = b1; m = m1; v = v1; bf = B1f; k0 = rs; }
    else if (rs < 256) { W = w2; g = g2; bb = b2; m = m2; v = v2; bf = B2f; k0 = rs - 128; }
    else if (rs < 512) { W = u1; g = g3; bb = b3; m = m3; v = v3; bf = C1f; k0 = rs - 256; }
    else               { W = u2; g = g4; bb = b4; m = m4; v = v4; bf = C2f; k0 = rs - 512; }

    const int t = threadIdx.x, j = t & 127, h = t >> 7;
    float acc = 0.f;
    #pragma unroll
    for (int kk = 0; kk < 16; ++kk) {
        int k = k0 + h * 16 + kk;
        float s = g[k] * rsqrtf(v[k] + BN_EPS);
        float tt = bb[k] - m[k] * s;
        acc = fmaf(tt, W[k * DD + j], acc);
    }
    __shared__ float S[256];
    S[t] = acc;
    __syncthreads();
    if (h == 0) atomicAdd(&bf[j], S[j] + S[128 + j]);
}

#define YLD 136

// ---------------- prep kernel: per-NODE FFN_pre -> msgN bf16 [NN][128] ----------------
__global__ __launch_bounds__(512, 4) void prep_kernel(
    const float* __restrict__ reps,
    const ushort* __restrict__ W1h, const ushort* __restrict__ W1l, const float* __restrict__ B1,
    const ushort* __restrict__ W2h, const ushort* __restrict__ W2l, const float* __restrict__ B2,
    ushort* __restrict__ msgN)
{
    __shared__ ushort Yh[128 * YLD];
    const int t = threadIdx.x;
    const int w = t >> 6, l = t & 63, lg = l >> 4, lr = l & 15;
    const int n0 = blockIdx.x * 128;
    int n = n0 + w * 16 + lr;
    int nc = n < NN ? n : NN - 1;
    const float* src = reps + (size_t)nc * DD;

    float b1v[8], b2v[8];
    #pragma unroll
    for (int c = 0; c < 8; ++c) { b1v[c] = B1[c * 16 + lr]; b2v[c] = B2[c * 16 + lr]; }

    f32x4 acc[8];
    #pragma unroll
    for (int c = 0; c < 8; ++c) acc[c] = (f32x4)(0.f);

    // ---- layer 1 (A hi+lo, 3 MFMAs) ----
    #pragma unroll
    for (int s = 0; s < 4; ++s) {
        float4 x0 = *reinterpret_cast<const float4*>(src + s * 32 + lg * 8);
        float4 x1 = *reinterpret_cast<const float4*>(src + s * 32 + lg * 8 + 4);
        bf16x8 ah, al;
        cvt_hilo(x0, x1, ah, al);
        #pragma unroll
        for (int c = 0; c < 8; ++c) {
            bf16x8 bh = *reinterpret_cast<const bf16x8*>(W1h + (size_t)((c * 4 + s) * 64 + l) * 8);
            bf16x8 bl = *reinterpret_cast<const bf16x8*>(W1l + (size_t)((c * 4 + s) * 64 + l) * 8);
            acc[c] = MFMA16(al, bh, acc[c]);
            acc[c] = MFMA16(ah, bl, acc[c]);
            acc[c] = MFMA16(ah, bh, acc[c]);
        }
    }
    #pragma unroll
    for (int c = 0; c < 8; ++c) {
        #pragma unroll
        for (int i = 0; i < 4; ++i) {
            float yv = gelu_f(acc[c][i] + b1v[c]);
            Yh[(w * 16 + lg * 4 + i) * YLD + c * 16 + lr] = f2bf_rn(yv);
        }
    }

    // ---- layer 2 (A = bf16 Y from LDS; B hi/lo -> 2 MFMAs) ----
    #pragma unroll
    for (int c = 0; c < 8; ++c) acc[c] = (f32x4)(0.f);
    const ushort* yr = Yh + (w * 16 + lr) * YLD;
    #pragma unroll
    for (int s = 0; s < 4; ++s) {
        bf16x8 ah = *reinterpret_cast<const bf16x8*>(yr + s * 32 + lg * 8);
        #pragma unroll
        for (int c = 0; c < 8; ++c) {
            bf16x8 bh = *reinterpret_cast<const bf16x8*>(W2h + (size_t)((c * 4 + s) * 64 + l) * 8);
            bf16x8 bl = *reinterpret_cast<const bf16x8*>(W2l + (size_t)((c * 4 + s) * 64 + l) * 8);
            acc[c] = MFMA16(ah, bl, acc[c]);
            acc[c] = MFMA16(ah, bh, acc[c]);
        }
    }

    // ---- bias + GELU -> msgN bf16 ----
    const int nrow = n0 + w * 16 + lg * 4;
    #pragma unroll
    for (int i = 0; i < 4; ++i) {
        if (nrow + i < NN) {
            #pragma unroll
            for (int c = 0; c < 8; ++c)
                msgN[(size_t)(nrow + i) * DD + c * 16 + lr] = f2bf_rn(gelu_f(acc[c][i] + b2v[c]));
        }
    }
}

// ---------------- single-pass bucket build (replaces hist+scan+fill) ----------------
// bucket[dst][0..63] = edge ids; overflow -> spill list (correct for any distribution).
__global__ void fill_bucket(const int* __restrict__ edges,
                            int* __restrict__ cnt, int* __restrict__ spillCnt,
                            int* __restrict__ spill, int* __restrict__ bucket) {
    int e = blockIdx.x * 256 + threadIdx.x;
    if (e >= EE) return;
    int d = edges[e];
    int s = atomicAdd(&cnt[d], 1);
    if (s < 64) bucket[d * 64 + s] = e;
    else        spill[atomicAdd(spillCnt, 1)] = e;   // capacity EE: can't overflow
}

// ---------------- agg kernel: per-dst weighted sum of msgN rows (NO atomics) ----------
// 16 lanes per node; eid -> (nbr, ew) via L2-resident edges/ew arrays.
__global__ __launch_bounds__(256, 8) void agg_kernel(
    const int* __restrict__ bucket, const int* __restrict__ cnt,
    const int* __restrict__ edges, const float* __restrict__ ew,
    const ushort* __restrict__ msgN, ushort* __restrict__ aggb)
{
    const int t = threadIdx.x;
    const int node = blockIdx.x * 16 + (t >> 4);
    const int la = t & 15;
    int deg = cnt[node]; deg = deg < 64 ? deg : 64;
    const int* b = bucket + node * 64;
    const ushort* base = msgN + la * 8;

    float acc[8] = {0.f, 0.f, 0.f, 0.f, 0.f, 0.f, 0.f, 0.f};
    int k = 0;
    for (; k + 1 < deg; k += 2) {           // 2-way unroll for load ILP
        int e0 = b[k], e1 = b[k + 1];
        int n0 = edges[EE + e0], n1 = edges[EE + e1];
        float w0 = ew[e0], w1 = ew[e1];
        bf16x8 m0 = *reinterpret_cast<const bf16x8*>(base + (size_t)n0 * DD);
        bf16x8 m1 = *reinterpret_cast<const bf16x8*>(base + (size_t)n1 * DD);
        #pragma unroll
        for (int j = 0; j < 8; ++j) {
            acc[j] = fmaf(w0, bf2f((ushort)m0[j]), acc[j]);
            acc[j] = fmaf(w1, bf2f((ushort)m1[j]), acc[j]);
        }
    }
    if (k < deg) {
        int e0 = b[k];
        int n0 = edges[EE + e0];
        float w0 = ew[e0];
        bf16x8 m0 = *reinterpret_cast<const bf16x8*>(base + (size_t)n0 * DD);
        #pragma unroll
        for (int j = 0; j < 8; ++j) acc[j] = fmaf(w0, bf2f((ushort)m0[j]), acc[j]);
    }
    uint4 o;
    o.x = pk2(acc[0], acc[1]);
    o.y = pk2(acc[2], acc[3]);
    o.z = pk2(acc[4], acc[5]);
    o.w = pk2(acc[6], acc[7]);
    *reinterpret_cast<uint4*>(aggb + (size_t)node * DD + la * 8) = o;
}

// spill fold-in: one (edge, col-pair) per work item; pk-bf16 atomics. No-op if spillCnt==0.
__global__ void spill_add(const int* __restrict__ spillCnt, const int* __restrict__ spill,
                          const int* __restrict__ edges, const float* __restrict__ ew,
                          const ushort* __restrict__ msgN, ushort* __restrict__ aggb) {
    long total = (long)spillCnt[0] * 64;
    for (long i = (long)blockIdx.x * 256 + threadIdx.x; i < total; i += 64L * 256) {
        int sp = (int)(i >> 6), cp = (int)(i & 63);
        int eid = spill[sp];
        int dst = edges[eid], nbr = edges[EE + eid];
        float w = ew[eid];
        float m0 = bf2f(msgN[(size_t)nbr * DD + cp * 2]);
        float m1 = bf2f(msgN[(size_t)nbr * DD + cp * 2 + 1]);
        atomic_pk_add_bf16(aggb + (size_t)dst * DD + cp * 2, pk2(w * m0, w * m1));
    }
}

// ---------------- node kernel: concat -> MFMA FFN(2 layers) -> L2 normalize ----------
__global__ __launch_bounds__(256, 4) void node_kernel(
    const float* __restrict__ reps, const ushort* __restrict__ aggb,
    const ushort* __restrict__ U1h, const ushort* __restrict__ U1l, const float* __restrict__ C1,
    const ushort* __restrict__ U2h, const ushort* __restrict__ U2l, const float* __restrict__ C2,
    float* __restrict__ out)
{
    __shared__ ushort Yh[64 * YLD];
    const int t = threadIdx.x;
    const int w = t >> 6, l = t & 63, lg = l >> 4, lr = l & 15;
    const int n0 = blockIdx.x * 64;
    int n = n0 + w * 16 + lr;
    int nc = n < NN ? n : NN - 1;

    float c1v[8], c2v[8];
    #pragma unroll
    for (int c = 0; c < 8; ++c) { c1v[c] = C1[c * 16 + lr]; c2v[c] = C2[c * 16 + lr]; }

    f32x4 acc[8];
    #pragma unroll
    for (int c = 0; c < 8; ++c) acc[c] = (f32x4)(0.f);

    // ---- update layer 1, reps half (k=0..127): f32 A hi+lo, 3 MFMAs ----
    #pragma unroll
    for (int s = 0; s < 4; ++s) {
        const float* sp = reps + (size_t)nc * DD + s * 32 + lg * 8;
        float4 x0 = *reinterpret_cast<const float4*>(sp);
        float4 x1 = *reinterpret_cast<const float4*>(sp + 4);
        bf16x8 ah, al;
        cvt_hilo(x0, x1, ah, al);
        #pragma unroll
        for (int c = 0; c < 8; ++c) {
            bf16x8 bh = *reinterpret_cast<const bf16x8*>(U1h + (size_t)((c * 8 + s) * 64 + l) * 8);
            bf16x8 bl = *reinterpret_cast<const bf16x8*>(U1l + (size_t)((c * 8 + s) * 64 + l) * 8);
            acc[c] = MFMA16(al, bh, acc[c]);
            acc[c] = MFMA16(ah, bl, acc[c]);
            acc[c] = MFMA16(ah, bh, acc[c]);
        }
    }
    // ---- update layer 1, agg half (k=128..255): bf16 A direct, 2 MFMAs ----
    #pragma unroll
    for (int s = 4; s < 8; ++s) {
        bf16x8 ah = *reinterpret_cast<const bf16x8*>(aggb + (size_t)nc * DD + (s - 4) * 32 + lg * 8);
        #pragma unroll
        for (int c = 0; c < 8; ++c) {
            bf16x8 bh = *reinterpret_cast<const bf16x8*>(U1h + (size_t)((c * 8 + s) * 64 + l) * 8);
            bf16x8 bl = *reinterpret_cast<const bf16x8*>(U1l + (size_t)((c * 8 + s) * 64 + l) * 8);
            acc[c] = MFMA16(ah, bl, acc[c]);
            acc[c] = MFMA16(ah, bh, acc[c]);
        }
    }
    #pragma unroll
    for (int c = 0; c < 8; ++c) {
        #pragma unroll
        for (int i = 0; i < 4; ++i) {
            float yv = gelu_f(acc[c][i] + c1v[c]);
            Yh[(w * 16 + lg * 4 + i) * YLD + c * 16 + lr] = f2bf_rn(yv);
        }
    }

    // ---- update layer 2: K=128, A = bf16 Y from LDS, 2 MFMAs ----
    #pragma unroll
    for (int c = 0; c < 8; ++c) acc[c] = (f32x4)(0.f);
    const ushort* yr = Yh + (w * 16 + lr) * YLD;
    #pragma unroll
    for (int s = 0; s < 4; ++s) {
        bf16x8 ah = *reinterpret_cast<const bf16x8*>(yr + s * 32 + lg * 8);
        #pragma unroll
        for (int c = 0; c < 8; ++c) {
            bf16x8 bh = *reinterpret_cast<const bf16x8*>(U2h + (size_t)((c * 4 + s) * 64 + l) * 8);
            bf16x8 bl = *reinterpret_cast<const bf16x8*>(U2l + (size_t)((c * 4 + s) * 64 + l) * 8);
            acc[c] = MFMA16(ah, bl, acc[c]);
            acc[c] = MFMA16(ah, bh, acc[c]);
        }
    }

    // ---- bias + GELU + L2 normalize + store ----
    float ssq[4] = {0.f, 0.f, 0.f, 0.f};
    #pragma unroll
    for (int c = 0; c < 8; ++c) {
        #pragma unroll
        for (int i = 0; i < 4; ++i) {
            float vv = gelu_f(acc[c][i] + c2v[c]);
            acc[c][i] = vv;
            ssq[i] = fmaf(vv, vv, ssq[i]);
        }
    }
    #pragma unroll
    for (int i = 0; i < 4; ++i) {
        #pragma unroll
        for (int msk = 1; msk < 16; msk <<= 1) ssq[i] += __shfl_xor(ssq[i], msk);
        ssq[i] = rsqrtf(fmaxf(ssq[i], 1e-12f));
    }
    const int nrow = n0 + w * 16 + lg * 4;
    #pragma unroll
    for (int i = 0; i < 4; ++i) {
        if (nrow + i < NN) {
            #pragma unroll
            for (int c = 0; c < 8; ++c)
                out[(size_t)(nrow + i) * DD + c * 16 + lr] = acc[c][i] * ssq[i];
        }
    }
}

// ---------------- launch ----------------
extern "C" void kernel_launch(void* const* d_in, const int* in_sizes, int n_in,
                              void* d_out, int out_size, void* d_ws, size_t ws_size,
                              hipStream_t stream)
{
    const float* reps = (const float*)d_in[0];
    const int*   edges = (const int*)d_in[1];
    const float* ew   = (const float*)d_in[2];
    const float* bn1g = (const float*)d_in[3];
    const float* bn1b = (const float*)d_in[4];
    const float* bn1m = (const float*)d_in[5];
    const float* bn1v = (const float*)d_in[6];
    const float* w1   = (const float*)d_in[7];
    const float* b1   = (const float*)d_in[8];
    const float* bn2g = (const float*)d_in[9];
    const float* bn2b = (const float*)d_in[10];
    const float* bn2m = (const float*)d_in[11];
    const float* bn2v = (const float*)d_in[12];
    const float* w2   = (const float*)d_in[13];
    const float* b2   = (const float*)d_in[14];
    const float* ubn1g = (const float*)d_in[15];
    const float* ubn1b = (const float*)d_in[16];
    const float* ubn1m = (const float*)d_in[17];
    const float* ubn1v = (const float*)d_in[18];
    const float* u1    = (const float*)d_in[19];
    const float* ub1   = (const float*)d_in[20];
    const float* ubn2g = (const float*)d_in[21];
    const float* ubn2b = (const float*)d_in[22];
    const float* ubn2m = (const float*)d_in[23];
    const float* ubn2v = (const float*)d_in[24];
    const float* u2    = (const float*)d_in[25];
    const float* ub2   = (const float*)d_in[26];

    // workspace layout (bytes)
    char* wsb = (char*)d_ws;
    ushort* aggb     = (ushort*)wsb;                     // 12,800,000 B
    int*    cnt      = (int*)(wsb + 12800000);           // 200,000 B
    int*    spillCnt = (int*)(wsb + 13000000);           // 4 B (memset with cnt)
    int*    spill    = (int*)(wsb + 13000016);           // 3,200,000 B (capacity EE)
    float*  B1f      = (float*)(wsb + 16200016);         // 128 f32 each, 16B aligned
    float*  B2f = B1f + 128;
    float*  C1f = B2f + 128;
    float*  C2f = C1f + 128;
    ushort* up  = (ushort*)(C2f + 128);
    ushort* W1h = up;                                    // 16384 each
    ushort* W1l = W1h + 16384;
    ushort* W2h = W1l + 16384;
    ushort* W2l = W2h + 16384;
    ushort* U1h = W2l + 16384;                           // 32768 each
    ushort* U1l = U1h + 32768;
    ushort* U2h = U1l + 32768;                           // 16384 each
    ushort* U2l = U2h + 16384;
    if (ws_size < 16600000) return;

    // d_out double-duty (both regions dead before node_kernel overwrites d_out):
    //   [0, 12.8MB)    msgN bf16 [NN][128]
    //   [12.8, 25.6MB) bucket int [NN][64]
    ushort* msgN   = (ushort*)d_out;
    int*    bucket = (int*)((char*)d_out + 12800000);

    init_bias<<<1, 128, 0, stream>>>(b1, b2, ub1, ub2, B1f, B2f, C1f, C2f);
    pack_all<<<320, 256, 0, stream>>>(w1, bn1g, bn1v, W1h, W1l,
                                      w2, bn2g, bn2v, W2h, W2l,
                                      u1, ubn1g, ubn1v, U1h, U1l,
                                      u2, ubn2g, ubn2v, U2h, U2l);
    fold_all<<<20, 256, 0, stream>>>(w1, bn1g, bn1b, bn1m, bn1v, B1f,
                                     w2, bn2g, bn2b, bn2m, bn2v, B2f,
                                     u1, ubn1g, ubn1b, ubn1m, ubn1v, C1f,
                                     u2, ubn2g, ubn2b, ubn2m, ubn2v, C2f);

    (void)hipMemsetAsync(cnt, 0, 200016, stream);  // cnt + spillCnt

    prep_kernel<<<(NN + 127) / 128, 512, 0, stream>>>(reps, W1h, W1l, B1f,
                                                      W2h, W2l, B2f, msgN);
    fill_bucket<<<(EE + 255) / 256, 256, 0, stream>>>(edges, cnt, spillCnt, spill, bucket);
    agg_kernel<<<NN / 16, 256, 0, stream>>>(bucket, cnt, edges, ew, msgN, aggb);
    spill_add<<<64, 256, 0, stream>>>(spillCnt, spill, edges, ew, msgN, aggb);
    node_kernel<<<(NN + 63) / 64, 256, 0, stream>>>(reps, aggb, U1h, U1l, C1f,
                                                    U2h, U2l, C2f, (float*)d_out);
}

// Round 15
// 179.825 us; speedup vs baseline: 3.6100x; 1.1010x over previous
//
#include <hip/hip_runtime.h>
#include <hip/hip_bf16.h>
#include <math.h>

#define NN 50000
#define DD 128
#define EE 800000

static constexpr float BN_EPS = 1e-3f;

typedef __attribute__((ext_vector_type(8))) short bf16x8;
typedef __attribute__((ext_vector_type(4))) float f32x4;

#define MFMA16(a, b, c) __builtin_amdgcn_mfma_f32_16x16x32_bf16((a), (b), (c), 0, 0, 0)

// fast exact-grade GELU: Abramowitz-Stegun 7.1.26 erf (abs err 1.5e-7)
__device__ __forceinline__ float gelu_f(float x) {
    float ax = fabsf(x) * 0.7071067811865475f;
    float t = __builtin_amdgcn_rcpf(fmaf(0.3275911f, ax, 1.0f));
    float p = t * fmaf(t, fmaf(t, fmaf(t, fmaf(t, 1.061405429f, -1.453152027f),
                                       1.421413741f), -0.284496736f), 0.254829592f);
    float e = __expf(-ax * ax);
    float er = fmaf(-p, e, 1.0f);        // erf(|x|/sqrt2) for ax>=0
    float s = copysignf(er, x);
    return 0.5f * x * (1.0f + s);
}

__device__ __forceinline__ ushort f2bf_rn(float f) {
    uint u = __float_as_uint(f);
    return (ushort)((u + 0x7FFFu + ((u >> 16) & 1u)) >> 16);
}
__device__ __forceinline__ float bf2f(ushort h) {
    return __uint_as_float(((uint)h) << 16);
}

// packed pair f32->bf16 RNE (compiler emits v_cvt_pk_bf16_f32); low16=a, high16=b
__device__ __forceinline__ uint pk2(float a, float b) {
    __hip_bfloat162 t = __float22bfloat162_rn(make_float2(a, b));
    uint r;
    __builtin_memcpy(&r, &t, 4);
    return r;
}

// packed bf16 atomic add (2 cols per op) — spill path only
__device__ __forceinline__ void atomic_pk_add_bf16(ushort* addr, uint val) {
    asm volatile("global_atomic_pk_add_bf16 %0, %1, off"
                 :: "v"((void*)addr), "v"(val) : "memory");
}

// split f32x8 -> bf16 hi + bf16 lo fragments (f ~= hi + lo, |resid| ~ 2^-17|f|)
__device__ __forceinline__ void cvt_hilo(float4 x0, float4 x1, bf16x8& h, bf16x8& l) {
    float f[8] = {x0.x, x0.y, x0.z, x0.w, x1.x, x1.y, x1.z, x1.w};
    union U { uint u[4]; bf16x8 v; } uh, ul;
    #pragma unroll
    for (int j = 0; j < 4; ++j) {
        uint p = pk2(f[2 * j], f[2 * j + 1]);
        uh.u[j] = p;
        float h0 = __uint_as_float(p << 16);
        float h1 = __uint_as_float(p & 0xFFFF0000u);
        ul.u[j] = pk2(f[2 * j] - h0, f[2 * j + 1] - h1);
    }
    h = uh.v;
    l = ul.v;
}

// ---------------- fused weight-prep kernels ----------------
__device__ __forceinline__ void pack_one(const float* __restrict__ W, const float* __restrict__ g,
                                         const float* __restrict__ v, ushort* __restrict__ hi,
                                         ushort* __restrict__ lo, int K, int idx) {
    int k = idx >> 7, col = idx & 127;
    float s = g[k] * rsqrtf(v[k] + BN_EPS);
    float f = s * W[idx];
    int S = K >> 5;
    int st = k >> 5, gq = (k >> 3) & 3, j = k & 7;
    int c = col >> 4, ln = (gq << 4) | (col & 15);
    int o = ((c * S + st) * 64 + ln) * 8 + j;
    ushort hb = f2bf_rn(f);
    hi[o] = hb;
    lo[o] = f2bf_rn(f - bf2f(hb));
}

__global__ void pack_all(
    const float* __restrict__ w1, const float* __restrict__ g1, const float* __restrict__ v1,
    ushort* __restrict__ W1h, ushort* __restrict__ W1l,
    const float* __restrict__ w2, const float* __restrict__ g2, const float* __restrict__ v2,
    ushort* __restrict__ W2h, ushort* __restrict__ W2l,
    const float* __restrict__ u1, const float* __restrict__ g3, const float* __restrict__ v3,
    ushort* __restrict__ U1h, ushort* __restrict__ U1l,
    const float* __restrict__ u2, const float* __restrict__ g4, const float* __restrict__ v4,
    ushort* __restrict__ U2h, ushort* __restrict__ U2l)
{
    int idx = blockIdx.x * 256 + threadIdx.x;       // 0..81919
    if (idx < 16384)       pack_one(w1, g1, v1, W1h, W1l, 128, idx);
    else if (idx < 32768)  pack_one(w2, g2, v2, W2h, W2l, 128, idx - 16384);
    else if (idx < 65536)  pack_one(u1, g3, v3, U1h, U1l, 256, idx - 32768);
    else                   pack_one(u2, g4, v4, U2h, U2l, 128, idx - 65536);
}

__global__ void init_bias(const float* __restrict__ b1, const float* __restrict__ b2,
                          const float* __restrict__ ub1, const float* __restrict__ ub2,
                          float* __restrict__ B1f, float* __restrict__ B2f,
                          float* __restrict__ C1f, float* __restrict__ C2f) {
    int t = threadIdx.x;  // 128
    B1f[t] = b1[t]; B2f[t] = b2[t]; C1f[t] = ub1[t]; C2f[t] = ub2[t];
}

// fused BN-bias fold: 20 blocks x 32 k-rows; coalesced loads, LDS reduce, 1 atomic/col.
__global__ __launch_bounds__(256) void fold_all(
    const float* __restrict__ w1, const float* __restrict__ g1, const float* __restrict__ b1,
    const float* __restrict__ m1, const float* __restrict__ v1, float* __restrict__ B1f,
    const float* __restrict__ w2, const float* __restrict__ g2, const float* __restrict__ b2,
    const float* __restrict__ m2, const float* __restrict__ v2, float* __restrict__ B2f,
    const float* __restrict__ u1, const float* __restrict__ g3, const float* __restrict__ b3,
    const float* __restrict__ m3, const float* __restrict__ v3, float* __restrict__ C1f,
    const float* __restrict__ u2, const float* __restrict__ g4, const float* __restrict__ b4,
    const float* __restrict__ m4, const float* __restrict__ v4, float* __restrict__ C2f)
{
    const int rs = blockIdx.x * 32;
    const float *W, *g, *bb, *m, *v;
    float* bf;
    int k0;
    if (rs < 128)      { W = w1; g = g1; bb = b1; m = m1; v = v1; bf = B1f; k0 = rs; }
    else if (rs < 256) { W = w2; g = g2; bb = b2; m = m2; v = v2; bf = B2f; k0 = rs - 128; }
    else if (rs < 512) { W = u1; g = g3; bb = b3; m = m3; v = v3; bf = C1f; k0 = rs - 256; }
    else               { W = u2; g = g4; bb = b4; m = m4; v = v4; bf = C2f; k0 = rs - 512; }

    const int t = threadIdx.x, j = t & 127, h = t >> 7;
    float acc = 0.f;
    #pragma unroll
    for (int kk = 0; kk < 16; ++kk) {
        int k = k0 + h * 16 + kk;
        float s = g[k] * rsqrtf(v[k] + BN_EPS);
        float tt = bb[k] - m[k] * s;
        acc = fmaf(tt, W[k * DD + j], acc);
    }
    __shared__ float S[256];
    S[t] = acc;
    __syncthreads();
    if (h == 0) atomicAdd(&bf[j], S[j] + S[128 + j]);
}

#define YLD 136

// ---------------- prep kernel: per-NODE FFN_pre -> msgN bf16 [NN][128] ----------------
__global__ __launch_bounds__(512, 4) void prep_kernel(
    const float* __restrict__ reps,
    const ushort* __restrict__ W1h, const ushort* __restrict__ W1l, const float* __restrict__ B1,
    const ushort* __restrict__ W2h, const ushort* __restrict__ W2l, const float* __restrict__ B2,
    ushort* __restrict__ msgN)
{
    __shared__ ushort Yh[128 * YLD];
    const int t = threadIdx.x;
    const int w = t >> 6, l = t & 63, lg = l >> 4, lr = l & 15;
    const int n0 = blockIdx.x * 128;
    int n = n0 + w * 16 + lr;
    int nc = n < NN ? n : NN - 1;
    const float* src = reps + (size_t)nc * DD;

    float b1v[8], b2v[8];
    #pragma unroll
    for (int c = 0; c < 8; ++c) { b1v[c] = B1[c * 16 + lr]; b2v[c] = B2[c * 16 + lr]; }

    f32x4 acc[8];
    #pragma unroll
    for (int c = 0; c < 8; ++c) acc[c] = (f32x4)(0.f);

    // ---- layer 1 (A hi+lo, 3 MFMAs) ----
    #pragma unroll
    for (int s = 0; s < 4; ++s) {
        float4 x0 = *reinterpret_cast<const float4*>(src + s * 32 + lg * 8);
        float4 x1 = *reinterpret_cast<const float4*>(src + s * 32 + lg * 8 + 4);
        bf16x8 ah, al;
        cvt_hilo(x0, x1, ah, al);
        #pragma unroll
        for (int c = 0; c < 8; ++c) {
            bf16x8 bh = *reinterpret_cast<const bf16x8*>(W1h + (size_t)((c * 4 + s) * 64 + l) * 8);
            bf16x8 bl = *reinterpret_cast<const bf16x8*>(W1l + (size_t)((c * 4 + s) * 64 + l) * 8);
            acc[c] = MFMA16(al, bh, acc[c]);
            acc[c] = MFMA16(ah, bl, acc[c]);
            acc[c] = MFMA16(ah, bh, acc[c]);
        }
    }
    #pragma unroll
    for (int c = 0; c < 8; ++c) {
        #pragma unroll
        for (int i = 0; i < 4; ++i) {
            float yv = gelu_f(acc[c][i] + b1v[c]);
            Yh[(w * 16 + lg * 4 + i) * YLD + c * 16 + lr] = f2bf_rn(yv);
        }
    }

    // ---- layer 2 (A = bf16 Y from LDS; B hi/lo -> 2 MFMAs) ----
    #pragma unroll
    for (int c = 0; c < 8; ++c) acc[c] = (f32x4)(0.f);
    const ushort* yr = Yh + (w * 16 + lr) * YLD;
    #pragma unroll
    for (int s = 0; s < 4; ++s) {
        bf16x8 ah = *reinterpret_cast<const bf16x8*>(yr + s * 32 + lg * 8);
        #pragma unroll
        for (int c = 0; c < 8; ++c) {
            bf16x8 bh = *reinterpret_cast<const bf16x8*>(W2h + (size_t)((c * 4 + s) * 64 + l) * 8);
            bf16x8 bl = *reinterpret_cast<const bf16x8*>(W2l + (size_t)((c * 4 + s) * 64 + l) * 8);
            acc[c] = MFMA16(ah, bl, acc[c]);
            acc[c] = MFMA16(ah, bh, acc[c]);
        }
    }

    // ---- bias + GELU -> msgN bf16 ----
    const int nrow = n0 + w * 16 + lg * 4;
    #pragma unroll
    for (int i = 0; i < 4; ++i) {
        if (nrow + i < NN) {
            #pragma unroll
            for (int c = 0; c < 8; ++c)
                msgN[(size_t)(nrow + i) * DD + c * 16 + lr] = f2bf_rn(gelu_f(acc[c][i] + b2v[c]));
        }
    }
}

// ---------------- single-pass bucket build, dst-partitioned for XCD L2 affinity -------
// 8 dst-partitions x 6250 nodes (bucket slice 1.6 MB << 4 MB per-XCD L2). Block b handles
// edge chunk b>>3, writes only dsts in partition b&7; round-robin dispatch puts all blocks
// of one partition on one XCD -> bucket lines accumulate in that L2, single writeback.
// Correct under ANY block->XCD mapping (filter is explicit); only speed rides the heuristic.
#define NCHUNK 400
#define CHSZ (EE / NCHUNK)   // 2000
#define PSZ 6250             // NN / 8

__global__ __launch_bounds__(256) void fill_bucket(const int* __restrict__ edges,
                                                   int* __restrict__ cnt,
                                                   int* __restrict__ spillCnt,
                                                   int* __restrict__ spill,
                                                   int* __restrict__ bucket) {
    const int part = blockIdx.x & 7;
    const int ch   = blockIdx.x >> 3;
    const int lo = part * PSZ, hi = lo + PSZ;
    const int base = ch * CHSZ;
    for (int i = threadIdx.x; i < CHSZ; i += 256) {
        int e = base + i;
        int d = edges[e];
        if (d >= lo && d < hi) {
            int s = atomicAdd(&cnt[d], 1);
            if (s < 64) bucket[d * 64 + s] = e;
            else        spill[atomicAdd(spillCnt, 1)] = e;   // capacity EE: can't overflow
        }
    }
}

// ---------------- agg kernel: per-dst weighted sum of msgN rows (NO atomics) ----------
__global__ __launch_bounds__(256, 8) void agg_kernel(
    const int* __restrict__ bucket, const int* __restrict__ cnt,
    const int* __restrict__ edges, const float* __restrict__ ew,
    const ushort* __restrict__ msgN, ushort* __restrict__ aggb)
{
    const int t = threadIdx.x;
    const int node = blockIdx.x * 16 + (t >> 4);
    const int la = t & 15;
    int deg = cnt[node]; deg = deg < 64 ? deg : 64;
    const int* b = bucket + node * 64;
    const ushort* base = msgN + la * 8;

    float acc[8] = {0.f, 0.f, 0.f, 0.f, 0.f, 0.f, 0.f, 0.f};
    int k = 0;
    for (; k + 1 < deg; k += 2) {           // 2-way unroll for load ILP
        int e0 = b[k], e1 = b[k + 1];
        int n0 = edges[EE + e0], n1 = edges[EE + e1];
        float w0 = ew[e0], w1 = ew[e1];
        bf16x8 m0 = *reinterpret_cast<const bf16x8*>(base + (size_t)n0 * DD);
        bf16x8 m1 = *reinterpret_cast<const bf16x8*>(base + (size_t)n1 * DD);
        #pragma unroll
        for (int j = 0; j < 8; ++j) {
            acc[j] = fmaf(w0, bf2f((ushort)m0[j]), acc[j]);
            acc[j] = fmaf(w1, bf2f((ushort)m1[j]), acc[j]);
        }
    }
    if (k < deg) {
        int e0 = b[k];
        int n0 = edges[EE + e0];
        float w0 = ew[e0];
        bf16x8 m0 = *reinterpret_cast<const bf16x8*>(base + (size_t)n0 * DD);
        #pragma unroll
        for (int j = 0; j < 8; ++j) acc[j] = fmaf(w0, bf2f((ushort)m0[j]), acc[j]);
    }
    uint4 o;
    o.x = pk2(acc[0], acc[1]);
    o.y = pk2(acc[2], acc[3]);
    o.z = pk2(acc[4], acc[5]);
    o.w = pk2(acc[6], acc[7]);
    *reinterpret_cast<uint4*>(aggb + (size_t)node * DD + la * 8) = o;
}

// spill fold-in: one (edge, col-pair) per work item; pk-bf16 atomics. No-op if spillCnt==0.
__global__ void spill_add(const int* __restrict__ spillCnt, const int* __restrict__ spill,
                          const int* __restrict__ edges, const float* __restrict__ ew,
                          const ushort* __restrict__ msgN, ushort* __restrict__ aggb) {
    long total = (long)spillCnt[0] * 64;
    for (long i = (long)blockIdx.x * 256 + threadIdx.x; i < total; i += 64L * 256) {
        int sp = (int)(i >> 6), cp = (int)(i & 63);
        int eid = spill[sp];
        int dst = edges[eid], nbr = edges[EE + eid];
        float w = ew[eid];
        float m0 = bf2f(msgN[(size_t)nbr * DD + cp * 2]);
        float m1 = bf2f(msgN[(size_t)nbr * DD + cp * 2 + 1]);
        atomic_pk_add_bf16(aggb + (size_t)dst * DD + cp * 2, pk2(w * m0, w * m1));
    }
}

// ---------------- node kernel: concat -> MFMA FFN(2 layers) -> L2 normalize ----------
__global__ __launch_bounds__(256, 4) void node_kernel(
    const float* __restrict__ reps, const ushort* __restrict__ aggb,
    const ushort* __restrict__ U1h, const ushort* __restrict__ U1l, const float* __restrict__ C1,
    const ushort* __restrict__ U2h, const ushort* __restrict__ U2l, const float* __restrict__ C2,
    float* __restrict__ out)
{
    __shared__ ushort Yh[64 * YLD];
    const int t = threadIdx.x;
    const int w = t >> 6, l = t & 63, lg = l >> 4, lr = l & 15;
    const int n0 = blockIdx.x * 64;
    int n = n0 + w * 16 + lr;
    int nc = n < NN ? n : NN - 1;

    float c1v[8], c2v[8];
    #pragma unroll
    for (int c = 0; c < 8; ++c) { c1v[c] = C1[c * 16 + lr]; c2v[c] = C2[c * 16 + lr]; }

    f32x4 acc[8];
    #pragma unroll
    for (int c = 0; c < 8; ++c) acc[c] = (f32x4)(0.f);

    // ---- update layer 1, reps half (k=0..127): f32 A hi+lo, 3 MFMAs ----
    #pragma unroll
    for (int s = 0; s < 4; ++s) {
        const float* sp = reps + (size_t)nc * DD + s * 32 + lg * 8;
        float4 x0 = *reinterpret_cast<const float4*>(sp);
        float4 x1 = *reinterpret_cast<const float4*>(sp + 4);
        bf16x8 ah, al;
        cvt_hilo(x0, x1, ah, al);
        #pragma unroll
        for (int c = 0; c < 8; ++c) {
            bf16x8 bh = *reinterpret_cast<const bf16x8*>(U1h + (size_t)((c * 8 + s) * 64 + l) * 8);
            bf16x8 bl = *reinterpret_cast<const bf16x8*>(U1l + (size_t)((c * 8 + s) * 64 + l) * 8);
            acc[c] = MFMA16(al, bh, acc[c]);
            acc[c] = MFMA16(ah, bl, acc[c]);
            acc[c] = MFMA16(ah, bh, acc[c]);
        }
    }
    // ---- update layer 1, agg half (k=128..255): bf16 A direct, 2 MFMAs ----
    #pragma unroll
    for (int s = 4; s < 8; ++s) {
        bf16x8 ah = *reinterpret_cast<const bf16x8*>(aggb + (size_t)nc * DD + (s - 4) * 32 + lg * 8);
        #pragma unroll
        for (int c = 0; c < 8; ++c) {
            bf16x8 bh = *reinterpret_cast<const bf16x8*>(U1h + (size_t)((c * 8 + s) * 64 + l) * 8);
            bf16x8 bl = *reinterpret_cast<const bf16x8*>(U1l + (size_t)((c * 8 + s) * 64 + l) * 8);
            acc[c] = MFMA16(ah, bl, acc[c]);
            acc[c] = MFMA16(ah, bh, acc[c]);
        }
    }
    #pragma unroll
    for (int c = 0; c < 8; ++c) {
        #pragma unroll
        for (int i = 0; i < 4; ++i) {
            float yv = gelu_f(acc[c][i] + c1v[c]);
            Yh[(w * 16 + lg * 4 + i) * YLD + c * 16 + lr] = f2bf_rn(yv);
        }
    }

    // ---- update layer 2: K=128, A = bf16 Y from LDS, 2 MFMAs ----
    #pragma unroll
    for (int c = 0; c < 8; ++c) acc[c] = (f32x4)(0.f);
    const ushort* yr = Yh + (w * 16 + lr) * YLD;
    #pragma unroll
    for (int s = 0; s < 4; ++s) {
        bf16x8 ah = *reinterpret_cast<const bf16x8*>(yr + s * 32 + lg * 8);
        #pragma unroll
        for (int c = 0; c < 8; ++c) {
            bf16x8 bh = *reinterpret_cast<const bf16x8*>(U2h + (size_t)((c * 4 + s) * 64 + l) * 8);
            bf16x8 bl = *reinterpret_cast<const bf16x8*>(U2l + (size_t)((c * 4 + s) * 64 + l) * 8);
            acc[c] = MFMA16(ah, bl, acc[c]);
            acc[c] = MFMA16(ah, bh, acc[c]);
        }
    }

    // ---- bias + GELU + L2 normalize + store ----
    float ssq[4] = {0.f, 0.f, 0.f, 0.f};
    #pragma unroll
    for (int c = 0; c < 8; ++c) {
        #pragma unroll
        for (int i = 0; i < 4; ++i) {
            float vv = gelu_f(acc[c][i] + c2v[c]);
            acc[c][i] = vv;
            ssq[i] = fmaf(vv, vv, ssq[i]);
        }
    }
    #pragma unroll
    for (int i = 0; i < 4; ++i) {
        #pragma unroll
        for (int msk = 1; msk < 16; msk <<= 1) ssq[i] += __shfl_xor(ssq[i], msk);
        ssq[i] = rsqrtf(fmaxf(ssq[i], 1e-12f));
    }
    const int nrow = n0 + w * 16 + lg * 4;
    #pragma unroll
    for (int i = 0; i < 4; ++i) {
        if (nrow + i < NN) {
            #pragma unroll
            for (int c = 0; c < 8; ++c)
                out[(size_t)(nrow + i) * DD + c * 16 + lr] = acc[c][i] * ssq[i];
        }
    }
}

// ---------------- launch ----------------
extern "C" void kernel_launch(void* const* d_in, const int* in_sizes, int n_in,
                              void* d_out, int out_size, void* d_ws, size_t ws_size,
                              hipStream_t stream)
{
    const float* reps = (const float*)d_in[0];
    const int*   edges = (const int*)d_in[1];
    const float* ew   = (const float*)d_in[2];
    const float* bn1g = (const float*)d_in[3];
    const float* bn1b = (const float*)d_in[4];
    const float* bn1m = (const float*)d_in[5];
    const float* bn1v = (const float*)d_in[6];
    const float* w1   = (const float*)d_in[7];
    const float* b1   = (const float*)d_in[8];
    const float* bn2g = (const float*)d_in[9];
    const float* bn2b = (const float*)d_in[10];
    const float* bn2m = (const float*)d_in[11];
    const float* bn2v = (const float*)d_in[12];
    const float* w2   = (const float*)d_in[13];
    const float* b2   = (const float*)d_in[14];
    const float* ubn1g = (const float*)d_in[15];
    const float* ubn1b = (const float*)d_in[16];
    const float* ubn1m = (const float*)d_in[17];
    const float* ubn1v = (const float*)d_in[18];
    const float* u1    = (const float*)d_in[19];
    const float* ub1   = (const float*)d_in[20];
    const float* ubn2g = (const float*)d_in[21];
    const float* ubn2b = (const float*)d_in[22];
    const float* ubn2m = (const float*)d_in[23];
    const float* ubn2v = (const float*)d_in[24];
    const float* u2    = (const float*)d_in[25];
    const float* ub2   = (const float*)d_in[26];

    // workspace layout (bytes)
    char* wsb = (char*)d_ws;
    ushort* aggb     = (ushort*)wsb;                     // 12,800,000 B
    int*    cnt      = (int*)(wsb + 12800000);           // 200,000 B
    int*    spillCnt = (int*)(wsb + 13000000);           // 4 B (memset with cnt)
    int*    spill    = (int*)(wsb + 13000016);           // 3,200,000 B (capacity EE)
    float*  B1f      = (float*)(wsb + 16200016);         // 128 f32 each, 16B aligned
    float*  B2f = B1f + 128;
    float*  C1f = B2f + 128;
    float*  C2f = C1f + 128;
    ushort* up  = (ushort*)(C2f + 128);
    ushort* W1h = up;                                    // 16384 each
    ushort* W1l = W1h + 16384;
    ushort* W2h = W1l + 16384;
    ushort* W2l = W2h + 16384;
    ushort* U1h = W2l + 16384;                           // 32768 each
    ushort* U1l = U1h + 32768;
    ushort* U2h = U1l + 32768;                           // 16384 each
    ushort* U2l = U2h + 16384;
    if (ws_size < 16600000) return;

    // d_out double-duty (both regions dead before node_kernel overwrites d_out):
    //   [0, 12.8MB)    msgN bf16 [NN][128]
    //   [12.8, 25.6MB) bucket int [NN][64]
    ushort* msgN   = (ushort*)d_out;
    int*    bucket = (int*)((char*)d_out + 12800000);

    init_bias<<<1, 128, 0, stream>>>(b1, b2, ub1, ub2, B1f, B2f, C1f, C2f);
    pack_all<<<320, 256, 0, stream>>>(w1, bn1g, bn1v, W1h, W1l,
                                      w2, bn2g, bn2v, W2h, W2l,
                                      u1, ubn1g, ubn1v, U1h, U1l,
                                      u2, ubn2g, ubn2v, U2h, U2l);
    fold_all<<<20, 256, 0, stream>>>(w1, bn1g, bn1b, bn1m, bn1v, B1f,
                                     w2, bn2g, bn2b, bn2m, bn2v, B2f,
                                     u1, ubn1g, ubn1b, ubn1m, ubn1v, C1f,
                                     u2, ubn2g, ubn2b, ubn2m, ubn2v, C2f);

    (void)hipMemsetAsync(cnt, 0, 200016, stream);  // cnt + spillCnt

    prep_kernel<<<(NN + 127) / 128, 512, 0, stream>>>(reps, W1h, W1l, B1f,
                                                      W2h, W2l, B2f, msgN);
    fill_bucket<<<NCHUNK * 8, 256, 0, stream>>>(edges, cnt, spillCnt, spill, bucket);
    agg_kernel<<<NN / 16, 256, 0, stream>>>(bucket, cnt, edges, ew, msgN, aggb);
    spill_add<<<64, 256, 0, stream>>>(spillCnt, spill, edges, ew, msgN, aggb);
    node_kernel<<<(NN + 63) / 64, 256, 0, stream>>>(reps, aggb, U1h, U1l, C1f,
                                                    U2h, U2l, C2f, (float*)d_out);
}

// Round 16
// 178.373 us; speedup vs baseline: 3.6394x; 1.0081x over previous
//
#include <hip/hip_runtime.h>
#include <hip/hip_bf16.h>
#include <math.h>

#define NN 50000
#define DD 128
#define EE 800000

static constexpr float BN_EPS = 1e-3f;

typedef __attribute__((ext_vector_type(8))) short bf16x8;
typedef __attribute__((ext_vector_type(4))) float f32x4;

#define MFMA16(a, b, c) __builtin_amdgcn_mfma_f32_16x16x32_bf16((a), (b), (c), 0, 0, 0)

// fast exact-grade GELU: Abramowitz-Stegun 7.1.26 erf (abs err 1.5e-7)
__device__ __forceinline__ float gelu_f(float x) {
    float ax = fabsf(x) * 0.7071067811865475f;
    float t = __builtin_amdgcn_rcpf(fmaf(0.3275911f, ax, 1.0f));
    float p = t * fmaf(t, fmaf(t, fmaf(t, fmaf(t, 1.061405429f, -1.453152027f),
                                       1.421413741f), -0.284496736f), 0.254829592f);
    float e = __expf(-ax * ax);
    float er = fmaf(-p, e, 1.0f);        // erf(|x|/sqrt2) for ax>=0
    float s = copysignf(er, x);
    return 0.5f * x * (1.0f + s);
}

__device__ __forceinline__ ushort f2bf_rn(float f) {
    uint u = __float_as_uint(f);
    return (ushort)((u + 0x7FFFu + ((u >> 16) & 1u)) >> 16);
}
__device__ __forceinline__ float bf2f(ushort h) {
    return __uint_as_float(((uint)h) << 16);
}

// packed pair f32->bf16 RNE (compiler emits v_cvt_pk_bf16_f32); low16=a, high16=b
__device__ __forceinline__ uint pk2(float a, float b) {
    __hip_bfloat162 t = __float22bfloat162_rn(make_float2(a, b));
    uint r;
    __builtin_memcpy(&r, &t, 4);
    return r;
}

// packed bf16 atomic add (2 cols per op) — spill path only
__device__ __forceinline__ void atomic_pk_add_bf16(ushort* addr, uint val) {
    asm volatile("global_atomic_pk_add_bf16 %0, %1, off"
                 :: "v"((void*)addr), "v"(val) : "memory");
}

// split f32x8 -> bf16 hi + bf16 lo fragments (f ~= hi + lo, |resid| ~ 2^-17|f|)
__device__ __forceinline__ void cvt_hilo(float4 x0, float4 x1, bf16x8& h, bf16x8& l) {
    float f[8] = {x0.x, x0.y, x0.z, x0.w, x1.x, x1.y, x1.z, x1.w};
    union U { uint u[4]; bf16x8 v; } uh, ul;
    #pragma unroll
    for (int j = 0; j < 4; ++j) {
        uint p = pk2(f[2 * j], f[2 * j + 1]);
        uh.u[j] = p;
        float h0 = __uint_as_float(p << 16);
        float h1 = __uint_as_float(p & 0xFFFF0000u);
        ul.u[j] = pk2(f[2 * j] - h0, f[2 * j + 1] - h1);
    }
    h = uh.v;
    l = ul.v;
}

// ---------------- fused weight-prep kernels ----------------
__device__ __forceinline__ void pack_one(const float* __restrict__ W, const float* __restrict__ g,
                                         const float* __restrict__ v, ushort* __restrict__ hi,
                                         ushort* __restrict__ lo, int K, int idx) {
    int k = idx >> 7, col = idx & 127;
    float s = g[k] * rsqrtf(v[k] + BN_EPS);
    float f = s * W[idx];
    int S = K >> 5;
    int st = k >> 5, gq = (k >> 3) & 3, j = k & 7;
    int c = col >> 4, ln = (gq << 4) | (col & 15);
    int o = ((c * S + st) * 64 + ln) * 8 + j;
    ushort hb = f2bf_rn(f);
    hi[o] = hb;
    lo[o] = f2bf_rn(f - bf2f(hb));
}

__global__ void pack_all(
    const float* __restrict__ w1, const float* __restrict__ g1, const float* __restrict__ v1,
    ushort* __restrict__ W1h, ushort* __restrict__ W1l,
    const float* __restrict__ w2, const float* __restrict__ g2, const float* __restrict__ v2,
    ushort* __restrict__ W2h, ushort* __restrict__ W2l,
    const float* __restrict__ u1, const float* __restrict__ g3, const float* __restrict__ v3,
    ushort* __restrict__ U1h, ushort* __restrict__ U1l,
    const float* __restrict__ u2, const float* __restrict__ g4, const float* __restrict__ v4,
    ushort* __restrict__ U2h, ushort* __restrict__ U2l)
{
    int idx = blockIdx.x * 256 + threadIdx.x;       // 0..81919
    if (idx < 16384)       pack_one(w1, g1, v1, W1h, W1l, 128, idx);
    else if (idx < 32768)  pack_one(w2, g2, v2, W2h, W2l, 128, idx - 16384);
    else if (idx < 65536)  pack_one(u1, g3, v3, U1h, U1l, 256, idx - 32768);
    else                   pack_one(u2, g4, v4, U2h, U2l, 128, idx - 65536);
}

__global__ void init_bias(const float* __restrict__ b1, const float* __restrict__ b2,
                          const float* __restrict__ ub1, const float* __restrict__ ub2,
                          float* __restrict__ B1f, float* __restrict__ B2f,
                          float* __restrict__ C1f, float* __restrict__ C2f) {
    int t = threadIdx.x;  // 128
    B1f[t] = b1[t]; B2f[t] = b2[t]; C1f[t] = ub1[t]; C2f[t] = ub2[t];
}

// fused BN-bias fold: 20 blocks x 32 k-rows; coalesced loads, LDS reduce, 1 atomic/col.
__global__ __launch_bounds__(256) void fold_all(
    const float* __restrict__ w1, const float* __restrict__ g1, const float* __restrict__ b1,
    const float* __restrict__ m1, const float* __restrict__ v1, float* __restrict__ B1f,
    const float* __restrict__ w2, const float* __restrict__ g2, const float* __restrict__ b2,
    const float* __restrict__ m2, const float* __restrict__ v2, float* __restrict__ B2f,
    const float* __restrict__ u1, const float* __restrict__ g3, const float* __restrict__ b3,
    const float* __restrict__ m3, const float* __restrict__ v3, float* __restrict__ C1f,
    const float* __restrict__ u2, const float* __restrict__ g4, const float* __restrict__ b4,
    const float* __restrict__ m4, const float* __restrict__ v4, float* __restrict__ C2f)
{
    const int rs = blockIdx.x * 32;
    const float *W, *g, *bb, *m, *v;
    float* bf;
    int k0;
    if (rs < 128)      { W = w1; g = g1; bb = b1; m = m1; v = v1; bf = B1f; k0 = rs; }
    else if (rs < 256) { W = w2; g = g2; bb = b2; m = m2; v = v2; bf = B2f; k0 = rs - 128; }
    else if (rs < 512) { W = u1; g = g3; bb = b3; m = m3; v = v3; bf = C1f; k0 = rs - 256; }
    else               { W = u2; g = g4; bb = b4; m = m4; v = v4; bf = C2f; k0 = rs - 512; }

    const int t = threadIdx.x, j = t & 127, h = t >> 7;
    float acc = 0.f;
    #pragma unroll
    for (int kk = 0; kk < 16; ++kk) {
        int k = k0 + h * 16 + kk;
        float s = g[k] * rsqrtf(v[k] + BN_EPS);
        float tt = bb[k] - m[k] * s;
        acc = fmaf(tt, W[k * DD + j], acc);
    }
    __shared__ float S[256];
    S[t] = acc;
    __syncthreads();
    if (h == 0) atomicAdd(&bf[j], S[j] + S[128 + j]);
}

#define YLD 136

// ---------------- prep kernel: per-NODE FFN_pre -> msgN bf16 [NN][128] ----------------
__global__ __launch_bounds__(512, 4) void prep_kernel(
    const float* __restrict__ reps,
    const ushort* __restrict__ W1h, const ushort* __restrict__ W1l, const float* __restrict__ B1,
    const ushort* __restrict__ W2h, const ushort* __restrict__ W2l, const float* __restrict__ B2,
    ushort* __restrict__ msgN)
{
    __shared__ ushort Yh[128 * YLD];
    const int t = threadIdx.x;
    const int w = t >> 6, l = t & 63, lg = l >> 4, lr = l & 15;
    const int n0 = blockIdx.x * 128;
    int n = n0 + w * 16 + lr;
    int nc = n < NN ? n : NN - 1;
    const float* src = reps + (size_t)nc * DD;

    float b1v[8], b2v[8];
    #pragma unroll
    for (int c = 0; c < 8; ++c) { b1v[c] = B1[c * 16 + lr]; b2v[c] = B2[c * 16 + lr]; }

    f32x4 acc[8];
    #pragma unroll
    for (int c = 0; c < 8; ++c) acc[c] = (f32x4)(0.f);

    // ---- layer 1 (A hi+lo, 3 MFMAs) ----
    #pragma unroll
    for (int s = 0; s < 4; ++s) {
        float4 x0 = *reinterpret_cast<const float4*>(src + s * 32 + lg * 8);
        float4 x1 = *reinterpret_cast<const float4*>(src + s * 32 + lg * 8 + 4);
        bf16x8 ah, al;
        cvt_hilo(x0, x1, ah, al);
        #pragma unroll
        for (int c = 0; c < 8; ++c) {
            bf16x8 bh = *reinterpret_cast<const bf16x8*>(W1h + (size_t)((c * 4 + s) * 64 + l) * 8);
            bf16x8 bl = *reinterpret_cast<const bf16x8*>(W1l + (size_t)((c * 4 + s) * 64 + l) * 8);
            acc[c] = MFMA16(al, bh, acc[c]);
            acc[c] = MFMA16(ah, bl, acc[c]);
            acc[c] = MFMA16(ah, bh, acc[c]);
        }
    }
    #pragma unroll
    for (int c = 0; c < 8; ++c) {
        #pragma unroll
        for (int i = 0; i < 4; ++i) {
            float yv = gelu_f(acc[c][i] + b1v[c]);
            Yh[(w * 16 + lg * 4 + i) * YLD + c * 16 + lr] = f2bf_rn(yv);
        }
    }

    // ---- layer 2 (A = bf16 Y from LDS; B hi/lo -> 2 MFMAs) ----
    #pragma unroll
    for (int c = 0; c < 8; ++c) acc[c] = (f32x4)(0.f);
    const ushort* yr = Yh + (w * 16 + lr) * YLD;
    #pragma unroll
    for (int s = 0; s < 4; ++s) {
        bf16x8 ah = *reinterpret_cast<const bf16x8*>(yr + s * 32 + lg * 8);
        #pragma unroll
        for (int c = 0; c < 8; ++c) {
            bf16x8 bh = *reinterpret_cast<const bf16x8*>(W2h + (size_t)((c * 4 + s) * 64 + l) * 8);
            bf16x8 bl = *reinterpret_cast<const bf16x8*>(W2l + (size_t)((c * 4 + s) * 64 + l) * 8);
            acc[c] = MFMA16(ah, bl, acc[c]);
            acc[c] = MFMA16(ah, bh, acc[c]);
        }
    }

    // ---- bias + GELU -> msgN bf16 ----
    const int nrow = n0 + w * 16 + lg * 4;
    #pragma unroll
    for (int i = 0; i < 4; ++i) {
        if (nrow + i < NN) {
            #pragma unroll
            for (int c = 0; c < 8; ++c)
                msgN[(size_t)(nrow + i) * DD + c * 16 + lr] = f2bf_rn(gelu_f(acc[c][i] + b2v[c]));
        }
    }
}

// ---------------- single-pass bucket build, dst-partitioned for XCD L2 affinity -------
#define NCHUNK 400
#define CHSZ (EE / NCHUNK)   // 2000
#define PSZ 6250             // NN / 8

__global__ __launch_bounds__(256) void fill_bucket(const int* __restrict__ edges,
                                                   int* __restrict__ cnt,
                                                   int* __restrict__ spillCnt,
                                                   int* __restrict__ spill,
                                                   int* __restrict__ bucket) {
    const int part = blockIdx.x & 7;
    const int ch   = blockIdx.x >> 3;
    const int lo = part * PSZ, hi = lo + PSZ;
    const int base = ch * CHSZ;
    for (int i = threadIdx.x; i < CHSZ; i += 256) {
        int e = base + i;
        int d = edges[e];
        if (d >= lo && d < hi) {
            int s = atomicAdd(&cnt[d], 1);
            if (s < 64) bucket[d * 64 + s] = e;
            else        spill[atomicAdd(spillCnt, 1)] = e;   // capacity EE: can't overflow
        }
    }
}

// ---------------- agg kernel: per-dst weighted sum of msgN rows (NO atomics) ----------
// 16 lanes per node. 4-way unrolled edge loop: 4 independent eid->(nbr,ew)->msgN load
// chains in flight (latency-bound fix: round-15 counters showed 3.1 TB/s @ 18% VALU).
__global__ __launch_bounds__(256, 8) void agg_kernel(
    const int* __restrict__ bucket, const int* __restrict__ cnt,
    const int* __restrict__ edges, const float* __restrict__ ew,
    const ushort* __restrict__ msgN, ushort* __restrict__ aggb)
{
    const int t = threadIdx.x;
    const int node = blockIdx.x * 16 + (t >> 4);
    const int la = t & 15;
    int deg = cnt[node]; deg = deg < 64 ? deg : 64;
    const int* b = bucket + node * 64;
    const ushort* base = msgN + la * 8;

    float acc[8] = {0.f, 0.f, 0.f, 0.f, 0.f, 0.f, 0.f, 0.f};
    int k = 0;
    for (; k + 3 < deg; k += 4) {
        int e0 = b[k], e1 = b[k + 1], e2 = b[k + 2], e3 = b[k + 3];
        int n0 = edges[EE + e0], n1 = edges[EE + e1];
        int n2 = edges[EE + e2], n3 = edges[EE + e3];
        float w0 = ew[e0], w1 = ew[e1], w2 = ew[e2], w3 = ew[e3];
        bf16x8 m0 = *reinterpret_cast<const bf16x8*>(base + (size_t)n0 * DD);
        bf16x8 m1 = *reinterpret_cast<const bf16x8*>(base + (size_t)n1 * DD);
        bf16x8 m2 = *reinterpret_cast<const bf16x8*>(base + (size_t)n2 * DD);
        bf16x8 m3 = *reinterpret_cast<const bf16x8*>(base + (size_t)n3 * DD);
        #pragma unroll
        for (int j = 0; j < 8; ++j) {
            acc[j] = fmaf(w0, bf2f((ushort)m0[j]), acc[j]);
            acc[j] = fmaf(w1, bf2f((ushort)m1[j]), acc[j]);
            acc[j] = fmaf(w2, bf2f((ushort)m2[j]), acc[j]);
            acc[j] = fmaf(w3, bf2f((ushort)m3[j]), acc[j]);
        }
    }
    for (; k < deg; ++k) {
        int e0 = b[k];
        int n0 = edges[EE + e0];
        float w0 = ew[e0];
        bf16x8 m0 = *reinterpret_cast<const bf16x8*>(base + (size_t)n0 * DD);
        #pragma unroll
        for (int j = 0; j < 8; ++j) acc[j] = fmaf(w0, bf2f((ushort)m0[j]), acc[j]);
    }
    uint4 o;
    o.x = pk2(acc[0], acc[1]);
    o.y = pk2(acc[2], acc[3]);
    o.z = pk2(acc[4], acc[5]);
    o.w = pk2(acc[6], acc[7]);
    *reinterpret_cast<uint4*>(aggb + (size_t)node * DD + la * 8) = o;
}

// spill fold-in: one (edge, col-pair) per work item; pk-bf16 atomics. No-op if spillCnt==0.
__global__ void spill_add(const int* __restrict__ spillCnt, const int* __restrict__ spill,
                          const int* __restrict__ edges, const float* __restrict__ ew,
                          const ushort* __restrict__ msgN, ushort* __restrict__ aggb) {
    long total = (long)spillCnt[0] * 64;
    for (long i = (long)blockIdx.x * 256 + threadIdx.x; i < total; i += 64L * 256) {
        int sp = (int)(i >> 6), cp = (int)(i & 63);
        int eid = spill[sp];
        int dst = edges[eid], nbr = edges[EE + eid];
        float w = ew[eid];
        float m0 = bf2f(msgN[(size_t)nbr * DD + cp * 2]);
        float m1 = bf2f(msgN[(size_t)nbr * DD + cp * 2 + 1]);
        atomic_pk_add_bf16(aggb + (size_t)dst * DD + cp * 2, pk2(w * m0, w * m1));
    }
}

// ---------------- node kernel: concat -> MFMA FFN(2 layers) -> L2 normalize ----------
__global__ __launch_bounds__(256, 4) void node_kernel(
    const float* __restrict__ reps, const ushort* __restrict__ aggb,
    const ushort* __restrict__ U1h, const ushort* __restrict__ U1l, const float* __restrict__ C1,
    const ushort* __restrict__ U2h, const ushort* __restrict__ U2l, const float* __restrict__ C2,
    float* __restrict__ out)
{
    __shared__ ushort Yh[64 * YLD];
    const int t = threadIdx.x;
    const int w = t >> 6, l = t & 63, lg = l >> 4, lr = l & 15;
    const int n0 = blockIdx.x * 64;
    int n = n0 + w * 16 + lr;
    int nc = n < NN ? n : NN - 1;

    float c1v[8], c2v[8];
    #pragma unroll
    for (int c = 0; c < 8; ++c) { c1v[c] = C1[c * 16 + lr]; c2v[c] = C2[c * 16 + lr]; }

    f32x4 acc[8];
    #pragma unroll
    for (int c = 0; c < 8; ++c) acc[c] = (f32x4)(0.f);

    // ---- update layer 1, reps half (k=0..127): f32 A hi+lo, 3 MFMAs ----
    #pragma unroll
    for (int s = 0; s < 4; ++s) {
        const float* sp = reps + (size_t)nc * DD + s * 32 + lg * 8;
        float4 x0 = *reinterpret_cast<const float4*>(sp);
        float4 x1 = *reinterpret_cast<const float4*>(sp + 4);
        bf16x8 ah, al;
        cvt_hilo(x0, x1, ah, al);
        #pragma unroll
        for (int c = 0; c < 8; ++c) {
            bf16x8 bh = *reinterpret_cast<const bf16x8*>(U1h + (size_t)((c * 8 + s) * 64 + l) * 8);
            bf16x8 bl = *reinterpret_cast<const bf16x8*>(U1l + (size_t)((c * 8 + s) * 64 + l) * 8);
            acc[c] = MFMA16(al, bh, acc[c]);
            acc[c] = MFMA16(ah, bl, acc[c]);
            acc[c] = MFMA16(ah, bh, acc[c]);
        }
    }
    // ---- update layer 1, agg half (k=128..255): bf16 A direct, 2 MFMAs ----
    #pragma unroll
    for (int s = 4; s < 8; ++s) {
        bf16x8 ah = *reinterpret_cast<const bf16x8*>(aggb + (size_t)nc * DD + (s - 4) * 32 + lg * 8);
        #pragma unroll
        for (int c = 0; c < 8; ++c) {
            bf16x8 bh = *reinterpret_cast<const bf16x8*>(U1h + (size_t)((c * 8 + s) * 64 + l) * 8);
            bf16x8 bl = *reinterpret_cast<const bf16x8*>(U1l + (size_t)((c * 8 + s) * 64 + l) * 8);
            acc[c] = MFMA16(ah, bl, acc[c]);
            acc[c] = MFMA16(ah, bh, acc[c]);
        }
    }
    #pragma unroll
    for (int c = 0; c < 8; ++c) {
        #pragma unroll
        for (int i = 0; i < 4; ++i) {
            float yv = gelu_f(acc[c][i] + c1v[c]);
            Yh[(w * 16 + lg * 4 + i) * YLD + c * 16 + lr] = f2bf_rn(yv);
        }
    }

    // ---- update layer 2: K=128, A = bf16 Y from LDS, 2 MFMAs ----
    #pragma unroll
    for (int c = 0; c < 8; ++c) acc[c] = (f32x4)(0.f);
    const ushort* yr = Yh + (w * 16 + lr) * YLD;
    #pragma unroll
    for (int s = 0; s < 4; ++s) {
        bf16x8 ah = *reinterpret_cast<const bf16x8*>(yr + s * 32 + lg * 8);
        #pragma unroll
        for (int c = 0; c < 8; ++c) {
            bf16x8 bh = *reinterpret_cast<const bf16x8*>(U2h + (size_t)((c * 4 + s) * 64 + l) * 8);
            bf16x8 bl = *reinterpret_cast<const bf16x8*>(U2l + (size_t)((c * 4 + s) * 64 + l) * 8);
            acc[c] = MFMA16(ah, bl, acc[c]);
            acc[c] = MFMA16(ah, bh, acc[c]);
        }
    }

    // ---- bias + GELU + L2 normalize + store ----
    float ssq[4] = {0.f, 0.f, 0.f, 0.f};
    #pragma unroll
    for (int c = 0; c < 8; ++c) {
        #pragma unroll
        for (int i = 0; i < 4; ++i) {
            float vv = gelu_f(acc[c][i] + c2v[c]);
            acc[c][i] = vv;
            ssq[i] = fmaf(vv, vv, ssq[i]);
        }
    }
    #pragma unroll
    for (int i = 0; i < 4; ++i) {
        #pragma unroll
        for (int msk = 1; msk < 16; msk <<= 1) ssq[i] += __shfl_xor(ssq[i], msk);
        ssq[i] = rsqrtf(fmaxf(ssq[i], 1e-12f));
    }
    const int nrow = n0 + w * 16 + lg * 4;
    #pragma unroll
    for (int i = 0; i < 4; ++i) {
        if (nrow + i < NN) {
            #pragma unroll
            for (int c = 0; c < 8; ++c)
                out[(size_t)(nrow + i) * DD + c * 16 + lr] = acc[c][i] * ssq[i];
        }
    }
}

// ---------------- launch ----------------
extern "C" void kernel_launch(void* const* d_in, const int* in_sizes, int n_in,
                              void* d_out, int out_size, void* d_ws, size_t ws_size,
                              hipStream_t stream)
{
    const float* reps = (const float*)d_in[0];
    const int*   edges = (const int*)d_in[1];
    const float* ew   = (const float*)d_in[2];
    const float* bn1g = (const float*)d_in[3];
    const float* bn1b = (const float*)d_in[4];
    const float* bn1m = (const float*)d_in[5];
    const float* bn1v = (const float*)d_in[6];
    const float* w1   = (const float*)d_in[7];
    const float* b1   = (const float*)d_in[8];
    const float* bn2g = (const float*)d_in[9];
    const float* bn2b = (const float*)d_in[10];
    const float* bn2m = (const float*)d_in[11];
    const float* bn2v = (const float*)d_in[12];
    const float* w2   = (const float*)d_in[13];
    const float* b2   = (const float*)d_in[14];
    const float* ubn1g = (const float*)d_in[15];
    const float* ubn1b = (const float*)d_in[16];
    const float* ubn1m = (const float*)d_in[17];
    const float* ubn1v = (const float*)d_in[18];
    const float* u1    = (const float*)d_in[19];
    const float* ub1   = (const float*)d_in[20];
    const float* ubn2g = (const float*)d_in[21];
    const float* ubn2b = (const float*)d_in[22];
    const float* ubn2m = (const float*)d_in[23];
    const float* ubn2v = (const float*)d_in[24];
    const float* u2    = (const float*)d_in[25];
    const float* ub2   = (const float*)d_in[26];

    // workspace layout (bytes)
    char* wsb = (char*)d_ws;
    ushort* aggb     = (ushort*)wsb;                     // 12,800,000 B
    int*    cnt      = (int*)(wsb + 12800000);           // 200,000 B
    int*    spillCnt = (int*)(wsb + 13000000);           // 4 B (memset with cnt)
    int*    spill    = (int*)(wsb + 13000016);           // 3,200,000 B (capacity EE)
    float*  B1f      = (float*)(wsb + 16200016);         // 128 f32 each, 16B aligned
    float*  B2f = B1f + 128;
    float*  C1f = B2f + 128;
    float*  C2f = C1f + 128;
    ushort* up  = (ushort*)(C2f + 128);
    ushort* W1h = up;                                    // 16384 each
    ushort* W1l = W1h + 16384;
    ushort* W2h = W1l + 16384;
    ushort* W2l = W2h + 16384;
    ushort* U1h = W2l + 16384;                           // 32768 each
    ushort* U1l = U1h + 32768;
    ushort* U2h = U1l + 32768;                           // 16384 each
    ushort* U2l = U2h + 16384;
    if (ws_size < 16600000) return;

    // d_out double-duty (both regions dead before node_kernel overwrites d_out):
    //   [0, 12.8MB)    msgN bf16 [NN][128]
    //   [12.8, 25.6MB) bucket int [NN][64]
    ushort* msgN   = (ushort*)d_out;
    int*    bucket = (int*)((char*)d_out + 12800000);

    init_bias<<<1, 128, 0, stream>>>(b1, b2, ub1, ub2, B1f, B2f, C1f, C2f);
    pack_all<<<320, 256, 0, stream>>>(w1, bn1g, bn1v, W1h, W1l,
                                      w2, bn2g, bn2v, W2h, W2l,
                                      u1, ubn1g, ubn1v, U1h, U1l,
                                      u2, ubn2g, ubn2v, U2h, U2l);
    fold_all<<<20, 256, 0, stream>>>(w1, bn1g, bn1b, bn1m, bn1v, B1f,
                                     w2, bn2g, bn2b, bn2m, bn2v, B2f,
                                     u1, ubn1g, ubn1b, ubn1m, ubn1v, C1f,
                                     u2, ubn2g, ubn2b, ubn2m, ubn2v, C2f);

    (void)hipMemsetAsync(cnt, 0, 200016, stream);  // cnt + spillCnt

    prep_kernel<<<(NN + 127) / 128, 512, 0, stream>>>(reps, W1h, W1l, B1f,
                                                      W2h, W2l, B2f, msgN);
    fill_bucket<<<NCHUNK * 8, 256, 0, stream>>>(edges, cnt, spillCnt, spill, bucket);
    agg_kernel<<<NN / 16, 256, 0, stream>>>(bucket, cnt, edges, ew, msgN, aggb);
    spill_add<<<64, 256, 0, stream>>>(spillCnt, spill, edges, ew, msgN, aggb);
    node_kernel<<<(NN + 63) / 64, 256, 0, stream>>>(reps, aggb, U1h, U1l, C1f,
                                                    U2h, U2l, C2f, (float*)d_out);
}

// Round 17
// 163.212 us; speedup vs baseline: 3.9775x; 1.0929x over previous
//
#include <hip/hip_runtime.h>
#include <hip/hip_bf16.h>
#include <math.h>

#define NN 50000
#define DD 128
#define EE 800000

static constexpr float BN_EPS = 1e-3f;

typedef __attribute__((ext_vector_type(8))) short bf16x8;
typedef __attribute__((ext_vector_type(4))) float f32x4;

#define MFMA16(a, b, c) __builtin_amdgcn_mfma_f32_16x16x32_bf16((a), (b), (c), 0, 0, 0)

// fast exact-grade GELU: Abramowitz-Stegun 7.1.26 erf (abs err 1.5e-7)
__device__ __forceinline__ float gelu_f(float x) {
    float ax = fabsf(x) * 0.7071067811865475f;
    float t = __builtin_amdgcn_rcpf(fmaf(0.3275911f, ax, 1.0f));
    float p = t * fmaf(t, fmaf(t, fmaf(t, fmaf(t, 1.061405429f, -1.453152027f),
                                       1.421413741f), -0.284496736f), 0.254829592f);
    float e = __expf(-ax * ax);
    float er = fmaf(-p, e, 1.0f);        // erf(|x|/sqrt2) for ax>=0
    float s = copysignf(er, x);
    return 0.5f * x * (1.0f + s);
}

__device__ __forceinline__ ushort f2bf_rn(float f) {
    uint u = __float_as_uint(f);
    return (ushort)((u + 0x7FFFu + ((u >> 16) & 1u)) >> 16);
}
__device__ __forceinline__ float bf2f(ushort h) {
    return __uint_as_float(((uint)h) << 16);
}

// packed pair f32->bf16 RNE (compiler emits v_cvt_pk_bf16_f32); low16=a, high16=b
__device__ __forceinline__ uint pk2(float a, float b) {
    __hip_bfloat162 t = __float22bfloat162_rn(make_float2(a, b));
    uint r;
    __builtin_memcpy(&r, &t, 4);
    return r;
}

// split f32x8 -> bf16 hi + bf16 lo fragments (f ~= hi + lo, |resid| ~ 2^-17|f|)
__device__ __forceinline__ void cvt_hilo(float4 x0, float4 x1, bf16x8& h, bf16x8& l) {
    float f[8] = {x0.x, x0.y, x0.z, x0.w, x1.x, x1.y, x1.z, x1.w};
    union U { uint u[4]; bf16x8 v; } uh, ul;
    #pragma unroll
    for (int j = 0; j < 4; ++j) {
        uint p = pk2(f[2 * j], f[2 * j + 1]);
        uh.u[j] = p;
        float h0 = __uint_as_float(p << 16);
        float h1 = __uint_as_float(p & 0xFFFF0000u);
        ul.u[j] = pk2(f[2 * j] - h0, f[2 * j + 1] - h1);
    }
    h = uh.v;
    l = ul.v;
}

// ---------------- fused weight-prep kernels ----------------
__device__ __forceinline__ void pack_one(const float* __restrict__ W, const float* __restrict__ g,
                                         const float* __restrict__ v, ushort* __restrict__ hi,
                                         ushort* __restrict__ lo, int K, int idx) {
    int k = idx >> 7, col = idx & 127;
    float s = g[k] * rsqrtf(v[k] + BN_EPS);
    float f = s * W[idx];
    int S = K >> 5;
    int st = k >> 5, gq = (k >> 3) & 3, j = k & 7;
    int c = col >> 4, ln = (gq << 4) | (col & 15);
    int o = ((c * S + st) * 64 + ln) * 8 + j;
    ushort hb = f2bf_rn(f);
    hi[o] = hb;
    lo[o] = f2bf_rn(f - bf2f(hb));
}

__global__ void pack_all(
    const float* __restrict__ w1, const float* __restrict__ g1, const float* __restrict__ v1,
    ushort* __restrict__ W1h, ushort* __restrict__ W1l,
    const float* __restrict__ w2, const float* __restrict__ g2, const float* __restrict__ v2,
    ushort* __restrict__ W2h, ushort* __restrict__ W2l,
    const float* __restrict__ u1, const float* __restrict__ g3, const float* __restrict__ v3,
    ushort* __restrict__ U1h, ushort* __restrict__ U1l,
    const float* __restrict__ u2, const float* __restrict__ g4, const float* __restrict__ v4,
    ushort* __restrict__ U2h, ushort* __restrict__ U2l)
{
    int idx = blockIdx.x * 256 + threadIdx.x;       // 0..81919
    if (idx < 16384)       pack_one(w1, g1, v1, W1h, W1l, 128, idx);
    else if (idx < 32768)  pack_one(w2, g2, v2, W2h, W2l, 128, idx - 16384);
    else if (idx < 65536)  pack_one(u1, g3, v3, U1h, U1l, 256, idx - 32768);
    else                   pack_one(u2, g4, v4, U2h, U2l, 128, idx - 65536);
}

__global__ void init_bias(const float* __restrict__ b1, const float* __restrict__ b2,
                          const float* __restrict__ ub1, const float* __restrict__ ub2,
                          float* __restrict__ B1f, float* __restrict__ B2f,
                          float* __restrict__ C1f, float* __restrict__ C2f) {
    int t = threadIdx.x;  // 128
    B1f[t] = b1[t]; B2f[t] = b2[t]; C1f[t] = ub1[t]; C2f[t] = ub2[t];
}

// fused BN-bias fold (also zeroes cnt+spillCnt for the fill pass downstream).
__global__ __launch_bounds__(256) void fold_all(
    const float* __restrict__ w1, const float* __restrict__ g1, const float* __restrict__ b1,
    const float* __restrict__ m1, const float* __restrict__ v1, float* __restrict__ B1f,
    const float* __restrict__ w2, const float* __restrict__ g2, const float* __restrict__ b2,
    const float* __restrict__ m2, const float* __restrict__ v2, float* __restrict__ B2f,
    const float* __restrict__ u1, const float* __restrict__ g3, const float* __restrict__ b3,
    const float* __restrict__ m3, const float* __restrict__ v3, float* __restrict__ C1f,
    const float* __restrict__ u2, const float* __restrict__ g4, const float* __restrict__ b4,
    const float* __restrict__ m4, const float* __restrict__ v4, float* __restrict__ C2f,
    int* __restrict__ cnt, int* __restrict__ spillCnt)
{
    // zero cnt[NN] + spillCnt (fill_bucket runs in the NEXT kernel -> ordering safe)
    for (int i = blockIdx.x * 256 + threadIdx.x; i < NN + 1; i += 20 * 256) {
        if (i < NN) cnt[i] = 0; else spillCnt[0] = 0;
    }

    const int rs = blockIdx.x * 32;
    const float *W, *g, *bb, *m, *v;
    float* bf;
    int k0;
    if (rs < 128)      { W = w1; g = g1; bb = b1; m = m1; v = v1; bf = B1f; k0 = rs; }
    else if (rs < 256) { W = w2; g = g2; bb = b2; m = m2; v = v2; bf = B2f; k0 = rs - 128; }
    else if (rs < 512) { W = u1; g = g3; bb = b3; m = m3; v = v3; bf = C1f; k0 = rs - 256; }
    else               { W = u2; g = g4; bb = b4; m = m4; v = v4; bf = C2f; k0 = rs - 512; }

    const int t = threadIdx.x, j = t & 127, h = t >> 7;
    float acc = 0.f;
    #pragma unroll
    for (int kk = 0; kk < 16; ++kk) {
        int k = k0 + h * 16 + kk;
        float s = g[k] * rsqrtf(v[k] + BN_EPS);
        float tt = bb[k] - m[k] * s;
        acc = fmaf(tt, W[k * DD + j], acc);
    }
    __shared__ float S[256];
    S[t] = acc;
    __syncthreads();
    if (h == 0) atomicAdd(&bf[j], S[j] + S[128 + j]);
}

#define YLD 136
#define BCAP 56            // bucket capacity per dst (max deg here ~45)
#define SPILL_CAP 100000   // guarded; unused for this input
#define NCHUNK 400
#define CHSZ (EE / NCHUNK) // 2000
#define PSZ 6250           // NN / 8
#define FILLB (NCHUNK * 8) // 3200 fill blocks (first -> bid&7 = XCD partition)

// ---------------- fused kernel A: fill_bucket (memory/atomics) || prep FFN (MFMA) ------
__global__ __launch_bounds__(512, 4) void prep_fill(
    const float* __restrict__ reps, const int* __restrict__ edges,
    const ushort* __restrict__ W1h, const ushort* __restrict__ W1l, const float* __restrict__ B1,
    const ushort* __restrict__ W2h, const ushort* __restrict__ W2l, const float* __restrict__ B2,
    ushort* __restrict__ msgN,
    int* __restrict__ cnt, int* __restrict__ spillCnt,
    int* __restrict__ spill, int* __restrict__ bucket)
{
    __shared__ ushort Yh[128 * YLD];

    if (blockIdx.x < FILLB) {
        // ---- fill path: dst-partitioned single-pass bucket build ----
        const int part = blockIdx.x & 7;
        const int ch   = blockIdx.x >> 3;
        const int lo = part * PSZ, hi2 = lo + PSZ;
        const int base = ch * CHSZ;
        for (int i = threadIdx.x; i < CHSZ; i += 512) {
            int e = base + i;
            int d = edges[e];
            if (d >= lo && d < hi2) {
                int s = atomicAdd(&cnt[d], 1);
                if (s < BCAP) bucket[d * BCAP + s] = e;
                else { int sl = atomicAdd(spillCnt, 1); if (sl < SPILL_CAP) spill[sl] = e; }
            }
        }
        return;
    }

    // ---- prep path: per-NODE FFN_pre -> msgN bf16 ----
    const int pb = blockIdx.x - FILLB;
    if (pb >= 391) return;
    const int t = threadIdx.x;
    const int w = t >> 6, l = t & 63, lg = l >> 4, lr = l & 15;
    const int n0 = pb * 128;
    int n = n0 + w * 16 + lr;
    int nc = n < NN ? n : NN - 1;
    const float* src = reps + (size_t)nc * DD;

    float b1v[8], b2v[8];
    #pragma unroll
    for (int c = 0; c < 8; ++c) { b1v[c] = B1[c * 16 + lr]; b2v[c] = B2[c * 16 + lr]; }

    f32x4 acc[8];
    #pragma unroll
    for (int c = 0; c < 8; ++c) acc[c] = (f32x4)(0.f);

    #pragma unroll
    for (int s = 0; s < 4; ++s) {
        float4 x0 = *reinterpret_cast<const float4*>(src + s * 32 + lg * 8);
        float4 x1 = *reinterpret_cast<const float4*>(src + s * 32 + lg * 8 + 4);
        bf16x8 ah, al;
        cvt_hilo(x0, x1, ah, al);
        #pragma unroll
        for (int c = 0; c < 8; ++c) {
            bf16x8 bh = *reinterpret_cast<const bf16x8*>(W1h + (size_t)((c * 4 + s) * 64 + l) * 8);
            bf16x8 bl = *reinterpret_cast<const bf16x8*>(W1l + (size_t)((c * 4 + s) * 64 + l) * 8);
            acc[c] = MFMA16(al, bh, acc[c]);
            acc[c] = MFMA16(ah, bl, acc[c]);
            acc[c] = MFMA16(ah, bh, acc[c]);
        }
    }
    #pragma unroll
    for (int c = 0; c < 8; ++c) {
        #pragma unroll
        for (int i = 0; i < 4; ++i) {
            float yv = gelu_f(acc[c][i] + b1v[c]);
            Yh[(w * 16 + lg * 4 + i) * YLD + c * 16 + lr] = f2bf_rn(yv);
        }
    }

    #pragma unroll
    for (int c = 0; c < 8; ++c) acc[c] = (f32x4)(0.f);
    const ushort* yr = Yh + (w * 16 + lr) * YLD;
    #pragma unroll
    for (int s = 0; s < 4; ++s) {
        bf16x8 ah = *reinterpret_cast<const bf16x8*>(yr + s * 32 + lg * 8);
        #pragma unroll
        for (int c = 0; c < 8; ++c) {
            bf16x8 bh = *reinterpret_cast<const bf16x8*>(W2h + (size_t)((c * 4 + s) * 64 + l) * 8);
            bf16x8 bl = *reinterpret_cast<const bf16x8*>(W2l + (size_t)((c * 4 + s) * 64 + l) * 8);
            acc[c] = MFMA16(ah, bl, acc[c]);
            acc[c] = MFMA16(ah, bh, acc[c]);
        }
    }

    const int nrow = n0 + w * 16 + lg * 4;
    #pragma unroll
    for (int i = 0; i < 4; ++i) {
        if (nrow + i < NN) {
            #pragma unroll
            for (int c = 0; c < 8; ++c)
                msgN[(size_t)(nrow + i) * DD + c * 16 + lr] = f2bf_rn(gelu_f(acc[c][i] + b2v[c]));
        }
    }
}

// ---------------- fused kernel B: agg (gather, phase 1 -> LDS) + node FFN (phase 2) ---
__global__ __launch_bounds__(256, 4) void agg_node(
    const float* __restrict__ reps, const int* __restrict__ edges, const float* __restrict__ ew,
    const int* __restrict__ bucket, const int* __restrict__ cnt,
    const int* __restrict__ spillCnt, const int* __restrict__ spill,
    const ushort* __restrict__ msgN,
    const ushort* __restrict__ U1h, const ushort* __restrict__ U1l, const float* __restrict__ C1,
    const ushort* __restrict__ U2h, const ushort* __restrict__ U2l, const float* __restrict__ C2,
    float* __restrict__ out)
{
    __shared__ ushort aggL[64 * YLD];
    __shared__ ushort Yh[64 * YLD];
    const int t = threadIdx.x;
    const int n0 = blockIdx.x * 64;

    // ---- phase 1: aggregate the block's 64 nodes; 16 lanes/node, 4 nodes/group ----
    {
        const int g = t >> 4, la = t & 15;
        const ushort* base = msgN + la * 8;
        for (int it = 0; it < 4; ++it) {
            const int nl = g * 4 + it;          // local node 0..63
            const int node = n0 + nl;
            float acc[8] = {0.f, 0.f, 0.f, 0.f, 0.f, 0.f, 0.f, 0.f};
            if (node < NN) {
                const int dc = cnt[node];
                const int deg = dc < BCAP ? dc : BCAP;
                const int* b = bucket + node * BCAP;
                int k = 0;
                for (; k + 3 < deg; k += 4) {
                    int e0 = b[k], e1 = b[k + 1], e2 = b[k + 2], e3 = b[k + 3];
                    int q0 = edges[EE + e0], q1 = edges[EE + e1];
                    int q2 = edges[EE + e2], q3 = edges[EE + e3];
                    float w0 = ew[e0], w1 = ew[e1], w2 = ew[e2], w3 = ew[e3];
                    bf16x8 m0 = *reinterpret_cast<const bf16x8*>(base + (size_t)q0 * DD);
                    bf16x8 m1 = *reinterpret_cast<const bf16x8*>(base + (size_t)q1 * DD);
                    bf16x8 m2 = *reinterpret_cast<const bf16x8*>(base + (size_t)q2 * DD);
                    bf16x8 m3 = *reinterpret_cast<const bf16x8*>(base + (size_t)q3 * DD);
                    #pragma unroll
                    for (int j = 0; j < 8; ++j) {
                        acc[j] = fmaf(w0, bf2f((ushort)m0[j]), acc[j]);
                        acc[j] = fmaf(w1, bf2f((ushort)m1[j]), acc[j]);
                        acc[j] = fmaf(w2, bf2f((ushort)m2[j]), acc[j]);
                        acc[j] = fmaf(w3, bf2f((ushort)m3[j]), acc[j]);
                    }
                }
                for (; k < deg; ++k) {
                    int e0 = b[k];
                    int q0 = edges[EE + e0];
                    float w0 = ew[e0];
                    bf16x8 m0 = *reinterpret_cast<const bf16x8*>(base + (size_t)q0 * DD);
                    #pragma unroll
                    for (int j = 0; j < 8; ++j) acc[j] = fmaf(w0, bf2f((ushort)m0[j]), acc[j]);
                }
                if (dc > BCAP) {                 // exact spill fold-in (empty here)
                    int sc = spillCnt[0]; if (sc > SPILL_CAP) sc = SPILL_CAP;
                    for (int i = 0; i < sc; ++i) {
                        int eid = spill[i];
                        if (edges[eid] == node) {
                            int q0 = edges[EE + eid];
                            float w0 = ew[eid];
                            bf16x8 m0 = *reinterpret_cast<const bf16x8*>(base + (size_t)q0 * DD);
                            #pragma unroll
                            for (int j = 0; j < 8; ++j)
                                acc[j] = fmaf(w0, bf2f((ushort)m0[j]), acc[j]);
                        }
                    }
                }
            }
            uint4 o;
            o.x = pk2(acc[0], acc[1]);
            o.y = pk2(acc[2], acc[3]);
            o.z = pk2(acc[4], acc[5]);
            o.w = pk2(acc[6], acc[7]);
            *reinterpret_cast<uint4*>(&aggL[nl * YLD + la * 8]) = o;
        }
    }
    __syncthreads();

    // ---- phase 2: node FFN (agg-half A from LDS) ----
    const int w = t >> 6, l = t & 63, lg = l >> 4, lr = l & 15;
    int n = n0 + w * 16 + lr;
    int nc = n < NN ? n : NN - 1;

    float c1v[8], c2v[8];
    #pragma unroll
    for (int c = 0; c < 8; ++c) { c1v[c] = C1[c * 16 + lr]; c2v[c] = C2[c * 16 + lr]; }

    f32x4 acc[8];
    #pragma unroll
    for (int c = 0; c < 8; ++c) acc[c] = (f32x4)(0.f);

    // reps half (k=0..127): f32 A hi+lo, 3 MFMAs
    #pragma unroll
    for (int s = 0; s < 4; ++s) {
        const float* sp = reps + (size_t)nc * DD + s * 32 + lg * 8;
        float4 x0 = *reinterpret_cast<const float4*>(sp);
        float4 x1 = *reinterpret_cast<const float4*>(sp + 4);
        bf16x8 ah, al;
        cvt_hilo(x0, x1, ah, al);
        #pragma unroll
        for (int c = 0; c < 8; ++c) {
            bf16x8 bh = *reinterpret_cast<const bf16x8*>(U1h + (size_t)((c * 8 + s) * 64 + l) * 8);
            bf16x8 bl = *reinterpret_cast<const bf16x8*>(U1l + (size_t)((c * 8 + s) * 64 + l) * 8);
            acc[c] = MFMA16(al, bh, acc[c]);
            acc[c] = MFMA16(ah, bl, acc[c]);
            acc[c] = MFMA16(ah, bh, acc[c]);
        }
    }
    // agg half (k=128..255): bf16 A from LDS, 2 MFMAs
    const ushort* ar = aggL + (w * 16 + lr) * YLD;
    #pragma unroll
    for (int s = 4; s < 8; ++s) {
        bf16x8 ah = *reinterpret_cast<const bf16x8*>(ar + (s - 4) * 32 + lg * 8);
        #pragma unroll
        for (int c = 0; c < 8; ++c) {
            bf16x8 bh = *reinterpret_cast<const bf16x8*>(U1h + (size_t)((c * 8 + s) * 64 + l) * 8);
            bf16x8 bl = *reinterpret_cast<const bf16x8*>(U1l + (size_t)((c * 8 + s) * 64 + l) * 8);
            acc[c] = MFMA16(ah, bl, acc[c]);
            acc[c] = MFMA16(ah, bh, acc[c]);
        }
    }
    #pragma unroll
    for (int c = 0; c < 8; ++c) {
        #pragma unroll
        for (int i = 0; i < 4; ++i) {
            float yv = gelu_f(acc[c][i] + c1v[c]);
            Yh[(w * 16 + lg * 4 + i) * YLD + c * 16 + lr] = f2bf_rn(yv);
        }
    }

    // layer 2: K=128, A = bf16 Y from LDS, 2 MFMAs
    #pragma unroll
    for (int c = 0; c < 8; ++c) acc[c] = (f32x4)(0.f);
    const ushort* yr = Yh + (w * 16 + lr) * YLD;
    #pragma unroll
    for (int s = 0; s < 4; ++s) {
        bf16x8 ah = *reinterpret_cast<const bf16x8*>(yr + s * 32 + lg * 8);
        #pragma unroll
        for (int c = 0; c < 8; ++c) {
            bf16x8 bh = *reinterpret_cast<const bf16x8*>(U2h + (size_t)((c * 4 + s) * 64 + l) * 8);
            bf16x8 bl = *reinterpret_cast<const bf16x8*>(U2l + (size_t)((c * 4 + s) * 64 + l) * 8);
            acc[c] = MFMA16(ah, bl, acc[c]);
            acc[c] = MFMA16(ah, bh, acc[c]);
        }
    }

    // bias + GELU + L2 normalize + store
    float ssq[4] = {0.f, 0.f, 0.f, 0.f};
    #pragma unroll
    for (int c = 0; c < 8; ++c) {
        #pragma unroll
        for (int i = 0; i < 4; ++i) {
            float vv = gelu_f(acc[c][i] + c2v[c]);
            acc[c][i] = vv;
            ssq[i] = fmaf(vv, vv, ssq[i]);
        }
    }
    #pragma unroll
    for (int i = 0; i < 4; ++i) {
        #pragma unroll
        for (int msk = 1; msk < 16; msk <<= 1) ssq[i] += __shfl_xor(ssq[i], msk);
        ssq[i] = rsqrtf(fmaxf(ssq[i], 1e-12f));
    }
    const int nrow = n0 + w * 16 + lg * 4;
    #pragma unroll
    for (int i = 0; i < 4; ++i) {
        if (nrow + i < NN) {
            #pragma unroll
            for (int c = 0; c < 8; ++c)
                out[(size_t)(nrow + i) * DD + c * 16 + lr] = acc[c][i] * ssq[i];
        }
    }
}

// ---------------- launch ----------------
extern "C" void kernel_launch(void* const* d_in, const int* in_sizes, int n_in,
                              void* d_out, int out_size, void* d_ws, size_t ws_size,
                              hipStream_t stream)
{
    const float* reps = (const float*)d_in[0];
    const int*   edges = (const int*)d_in[1];
    const float* ew   = (const float*)d_in[2];
    const float* bn1g = (const float*)d_in[3];
    const float* bn1b = (const float*)d_in[4];
    const float* bn1m = (const float*)d_in[5];
    const float* bn1v = (const float*)d_in[6];
    const float* w1   = (const float*)d_in[7];
    const float* b1   = (const float*)d_in[8];
    const float* bn2g = (const float*)d_in[9];
    const float* bn2b = (const float*)d_in[10];
    const float* bn2m = (const float*)d_in[11];
    const float* bn2v = (const float*)d_in[12];
    const float* w2   = (const float*)d_in[13];
    const float* b2   = (const float*)d_in[14];
    const float* ubn1g = (const float*)d_in[15];
    const float* ubn1b = (const float*)d_in[16];
    const float* ubn1m = (const float*)d_in[17];
    const float* ubn1v = (const float*)d_in[18];
    const float* u1    = (const float*)d_in[19];
    const float* ub1   = (const float*)d_in[20];
    const float* ubn2g = (const float*)d_in[21];
    const float* ubn2b = (const float*)d_in[22];
    const float* ubn2m = (const float*)d_in[23];
    const float* ubn2v = (const float*)d_in[24];
    const float* u2    = (const float*)d_in[25];
    const float* ub2   = (const float*)d_in[26];

    // workspace layout (bytes) — d_out is now used ONLY for the final output
    char* wsb = (char*)d_ws;
    ushort* msgN     = (ushort*)wsb;                     // 12,800,000 B
    int*    bucket   = (int*)(wsb + 12800000);           // NN*BCAP*4 = 11,200,000 B
    int*    cnt      = (int*)(wsb + 24000000);           // 200,000 B
    int*    spillCnt = (int*)(wsb + 24200000);           // 4 B (+pad)
    int*    spill    = (int*)(wsb + 24200016);           // 400,000 B
    float*  B1f      = (float*)(wsb + 24600016);         // 128 f32 each, 16B aligned
    float*  B2f = B1f + 128;
    float*  C1f = B2f + 128;
    float*  C2f = C1f + 128;
    ushort* up  = (ushort*)(C2f + 128);
    ushort* W1h = up;                                    // 16384 each
    ushort* W1l = W1h + 16384;
    ushort* W2h = W1l + 16384;
    ushort* W2l = W2h + 16384;
    ushort* U1h = W2l + 16384;                           // 32768 each
    ushort* U1l = U1h + 32768;
    ushort* U2h = U1l + 32768;                           // 16384 each
    ushort* U2l = U2h + 16384;
    if (ws_size < 24950000) return;

    init_bias<<<1, 128, 0, stream>>>(b1, b2, ub1, ub2, B1f, B2f, C1f, C2f);
    pack_all<<<320, 256, 0, stream>>>(w1, bn1g, bn1v, W1h, W1l,
                                      w2, bn2g, bn2v, W2h, W2l,
                                      u1, ubn1g, ubn1v, U1h, U1l,
                                      u2, ubn2g, ubn2v, U2h, U2l);
    fold_all<<<20, 256, 0, stream>>>(w1, bn1g, bn1b, bn1m, bn1v, B1f,
                                     w2, bn2g, bn2b, bn2m, bn2v, B2f,
                                     u1, ubn1g, ubn1b, ubn1m, ubn1v, C1f,
                                     u2, ubn2g, ubn2b, ubn2m, ubn2v, C2f,
                                     cnt, spillCnt);

    prep_fill<<<FILLB + 392, 512, 0, stream>>>(reps, edges, W1h, W1l, B1f,
                                               W2h, W2l, B2f, msgN,
                                               cnt, spillCnt, spill, bucket);
    agg_node<<<(NN + 63) / 64, 256, 0, stream>>>(reps, edges, ew, bucket, cnt,
                                                 spillCnt, spill, msgN,
                                                 U1h, U1l, C1f, U2h, U2l, C2f,
                                                 (float*)d_out);
}

// Round 18
// 161.692 us; speedup vs baseline: 4.0149x; 1.0094x over previous
//
#include <hip/hip_runtime.h>
#include <hip/hip_bf16.h>
#include <math.h>

#define NN 50000
#define DD 128
#define EE 800000

static constexpr float BN_EPS = 1e-3f;

typedef __attribute__((ext_vector_type(8))) short bf16x8;
typedef __attribute__((ext_vector_type(4))) float f32x4;

#define MFMA16(a, b, c) __builtin_amdgcn_mfma_f32_16x16x32_bf16((a), (b), (c), 0, 0, 0)

// fast exact-grade GELU: Abramowitz-Stegun 7.1.26 erf (abs err 1.5e-7)
__device__ __forceinline__ float gelu_f(float x) {
    float ax = fabsf(x) * 0.7071067811865475f;
    float t = __builtin_amdgcn_rcpf(fmaf(0.3275911f, ax, 1.0f));
    float p = t * fmaf(t, fmaf(t, fmaf(t, fmaf(t, 1.061405429f, -1.453152027f),
                                       1.421413741f), -0.284496736f), 0.254829592f);
    float e = __expf(-ax * ax);
    float er = fmaf(-p, e, 1.0f);        // erf(|x|/sqrt2) for ax>=0
    float s = copysignf(er, x);
    return 0.5f * x * (1.0f + s);
}

__device__ __forceinline__ ushort f2bf_rn(float f) {
    uint u = __float_as_uint(f);
    return (ushort)((u + 0x7FFFu + ((u >> 16) & 1u)) >> 16);
}
__device__ __forceinline__ float bf2f(ushort h) {
    return __uint_as_float(((uint)h) << 16);
}

// packed pair f32->bf16 RNE (compiler emits v_cvt_pk_bf16_f32); low16=a, high16=b
__device__ __forceinline__ uint pk2(float a, float b) {
    __hip_bfloat162 t = __float22bfloat162_rn(make_float2(a, b));
    uint r;
    __builtin_memcpy(&r, &t, 4);
    return r;
}

// split f32x8 -> bf16 hi + bf16 lo fragments (f ~= hi + lo, |resid| ~ 2^-17|f|)
__device__ __forceinline__ void cvt_hilo(float4 x0, float4 x1, bf16x8& h, bf16x8& l) {
    float f[8] = {x0.x, x0.y, x0.z, x0.w, x1.x, x1.y, x1.z, x1.w};
    union U { uint u[4]; bf16x8 v; } uh, ul;
    #pragma unroll
    for (int j = 0; j < 4; ++j) {
        uint p = pk2(f[2 * j], f[2 * j + 1]);
        uh.u[j] = p;
        float h0 = __uint_as_float(p << 16);
        float h1 = __uint_as_float(p & 0xFFFF0000u);
        ul.u[j] = pk2(f[2 * j] - h0, f[2 * j + 1] - h1);
    }
    h = uh.v;
    l = ul.v;
}

// ---------------- fused weight-prep kernels ----------------
__device__ __forceinline__ void pack_one(const float* __restrict__ W, const float* __restrict__ g,
                                         const float* __restrict__ v, ushort* __restrict__ hi,
                                         ushort* __restrict__ lo, int K, int idx) {
    int k = idx >> 7, col = idx & 127;
    float s = g[k] * rsqrtf(v[k] + BN_EPS);
    float f = s * W[idx];
    int S = K >> 5;
    int st = k >> 5, gq = (k >> 3) & 3, j = k & 7;
    int c = col >> 4, ln = (gq << 4) | (col & 15);
    int o = ((c * S + st) * 64 + ln) * 8 + j;
    ushort hb = f2bf_rn(f);
    hi[o] = hb;
    lo[o] = f2bf_rn(f - bf2f(hb));
}

__global__ void pack_all(
    const float* __restrict__ w1, const float* __restrict__ g1, const float* __restrict__ v1,
    ushort* __restrict__ W1h, ushort* __restrict__ W1l,
    const float* __restrict__ w2, const float* __restrict__ g2, const float* __restrict__ v2,
    ushort* __restrict__ W2h, ushort* __restrict__ W2l,
    const float* __restrict__ u1, const float* __restrict__ g3, const float* __restrict__ v3,
    ushort* __restrict__ U1h, ushort* __restrict__ U1l,
    const float* __restrict__ u2, const float* __restrict__ g4, const float* __restrict__ v4,
    ushort* __restrict__ U2h, ushort* __restrict__ U2l)
{
    int idx = blockIdx.x * 256 + threadIdx.x;       // 0..81919
    if (idx < 16384)       pack_one(w1, g1, v1, W1h, W1l, 128, idx);
    else if (idx < 32768)  pack_one(w2, g2, v2, W2h, W2l, 128, idx - 16384);
    else if (idx < 65536)  pack_one(u1, g3, v3, U1h, U1l, 256, idx - 32768);
    else                   pack_one(u2, g4, v4, U2h, U2l, 128, idx - 65536);
}

__global__ void init_bias(const float* __restrict__ b1, const float* __restrict__ b2,
                          const float* __restrict__ ub1, const float* __restrict__ ub2,
                          float* __restrict__ B1f, float* __restrict__ B2f,
                          float* __restrict__ C1f, float* __restrict__ C2f) {
    int t = threadIdx.x;  // 128
    B1f[t] = b1[t]; B2f[t] = b2[t]; C1f[t] = ub1[t]; C2f[t] = ub2[t];
}

// fused BN-bias fold (also zeroes cnt+spillCnt for the fill pass downstream).
__global__ __launch_bounds__(256) void fold_all(
    const float* __restrict__ w1, const float* __restrict__ g1, const float* __restrict__ b1,
    const float* __restrict__ m1, const float* __restrict__ v1, float* __restrict__ B1f,
    const float* __restrict__ w2, const float* __restrict__ g2, const float* __restrict__ b2,
    const float* __restrict__ m2, const float* __restrict__ v2, float* __restrict__ B2f,
    const float* __restrict__ u1, const float* __restrict__ g3, const float* __restrict__ b3,
    const float* __restrict__ m3, const float* __restrict__ v3, float* __restrict__ C1f,
    const float* __restrict__ u2, const float* __restrict__ g4, const float* __restrict__ b4,
    const float* __restrict__ m4, const float* __restrict__ v4, float* __restrict__ C2f,
    int* __restrict__ cnt, int* __restrict__ spillCnt)
{
    for (int i = blockIdx.x * 256 + threadIdx.x; i < NN + 1; i += 20 * 256) {
        if (i < NN) cnt[i] = 0; else spillCnt[0] = 0;
    }

    const int rs = blockIdx.x * 32;
    const float *W, *g, *bb, *m, *v;
    float* bf;
    int k0;
    if (rs < 128)      { W = w1; g = g1; bb = b1; m = m1; v = v1; bf = B1f; k0 = rs; }
    else if (rs < 256) { W = w2; g = g2; bb = b2; m = m2; v = v2; bf = B2f; k0 = rs - 128; }
    else if (rs < 512) { W = u1; g = g3; bb = b3; m = m3; v = v3; bf = C1f; k0 = rs - 256; }
    else               { W = u2; g = g4; bb = b4; m = m4; v = v4; bf = C2f; k0 = rs - 512; }

    const int t = threadIdx.x, j = t & 127, h = t >> 7;
    float acc = 0.f;
    #pragma unroll
    for (int kk = 0; kk < 16; ++kk) {
        int k = k0 + h * 16 + kk;
        float s = g[k] * rsqrtf(v[k] + BN_EPS);
        float tt = bb[k] - m[k] * s;
        acc = fmaf(tt, W[k * DD + j], acc);
    }
    __shared__ float S[256];
    S[t] = acc;
    __syncthreads();
    if (h == 0) atomicAdd(&bf[j], S[j] + S[128 + j]);
}

#define YLD 136
#define BCAP 56            // bucket capacity per dst (max deg here ~45)
#define SPILL_CAP 100000   // guarded; unused for this input
#define NCHUNK 400
#define CHSZ (EE / NCHUNK) // 2000
#define PSZ 6250           // NN / 8
#define FILLB (NCHUNK * 8) // 3200 fill blocks (first -> bid&7 = XCD partition)

// ---------------- fused kernel A: fill_bucket (memory/atomics) || prep FFN (MFMA) ------
__global__ __launch_bounds__(512, 4) void prep_fill(
    const float* __restrict__ reps, const int* __restrict__ edges,
    const ushort* __restrict__ W1h, const ushort* __restrict__ W1l, const float* __restrict__ B1,
    const ushort* __restrict__ W2h, const ushort* __restrict__ W2l, const float* __restrict__ B2,
    ushort* __restrict__ msgN,
    int* __restrict__ cnt, int* __restrict__ spillCnt,
    int* __restrict__ spill, int* __restrict__ bucket)
{
    __shared__ ushort Yh[128 * YLD];

    if (blockIdx.x < FILLB) {
        const int part = blockIdx.x & 7;
        const int ch   = blockIdx.x >> 3;
        const int lo = part * PSZ, hi2 = lo + PSZ;
        const int base = ch * CHSZ;
        for (int i = threadIdx.x; i < CHSZ; i += 512) {
            int e = base + i;
            int d = edges[e];
            if (d >= lo && d < hi2) {
                int s = atomicAdd(&cnt[d], 1);
                if (s < BCAP) bucket[d * BCAP + s] = e;
                else { int sl = atomicAdd(spillCnt, 1); if (sl < SPILL_CAP) spill[sl] = e; }
            }
        }
        return;
    }

    const int pb = blockIdx.x - FILLB;
    if (pb >= 391) return;
    const int t = threadIdx.x;
    const int w = t >> 6, l = t & 63, lg = l >> 4, lr = l & 15;
    const int n0 = pb * 128;
    int n = n0 + w * 16 + lr;
    int nc = n < NN ? n : NN - 1;
    const float* src = reps + (size_t)nc * DD;

    float b1v[8], b2v[8];
    #pragma unroll
    for (int c = 0; c < 8; ++c) { b1v[c] = B1[c * 16 + lr]; b2v[c] = B2[c * 16 + lr]; }

    f32x4 acc[8];
    #pragma unroll
    for (int c = 0; c < 8; ++c) acc[c] = (f32x4)(0.f);

    #pragma unroll
    for (int s = 0; s < 4; ++s) {
        float4 x0 = *reinterpret_cast<const float4*>(src + s * 32 + lg * 8);
        float4 x1 = *reinterpret_cast<const float4*>(src + s * 32 + lg * 8 + 4);
        bf16x8 ah, al;
        cvt_hilo(x0, x1, ah, al);
        #pragma unroll
        for (int c = 0; c < 8; ++c) {
            bf16x8 bh = *reinterpret_cast<const bf16x8*>(W1h + (size_t)((c * 4 + s) * 64 + l) * 8);
            bf16x8 bl = *reinterpret_cast<const bf16x8*>(W1l + (size_t)((c * 4 + s) * 64 + l) * 8);
            acc[c] = MFMA16(al, bh, acc[c]);
            acc[c] = MFMA16(ah, bl, acc[c]);
            acc[c] = MFMA16(ah, bh, acc[c]);
        }
    }
    #pragma unroll
    for (int c = 0; c < 8; ++c) {
        #pragma unroll
        for (int i = 0; i < 4; ++i) {
            float yv = gelu_f(acc[c][i] + b1v[c]);
            Yh[(w * 16 + lg * 4 + i) * YLD + c * 16 + lr] = f2bf_rn(yv);
        }
    }

    #pragma unroll
    for (int c = 0; c < 8; ++c) acc[c] = (f32x4)(0.f);
    const ushort* yr = Yh + (w * 16 + lr) * YLD;
    #pragma unroll
    for (int s = 0; s < 4; ++s) {
        bf16x8 ah = *reinterpret_cast<const bf16x8*>(yr + s * 32 + lg * 8);
        #pragma unroll
        for (int c = 0; c < 8; ++c) {
            bf16x8 bh = *reinterpret_cast<const bf16x8*>(W2h + (size_t)((c * 4 + s) * 64 + l) * 8);
            bf16x8 bl = *reinterpret_cast<const bf16x8*>(W2l + (size_t)((c * 4 + s) * 64 + l) * 8);
            acc[c] = MFMA16(ah, bl, acc[c]);
            acc[c] = MFMA16(ah, bh, acc[c]);
        }
    }

    const int nrow = n0 + w * 16 + lg * 4;
    #pragma unroll
    for (int i = 0; i < 4; ++i) {
        if (nrow + i < NN) {
            #pragma unroll
            for (int c = 0; c < 8; ++c)
                msgN[(size_t)(nrow + i) * DD + c * 16 + lr] = f2bf_rn(gelu_f(acc[c][i] + b2v[c]));
        }
    }
}

// ---------------- fused kernel B: agg (gather) + node FFN, 512 thr / 64 nodes ---------
// Phase 1: 32 groups x 2 nodes (2x waves vs r17 -> more outstanding gathers).
// Phase 2: column-split FFN — wave w: rows (w&3)*16.., cols half (w>>2). acc[4]/wave.
__global__ __launch_bounds__(512, 8) void agg_node(
    const float* __restrict__ reps, const int* __restrict__ edges, const float* __restrict__ ew,
    const int* __restrict__ bucket, const int* __restrict__ cnt,
    const int* __restrict__ spillCnt, const int* __restrict__ spill,
    const ushort* __restrict__ msgN,
    const ushort* __restrict__ U1h, const ushort* __restrict__ U1l, const float* __restrict__ C1,
    const ushort* __restrict__ U2h, const ushort* __restrict__ U2l, const float* __restrict__ C2,
    float* __restrict__ out)
{
    __shared__ ushort aggL[64 * YLD];
    __shared__ ushort Yh[64 * YLD];
    __shared__ float ssqP[2][64];
    const int t = threadIdx.x;
    const int n0 = blockIdx.x * 64;

    // ---- phase 1: aggregate 64 nodes; 16 lanes/node, 2 nodes/group, 32 groups ----
    {
        const int g = t >> 4, la = t & 15;
        const ushort* base = msgN + la * 8;
        #pragma unroll
        for (int it = 0; it < 2; ++it) {
            const int nl = g * 2 + it;          // local node 0..63
            const int node = n0 + nl;
            float acc[8] = {0.f, 0.f, 0.f, 0.f, 0.f, 0.f, 0.f, 0.f};
            if (node < NN) {
                const int dc = cnt[node];
                const int deg = dc < BCAP ? dc : BCAP;
                const int* b = bucket + node * BCAP;
                int k = 0;
                for (; k + 3 < deg; k += 4) {
                    int e0 = b[k], e1 = b[k + 1], e2 = b[k + 2], e3 = b[k + 3];
                    int q0 = edges[EE + e0], q1 = edges[EE + e1];
                    int q2 = edges[EE + e2], q3 = edges[EE + e3];
                    float w0 = ew[e0], w1 = ew[e1], w2 = ew[e2], w3 = ew[e3];
                    bf16x8 m0 = *reinterpret_cast<const bf16x8*>(base + (size_t)q0 * DD);
                    bf16x8 m1 = *reinterpret_cast<const bf16x8*>(base + (size_t)q1 * DD);
                    bf16x8 m2 = *reinterpret_cast<const bf16x8*>(base + (size_t)q2 * DD);
                    bf16x8 m3 = *reinterpret_cast<const bf16x8*>(base + (size_t)q3 * DD);
                    #pragma unroll
                    for (int j = 0; j < 8; ++j) {
                        acc[j] = fmaf(w0, bf2f((ushort)m0[j]), acc[j]);
                        acc[j] = fmaf(w1, bf2f((ushort)m1[j]), acc[j]);
                        acc[j] = fmaf(w2, bf2f((ushort)m2[j]), acc[j]);
                        acc[j] = fmaf(w3, bf2f((ushort)m3[j]), acc[j]);
                    }
                }
                for (; k < deg; ++k) {
                    int e0 = b[k];
                    int q0 = edges[EE + e0];
                    float w0 = ew[e0];
                    bf16x8 m0 = *reinterpret_cast<const bf16x8*>(base + (size_t)q0 * DD);
                    #pragma unroll
                    for (int j = 0; j < 8; ++j) acc[j] = fmaf(w0, bf2f((ushort)m0[j]), acc[j]);
                }
                if (dc > BCAP) {                 // exact spill fold-in (empty here)
                    int sc = spillCnt[0]; if (sc > SPILL_CAP) sc = SPILL_CAP;
                    for (int i = 0; i < sc; ++i) {
                        int eid = spill[i];
                        if (edges[eid] == node) {
                            int q0 = edges[EE + eid];
                            float w0 = ew[eid];
                            bf16x8 m0 = *reinterpret_cast<const bf16x8*>(base + (size_t)q0 * DD);
                            #pragma unroll
                            for (int j = 0; j < 8; ++j)
                                acc[j] = fmaf(w0, bf2f((ushort)m0[j]), acc[j]);
                        }
                    }
                }
            }
            uint4 o;
            o.x = pk2(acc[0], acc[1]);
            o.y = pk2(acc[2], acc[3]);
            o.z = pk2(acc[4], acc[5]);
            o.w = pk2(acc[6], acc[7]);
            *reinterpret_cast<uint4*>(&aggL[nl * YLD + la * 8]) = o;
        }
    }
    __syncthreads();

    // ---- phase 2: column-split node FFN ----
    const int w = t >> 6, l = t & 63, lg = l >> 4, lr = l & 15;
    const int wr = w & 3, hh = w >> 2;          // row group / column half
    int n = n0 + wr * 16 + lr;
    int nc = n < NN ? n : NN - 1;

    float c1v[4], c2v[4];
    #pragma unroll
    for (int cc = 0; cc < 4; ++cc) {
        c1v[cc] = C1[(4 * hh + cc) * 16 + lr];
        c2v[cc] = C2[(4 * hh + cc) * 16 + lr];
    }

    f32x4 acc[4];
    #pragma unroll
    for (int cc = 0; cc < 4; ++cc) acc[cc] = (f32x4)(0.f);

    // layer 1, reps half (k=0..127): f32 A hi+lo, 3 MFMAs
    #pragma unroll
    for (int s = 0; s < 4; ++s) {
        const float* sp = reps + (size_t)nc * DD + s * 32 + lg * 8;
        float4 x0 = *reinterpret_cast<const float4*>(sp);
        float4 x1 = *reinterpret_cast<const float4*>(sp + 4);
        bf16x8 ah, al;
        cvt_hilo(x0, x1, ah, al);
        #pragma unroll
        for (int cc = 0; cc < 4; ++cc) {
            int c = 4 * hh + cc;
            bf16x8 bh = *reinterpret_cast<const bf16x8*>(U1h + (size_t)((c * 8 + s) * 64 + l) * 8);
            bf16x8 bl = *reinterpret_cast<const bf16x8*>(U1l + (size_t)((c * 8 + s) * 64 + l) * 8);
            acc[cc] = MFMA16(al, bh, acc[cc]);
            acc[cc] = MFMA16(ah, bl, acc[cc]);
            acc[cc] = MFMA16(ah, bh, acc[cc]);
        }
    }
    // layer 1, agg half (k=128..255): bf16 A from LDS, 2 MFMAs
    const ushort* ar = aggL + (wr * 16 + lr) * YLD;
    #pragma unroll
    for (int s = 4; s < 8; ++s) {
        bf16x8 ah = *reinterpret_cast<const bf16x8*>(ar + (s - 4) * 32 + lg * 8);
        #pragma unroll
        for (int cc = 0; cc < 4; ++cc) {
            int c = 4 * hh + cc;
            bf16x8 bh = *reinterpret_cast<const bf16x8*>(U1h + (size_t)((c * 8 + s) * 64 + l) * 8);
            bf16x8 bl = *reinterpret_cast<const bf16x8*>(U1l + (size_t)((c * 8 + s) * 64 + l) * 8);
            acc[cc] = MFMA16(ah, bl, acc[cc]);
            acc[cc] = MFMA16(ah, bh, acc[cc]);
        }
    }
    #pragma unroll
    for (int cc = 0; cc < 4; ++cc) {
        #pragma unroll
        for (int i = 0; i < 4; ++i) {
            float yv = gelu_f(acc[cc][i] + c1v[cc]);
            Yh[(wr * 16 + lg * 4 + i) * YLD + (4 * hh + cc) * 16 + lr] = f2bf_rn(yv);
        }
    }
    __syncthreads();   // Y rows assembled from both column halves

    // layer 2: K=128, A = full bf16 Y row from LDS, 2 MFMAs
    #pragma unroll
    for (int cc = 0; cc < 4; ++cc) acc[cc] = (f32x4)(0.f);
    const ushort* yr2 = Yh + (wr * 16 + lr) * YLD;
    #pragma unroll
    for (int s = 0; s < 4; ++s) {
        bf16x8 ah = *reinterpret_cast<const bf16x8*>(yr2 + s * 32 + lg * 8);
        #pragma unroll
        for (int cc = 0; cc < 4; ++cc) {
            int c = 4 * hh + cc;
            bf16x8 bh = *reinterpret_cast<const bf16x8*>(U2h + (size_t)((c * 4 + s) * 64 + l) * 8);
            bf16x8 bl = *reinterpret_cast<const bf16x8*>(U2l + (size_t)((c * 4 + s) * 64 + l) * 8);
            acc[cc] = MFMA16(ah, bl, acc[cc]);
            acc[cc] = MFMA16(ah, bh, acc[cc]);
        }
    }

    // bias + GELU + split L2-norm (partials across column halves via LDS)
    float ssq[4] = {0.f, 0.f, 0.f, 0.f};
    #pragma unroll
    for (int cc = 0; cc < 4; ++cc) {
        #pragma unroll
        for (int i = 0; i < 4; ++i) {
            float vv = gelu_f(acc[cc][i] + c2v[cc]);
            acc[cc][i] = vv;
            ssq[i] = fmaf(vv, vv, ssq[i]);
        }
    }
    #pragma unroll
    for (int i = 0; i < 4; ++i) {
        #pragma unroll
        for (int msk = 1; msk < 16; msk <<= 1) ssq[i] += __shfl_xor(ssq[i], msk);
    }
    const int row0 = wr * 16 + lg * 4;
    if (lr == 0) {
        #pragma unroll
        for (int i = 0; i < 4; ++i) ssqP[hh][row0 + i] = ssq[i];
    }
    __syncthreads();
    #pragma unroll
    for (int i = 0; i < 4; ++i) {
        float tot = ssqP[0][row0 + i] + ssqP[1][row0 + i];
        float sc = rsqrtf(fmaxf(tot, 1e-12f));
        if (n0 + row0 + i < NN) {
            #pragma unroll
            for (int cc = 0; cc < 4; ++cc)
                out[(size_t)(n0 + row0 + i) * DD + (4 * hh + cc) * 16 + lr] = acc[cc][i] * sc;
        }
    }
}

// ---------------- launch ----------------
extern "C" void kernel_launch(void* const* d_in, const int* in_sizes, int n_in,
                              void* d_out, int out_size, void* d_ws, size_t ws_size,
                              hipStream_t stream)
{
    const float* reps = (const float*)d_in[0];
    const int*   edges = (const int*)d_in[1];
    const float* ew   = (const float*)d_in[2];
    const float* bn1g = (const float*)d_in[3];
    const float* bn1b = (const float*)d_in[4];
    const float* bn1m = (const float*)d_in[5];
    const float* bn1v = (const float*)d_in[6];
    const float* w1   = (const float*)d_in[7];
    const float* b1   = (const float*)d_in[8];
    const float* bn2g = (const float*)d_in[9];
    const float* bn2b = (const float*)d_in[10];
    const float* bn2m = (const float*)d_in[11];
    const float* bn2v = (const float*)d_in[12];
    const float* w2   = (const float*)d_in[13];
    const float* b2   = (const float*)d_in[14];
    const float* ubn1g = (const float*)d_in[15];
    const float* ubn1b = (const float*)d_in[16];
    const float* ubn1m = (const float*)d_in[17];
    const float* ubn1v = (const float*)d_in[18];
    const float* u1    = (const float*)d_in[19];
    const float* ub1   = (const float*)d_in[20];
    const float* ubn2g = (const float*)d_in[21];
    const float* ubn2b = (const float*)d_in[22];
    const float* ubn2m = (const float*)d_in[23];
    const float* ubn2v = (const float*)d_in[24];
    const float* u2    = (const float*)d_in[25];
    const float* ub2   = (const float*)d_in[26];

    // workspace layout (bytes) — d_out used ONLY for final output
    char* wsb = (char*)d_ws;
    ushort* msgN     = (ushort*)wsb;                     // 12,800,000 B
    int*    bucket   = (int*)(wsb + 12800000);           // NN*BCAP*4 = 11,200,000 B
    int*    cnt      = (int*)(wsb + 24000000);           // 200,000 B
    int*    spillCnt = (int*)(wsb + 24200000);           // 4 B (+pad)
    int*    spill    = (int*)(wsb + 24200016);           // 400,000 B
    float*  B1f      = (float*)(wsb + 24600016);         // 128 f32 each, 16B aligned
    float*  B2f = B1f + 128;
    float*  C1f = B2f + 128;
    float*  C2f = C1f + 128;
    ushort* up  = (ushort*)(C2f + 128);
    ushort* W1h = up;                                    // 16384 each
    ushort* W1l = W1h + 16384;
    ushort* W2h = W1l + 16384;
    ushort* W2l = W2h + 16384;
    ushort* U1h = W2l + 16384;                           // 32768 each
    ushort* U1l = U1h + 32768;
    ushort* U2h = U1l + 32768;                           // 16384 each
    ushort* U2l = U2h + 16384;
    if (ws_size < 24950000) return;

    init_bias<<<1, 128, 0, stream>>>(b1, b2, ub1, ub2, B1f, B2f, C1f, C2f);
    pack_all<<<320, 256, 0, stream>>>(w1, bn1g, bn1v, W1h, W1l,
                                      w2, bn2g, bn2v, W2h, W2l,
                                      u1, ubn1g, ubn1v, U1h, U1l,
                                      u2, ubn2g, ubn2v, U2h, U2l);
    fold_all<<<20, 256, 0, stream>>>(w1, bn1g, bn1b, bn1m, bn1v, B1f,
                                     w2, bn2g, bn2b, bn2m, bn2v, B2f,
                                     u1, ubn1g, ubn1b, ubn1m, ubn1v, C1f,
                                     u2, ubn2g, ubn2b, ubn2m, ubn2v, C2f,
                                     cnt, spillCnt);

    prep_fill<<<FILLB + 392, 512, 0, stream>>>(reps, edges, W1h, W1l, B1f,
                                               W2h, W2l, B2f, msgN,
                                               cnt, spillCnt, spill, bucket);
    agg_node<<<(NN + 63) / 64, 512, 0, stream>>>(reps, edges, ew, bucket, cnt,
                                                 spillCnt, spill, msgN,
                                                 U1h, U1l, C1f, U2h, U2l, C2f,
                                                 (float*)d_out);
}

// Round 19
// 155.760 us; speedup vs baseline: 4.1678x; 1.0381x over previous
//
#include <hip/hip_runtime.h>
#include <hip/hip_bf16.h>
#include <math.h>

#define NN 50000
#define DD 128
#define EE 800000

static constexpr float BN_EPS = 1e-3f;

typedef __attribute__((ext_vector_type(8))) short bf16x8;
typedef __attribute__((ext_vector_type(4))) float f32x4;

#define MFMA16(a, b, c) __builtin_amdgcn_mfma_f32_16x16x32_bf16((a), (b), (c), 0, 0, 0)

// fast exact-grade GELU: Abramowitz-Stegun 7.1.26 erf (abs err 1.5e-7)
__device__ __forceinline__ float gelu_f(float x) {
    float ax = fabsf(x) * 0.7071067811865475f;
    float t = __builtin_amdgcn_rcpf(fmaf(0.3275911f, ax, 1.0f));
    float p = t * fmaf(t, fmaf(t, fmaf(t, fmaf(t, 1.061405429f, -1.453152027f),
                                       1.421413741f), -0.284496736f), 0.254829592f);
    float e = __expf(-ax * ax);
    float er = fmaf(-p, e, 1.0f);        // erf(|x|/sqrt2) for ax>=0
    float s = copysignf(er, x);
    return 0.5f * x * (1.0f + s);
}

__device__ __forceinline__ ushort f2bf_rn(float f) {
    uint u = __float_as_uint(f);
    return (ushort)((u + 0x7FFFu + ((u >> 16) & 1u)) >> 16);
}
__device__ __forceinline__ float bf2f(ushort h) {
    return __uint_as_float(((uint)h) << 16);
}

// packed pair f32->bf16 RNE (compiler emits v_cvt_pk_bf16_f32); low16=a, high16=b
__device__ __forceinline__ uint pk2(float a, float b) {
    __hip_bfloat162 t = __float22bfloat162_rn(make_float2(a, b));
    uint r;
    __builtin_memcpy(&r, &t, 4);
    return r;
}

// split f32x8 -> bf16 hi + bf16 lo fragments (f ~= hi + lo, |resid| ~ 2^-17|f|)
__device__ __forceinline__ void cvt_hilo(float4 x0, float4 x1, bf16x8& h, bf16x8& l) {
    float f[8] = {x0.x, x0.y, x0.z, x0.w, x1.x, x1.y, x1.z, x1.w};
    union U { uint u[4]; bf16x8 v; } uh, ul;
    #pragma unroll
    for (int j = 0; j < 4; ++j) {
        uint p = pk2(f[2 * j], f[2 * j + 1]);
        uh.u[j] = p;
        float h0 = __uint_as_float(p << 16);
        float h1 = __uint_as_float(p & 0xFFFF0000u);
        ul.u[j] = pk2(f[2 * j] - h0, f[2 * j + 1] - h1);
    }
    h = uh.v;
    l = ul.v;
}

// ---------------- fused weight-prep kernels ----------------
__device__ __forceinline__ void pack_one(const float* __restrict__ W, const float* __restrict__ g,
                                         const float* __restrict__ v, ushort* __restrict__ hi,
                                         ushort* __restrict__ lo, int K, int idx) {
    int k = idx >> 7, col = idx & 127;
    float s = g[k] * rsqrtf(v[k] + BN_EPS);
    float f = s * W[idx];
    int S = K >> 5;
    int st = k >> 5, gq = (k >> 3) & 3, j = k & 7;
    int c = col >> 4, ln = (gq << 4) | (col & 15);
    int o = ((c * S + st) * 64 + ln) * 8 + j;
    ushort hb = f2bf_rn(f);
    hi[o] = hb;
    lo[o] = f2bf_rn(f - bf2f(hb));
}

__global__ void pack_all(
    const float* __restrict__ w1, const float* __restrict__ g1, const float* __restrict__ v1,
    ushort* __restrict__ W1h, ushort* __restrict__ W1l,
    const float* __restrict__ w2, const float* __restrict__ g2, const float* __restrict__ v2,
    ushort* __restrict__ W2h, ushort* __restrict__ W2l,
    const float* __restrict__ u1, const float* __restrict__ g3, const float* __restrict__ v3,
    ushort* __restrict__ U1h, ushort* __restrict__ U1l,
    const float* __restrict__ u2, const float* __restrict__ g4, const float* __restrict__ v4,
    ushort* __restrict__ U2h, ushort* __restrict__ U2l)
{
    int idx = blockIdx.x * 256 + threadIdx.x;       // 0..81919
    if (idx < 16384)       pack_one(w1, g1, v1, W1h, W1l, 128, idx);
    else if (idx < 32768)  pack_one(w2, g2, v2, W2h, W2l, 128, idx - 16384);
    else if (idx < 65536)  pack_one(u1, g3, v3, U1h, U1l, 256, idx - 32768);
    else                   pack_one(u2, g4, v4, U2h, U2l, 128, idx - 65536);
}

__global__ void init_bias(const float* __restrict__ b1, const float* __restrict__ b2,
                          const float* __restrict__ ub1, const float* __restrict__ ub2,
                          float* __restrict__ B1f, float* __restrict__ B2f,
                          float* __restrict__ C1f, float* __restrict__ C2f) {
    int t = threadIdx.x;  // 128
    B1f[t] = b1[t]; B2f[t] = b2[t]; C1f[t] = ub1[t]; C2f[t] = ub2[t];
}

// fused BN-bias fold (also zeroes cnt+spillCnt for the fill pass downstream).
__global__ __launch_bounds__(256) void fold_all(
    const float* __restrict__ w1, const float* __restrict__ g1, const float* __restrict__ b1,
    const float* __restrict__ m1, const float* __restrict__ v1, float* __restrict__ B1f,
    const float* __restrict__ w2, const float* __restrict__ g2, const float* __restrict__ b2,
    const float* __restrict__ m2, const float* __restrict__ v2, float* __restrict__ B2f,
    const float* __restrict__ u1, const float* __restrict__ g3, const float* __restrict__ b3,
    const float* __restrict__ m3, const float* __restrict__ v3, float* __restrict__ C1f,
    const float* __restrict__ u2, const float* __restrict__ g4, const float* __restrict__ b4,
    const float* __restrict__ m4, const float* __restrict__ v4, float* __restrict__ C2f,
    int* __restrict__ cnt, int* __restrict__ spillCnt)
{
    for (int i = blockIdx.x * 256 + threadIdx.x; i < NN + 1; i += 20 * 256) {
        if (i < NN) cnt[i] = 0; else spillCnt[0] = 0;
    }

    const int rs = blockIdx.x * 32;
    const float *W, *g, *bb, *m, *v;
    float* bf;
    int k0;
    if (rs < 128)      { W = w1; g = g1; bb = b1; m = m1; v = v1; bf = B1f; k0 = rs; }
    else if (rs < 256) { W = w2; g = g2; bb = b2; m = m2; v = v2; bf = B2f; k0 = rs - 128; }
    else if (rs < 512) { W = u1; g = g3; bb = b3; m = m3; v = v3; bf = C1f; k0 = rs - 256; }
    else               { W = u2; g = g4; bb = b4; m = m4; v = v4; bf = C2f; k0 = rs - 512; }

    const int t = threadIdx.x, j = t & 127, h = t >> 7;
    float acc = 0.f;
    #pragma unroll
    for (int kk = 0; kk < 16; ++kk) {
        int k = k0 + h * 16 + kk;
        float s = g[k] * rsqrtf(v[k] + BN_EPS);
        float tt = bb[k] - m[k] * s;
        acc = fmaf(tt, W[k * DD + j], acc);
    }
    __shared__ float S[256];
    S[t] = acc;
    __syncthreads();
    if (h == 0) atomicAdd(&bf[j], S[j] + S[128 + j]);
}

#define YLD 136
#define BCAP 56            // bucket capacity per dst (max deg here ~45)
#define SPILL_CAP 100000   // guarded; unused for this input
#define NCHUNK 400
#define CHSZ (EE / NCHUNK) // 2000
#define PSZ 6250           // NN / 8
#define FILLB (NCHUNK * 8) // 3200 fill blocks (first -> bid&7 = XCD partition)

// ---------------- fused kernel A: fill_bucket (memory/atomics) || prep FFN (MFMA) ------
__global__ __launch_bounds__(512, 4) void prep_fill(
    const float* __restrict__ reps, const int* __restrict__ edges,
    const ushort* __restrict__ W1h, const ushort* __restrict__ W1l, const float* __restrict__ B1,
    const ushort* __restrict__ W2h, const ushort* __restrict__ W2l, const float* __restrict__ B2,
    ushort* __restrict__ msgN,
    int* __restrict__ cnt, int* __restrict__ spillCnt,
    int* __restrict__ spill, int* __restrict__ bucket)
{
    __shared__ ushort Yh[128 * YLD];

    if (blockIdx.x < FILLB) {
        const int part = blockIdx.x & 7;
        const int ch   = blockIdx.x >> 3;
        const int lo = part * PSZ, hi2 = lo + PSZ;
        const int base = ch * CHSZ;
        for (int i = threadIdx.x; i < CHSZ; i += 512) {
            int e = base + i;
            int d = edges[e];
            if (d >= lo && d < hi2) {
                int s = atomicAdd(&cnt[d], 1);
                if (s < BCAP) bucket[d * BCAP + s] = e;
                else { int sl = atomicAdd(spillCnt, 1); if (sl < SPILL_CAP) spill[sl] = e; }
            }
        }
        return;
    }

    const int pb = blockIdx.x - FILLB;
    if (pb >= 391) return;
    const int t = threadIdx.x;
    const int w = t >> 6, l = t & 63, lg = l >> 4, lr = l & 15;
    const int n0 = pb * 128;
    int n = n0 + w * 16 + lr;
    int nc = n < NN ? n : NN - 1;
    const float* src = reps + (size_t)nc * DD;

    float b1v[8], b2v[8];
    #pragma unroll
    for (int c = 0; c < 8; ++c) { b1v[c] = B1[c * 16 + lr]; b2v[c] = B2[c * 16 + lr]; }

    f32x4 acc[8];
    #pragma unroll
    for (int c = 0; c < 8; ++c) acc[c] = (f32x4)(0.f);

    #pragma unroll
    for (int s = 0; s < 4; ++s) {
        float4 x0 = *reinterpret_cast<const float4*>(src + s * 32 + lg * 8);
        float4 x1 = *reinterpret_cast<const float4*>(src + s * 32 + lg * 8 + 4);
        bf16x8 ah, al;
        cvt_hilo(x0, x1, ah, al);
        #pragma unroll
        for (int c = 0; c < 8; ++c) {
            bf16x8 bh = *reinterpret_cast<const bf16x8*>(W1h + (size_t)((c * 4 + s) * 64 + l) * 8);
            bf16x8 bl = *reinterpret_cast<const bf16x8*>(W1l + (size_t)((c * 4 + s) * 64 + l) * 8);
            acc[c] = MFMA16(al, bh, acc[c]);
            acc[c] = MFMA16(ah, bl, acc[c]);
            acc[c] = MFMA16(ah, bh, acc[c]);
        }
    }
    #pragma unroll
    for (int c = 0; c < 8; ++c) {
        #pragma unroll
        for (int i = 0; i < 4; ++i) {
            float yv = gelu_f(acc[c][i] + b1v[c]);
            Yh[(w * 16 + lg * 4 + i) * YLD + c * 16 + lr] = f2bf_rn(yv);
        }
    }

    #pragma unroll
    for (int c = 0; c < 8; ++c) acc[c] = (f32x4)(0.f);
    const ushort* yr = Yh + (w * 16 + lr) * YLD;
    #pragma unroll
    for (int s = 0; s < 4; ++s) {
        bf16x8 ah = *reinterpret_cast<const bf16x8*>(yr + s * 32 + lg * 8);
        #pragma unroll
        for (int c = 0; c < 8; ++c) {
            bf16x8 bh = *reinterpret_cast<const bf16x8*>(W2h + (size_t)((c * 4 + s) * 64 + l) * 8);
            bf16x8 bl = *reinterpret_cast<const bf16x8*>(W2l + (size_t)((c * 4 + s) * 64 + l) * 8);
            acc[c] = MFMA16(ah, bl, acc[c]);
            acc[c] = MFMA16(ah, bh, acc[c]);
        }
    }

    const int nrow = n0 + w * 16 + lg * 4;
    #pragma unroll
    for (int i = 0; i < 4; ++i) {
        if (nrow + i < NN) {
            #pragma unroll
            for (int c = 0; c < 8; ++c)
                msgN[(size_t)(nrow + i) * DD + c * 16 + lr] = f2bf_rn(gelu_f(acc[c][i] + b2v[c]));
        }
    }
}

// ---------------- fused kernel B: 16 nodes/block (3125 blocks, 256 thr) ----------------
// Phase 1: r16's proven gather geometry (1 node per 16-lane group, 4-way unroll) -> LDS.
// Phase 2: node FFN column-split across 4 waves (wave w: col tiles 2w, 2w+1).
// NN = 3125*16 exactly -> no bounds checks.
__global__ __launch_bounds__(256, 8) void agg_node(
    const float* __restrict__ reps, const int* __restrict__ edges, const float* __restrict__ ew,
    const int* __restrict__ bucket, const int* __restrict__ cnt,
    const int* __restrict__ spillCnt, const int* __restrict__ spill,
    const ushort* __restrict__ msgN,
    const ushort* __restrict__ U1h, const ushort* __restrict__ U1l, const float* __restrict__ C1,
    const ushort* __restrict__ U2h, const ushort* __restrict__ U2l, const float* __restrict__ C2,
    float* __restrict__ out)
{
    __shared__ ushort aggL[16 * YLD];
    __shared__ ushort Yh[16 * YLD];
    __shared__ float ssqP[4][16];
    const int t = threadIdx.x;
    const int n0 = blockIdx.x * 16;

    // ---- phase 1: 16 groups x 1 node ----
    {
        const int g = t >> 4, la = t & 15;
        const int node = n0 + g;
        const ushort* base = msgN + la * 8;
        float acc[8] = {0.f, 0.f, 0.f, 0.f, 0.f, 0.f, 0.f, 0.f};
        const int dc = cnt[node];
        const int deg = dc < BCAP ? dc : BCAP;
        const int* b = bucket + node * BCAP;
        int k = 0;
        for (; k + 3 < deg; k += 4) {
            int e0 = b[k], e1 = b[k + 1], e2 = b[k + 2], e3 = b[k + 3];
            int q0 = edges[EE + e0], q1 = edges[EE + e1];
            int q2 = edges[EE + e2], q3 = edges[EE + e3];
            float w0 = ew[e0], w1 = ew[e1], w2 = ew[e2], w3 = ew[e3];
            bf16x8 m0 = *reinterpret_cast<const bf16x8*>(base + (size_t)q0 * DD);
            bf16x8 m1 = *reinterpret_cast<const bf16x8*>(base + (size_t)q1 * DD);
            bf16x8 m2 = *reinterpret_cast<const bf16x8*>(base + (size_t)q2 * DD);
            bf16x8 m3 = *reinterpret_cast<const bf16x8*>(base + (size_t)q3 * DD);
            #pragma unroll
            for (int j = 0; j < 8; ++j) {
                acc[j] = fmaf(w0, bf2f((ushort)m0[j]), acc[j]);
                acc[j] = fmaf(w1, bf2f((ushort)m1[j]), acc[j]);
                acc[j] = fmaf(w2, bf2f((ushort)m2[j]), acc[j]);
                acc[j] = fmaf(w3, bf2f((ushort)m3[j]), acc[j]);
            }
        }
        for (; k < deg; ++k) {
            int e0 = b[k];
            int q0 = edges[EE + e0];
            float w0 = ew[e0];
            bf16x8 m0 = *reinterpret_cast<const bf16x8*>(base + (size_t)q0 * DD);
            #pragma unroll
            for (int j = 0; j < 8; ++j) acc[j] = fmaf(w0, bf2f((ushort)m0[j]), acc[j]);
        }
        if (dc > BCAP) {                 // exact spill fold-in (empty here)
            int sc = spillCnt[0]; if (sc > SPILL_CAP) sc = SPILL_CAP;
            for (int i = 0; i < sc; ++i) {
                int eid = spill[i];
                if (edges[eid] == node) {
                    int q0 = edges[EE + eid];
                    float w0 = ew[eid];
                    bf16x8 m0 = *reinterpret_cast<const bf16x8*>(base + (size_t)q0 * DD);
                    #pragma unroll
                    for (int j = 0; j < 8; ++j)
                        acc[j] = fmaf(w0, bf2f((ushort)m0[j]), acc[j]);
                }
            }
        }
        uint4 o;
        o.x = pk2(acc[0], acc[1]);
        o.y = pk2(acc[2], acc[3]);
        o.z = pk2(acc[4], acc[5]);
        o.w = pk2(acc[6], acc[7]);
        *reinterpret_cast<uint4*>(&aggL[g * YLD + la * 8]) = o;
    }
    __syncthreads();

    // ---- phase 2: node FFN, wave w owns col tiles {2w, 2w+1} ----
    const int w = t >> 6, l = t & 63, lg = l >> 4, lr = l & 15;

    float c1v[2], c2v[2];
    #pragma unroll
    for (int cc = 0; cc < 2; ++cc) {
        c1v[cc] = C1[(2 * w + cc) * 16 + lr];
        c2v[cc] = C2[(2 * w + cc) * 16 + lr];
    }

    f32x4 acc[2];
    #pragma unroll
    for (int cc = 0; cc < 2; ++cc) acc[cc] = (f32x4)(0.f);

    // layer 1, reps half (k=0..127): f32 A hi+lo, 3 MFMAs
    #pragma unroll
    for (int s = 0; s < 4; ++s) {
        const float* sp = reps + (size_t)(n0 + lr) * DD + s * 32 + lg * 8;
        float4 x0 = *reinterpret_cast<const float4*>(sp);
        float4 x1 = *reinterpret_cast<const float4*>(sp + 4);
        bf16x8 ah, al;
        cvt_hilo(x0, x1, ah, al);
        #pragma unroll
        for (int cc = 0; cc < 2; ++cc) {
            int c = 2 * w + cc;
            bf16x8 bh = *reinterpret_cast<const bf16x8*>(U1h + (size_t)((c * 8 + s) * 64 + l) * 8);
            bf16x8 bl = *reinterpret_cast<const bf16x8*>(U1l + (size_t)((c * 8 + s) * 64 + l) * 8);
            acc[cc] = MFMA16(al, bh, acc[cc]);
            acc[cc] = MFMA16(ah, bl, acc[cc]);
            acc[cc] = MFMA16(ah, bh, acc[cc]);
        }
    }
    // layer 1, agg half (k=128..255): bf16 A from LDS, 2 MFMAs
    const ushort* ar = aggL + lr * YLD;
    #pragma unroll
    for (int s = 4; s < 8; ++s) {
        bf16x8 ah = *reinterpret_cast<const bf16x8*>(ar + (s - 4) * 32 + lg * 8);
        #pragma unroll
        for (int cc = 0; cc < 2; ++cc) {
            int c = 2 * w + cc;
            bf16x8 bh = *reinterpret_cast<const bf16x8*>(U1h + (size_t)((c * 8 + s) * 64 + l) * 8);
            bf16x8 bl = *reinterpret_cast<const bf16x8*>(U1l + (size_t)((c * 8 + s) * 64 + l) * 8);
            acc[cc] = MFMA16(ah, bl, acc[cc]);
            acc[cc] = MFMA16(ah, bh, acc[cc]);
        }
    }
    #pragma unroll
    for (int cc = 0; cc < 2; ++cc) {
        #pragma unroll
        for (int i = 0; i < 4; ++i) {
            float yv = gelu_f(acc[cc][i] + c1v[cc]);
            Yh[(lg * 4 + i) * YLD + (2 * w + cc) * 16 + lr] = f2bf_rn(yv);
        }
    }
    __syncthreads();   // Y rows assembled from all 4 waves' column slices

    // layer 2: K=128, A = full bf16 Y rows from LDS, 2 MFMAs
    #pragma unroll
    for (int cc = 0; cc < 2; ++cc) acc[cc] = (f32x4)(0.f);
    const ushort* yr2 = Yh + lr * YLD;
    #pragma unroll
    for (int s = 0; s < 4; ++s) {
        bf16x8 ah = *reinterpret_cast<const bf16x8*>(yr2 + s * 32 + lg * 8);
        #pragma unroll
        for (int cc = 0; cc < 2; ++cc) {
            int c = 2 * w + cc;
            bf16x8 bh = *reinterpret_cast<const bf16x8*>(U2h + (size_t)((c * 4 + s) * 64 + l) * 8);
            bf16x8 bl = *reinterpret_cast<const bf16x8*>(U2l + (size_t)((c * 4 + s) * 64 + l) * 8);
            acc[cc] = MFMA16(ah, bl, acc[cc]);
            acc[cc] = MFMA16(ah, bh, acc[cc]);
        }
    }

    // bias + GELU + 4-partial L2-norm
    float ssq[4] = {0.f, 0.f, 0.f, 0.f};
    #pragma unroll
    for (int cc = 0; cc < 2; ++cc) {
        #pragma unroll
        for (int i = 0; i < 4; ++i) {
            float vv = gelu_f(acc[cc][i] + c2v[cc]);
            acc[cc][i] = vv;
            ssq[i] = fmaf(vv, vv, ssq[i]);
        }
    }
    #pragma unroll
    for (int i = 0; i < 4; ++i) {
        #pragma unroll
        for (int msk = 1; msk < 16; msk <<= 1) ssq[i] += __shfl_xor(ssq[i], msk);
    }
    const int row0 = lg * 4;
    if (lr == 0) {
        #pragma unroll
        for (int i = 0; i < 4; ++i) ssqP[w][row0 + i] = ssq[i];
    }
    __syncthreads();
    #pragma unroll
    for (int i = 0; i < 4; ++i) {
        float tot = ssqP[0][row0 + i] + ssqP[1][row0 + i] +
                    ssqP[2][row0 + i] + ssqP[3][row0 + i];
        float sc = rsqrtf(fmaxf(tot, 1e-12f));
        #pragma unroll
        for (int cc = 0; cc < 2; ++cc)
            out[(size_t)(n0 + row0 + i) * DD + (2 * w + cc) * 16 + lr] = acc[cc][i] * sc;
    }
}

// ---------------- launch ----------------
extern "C" void kernel_launch(void* const* d_in, const int* in_sizes, int n_in,
                              void* d_out, int out_size, void* d_ws, size_t ws_size,
                              hipStream_t stream)
{
    const float* reps = (const float*)d_in[0];
    const int*   edges = (const int*)d_in[1];
    const float* ew   = (const float*)d_in[2];
    const float* bn1g = (const float*)d_in[3];
    const float* bn1b = (const float*)d_in[4];
    const float* bn1m = (const float*)d_in[5];
    const float* bn1v = (const float*)d_in[6];
    const float* w1   = (const float*)d_in[7];
    const float* b1   = (const float*)d_in[8];
    const float* bn2g = (const float*)d_in[9];
    const float* bn2b = (const float*)d_in[10];
    const float* bn2m = (const float*)d_in[11];
    const float* bn2v = (const float*)d_in[12];
    const float* w2   = (const float*)d_in[13];
    const float* b2   = (const float*)d_in[14];
    const float* ubn1g = (const float*)d_in[15];
    const float* ubn1b = (const float*)d_in[16];
    const float* ubn1m = (const float*)d_in[17];
    const float* ubn1v = (const float*)d_in[18];
    const float* u1    = (const float*)d_in[19];
    const float* ub1   = (const float*)d_in[20];
    const float* ubn2g = (const float*)d_in[21];
    const float* ubn2b = (const float*)d_in[22];
    const float* ubn2m = (const float*)d_in[23];
    const float* ubn2v = (const float*)d_in[24];
    const float* u2    = (const float*)d_in[25];
    const float* ub2   = (const float*)d_in[26];

    // workspace layout (bytes) — d_out used ONLY for final output
    char* wsb = (char*)d_ws;
    ushort* msgN     = (ushort*)wsb;                     // 12,800,000 B
    int*    bucket   = (int*)(wsb + 12800000);           // NN*BCAP*4 = 11,200,000 B
    int*    cnt      = (int*)(wsb + 24000000);           // 200,000 B
    int*    spillCnt = (int*)(wsb + 24200000);           // 4 B (+pad)
    int*    spill    = (int*)(wsb + 24200016);           // 400,000 B
    float*  B1f      = (float*)(wsb + 24600016);         // 128 f32 each, 16B aligned
    float*  B2f = B1f + 128;
    float*  C1f = B2f + 128;
    float*  C2f = C1f + 128;
    ushort* up  = (ushort*)(C2f + 128);
    ushort* W1h = up;                                    // 16384 each
    ushort* W1l = W1h + 16384;
    ushort* W2h = W1l + 16384;
    ushort* W2l = W2h + 16384;
    ushort* U1h = W2l + 16384;                           // 32768 each
    ushort* U1l = U1h + 32768;
    ushort* U2h = U1l + 32768;                           // 16384 each
    ushort* U2l = U2h + 16384;
    if (ws_size < 24950000) return;

    init_bias<<<1, 128, 0, stream>>>(b1, b2, ub1, ub2, B1f, B2f, C1f, C2f);
    pack_all<<<320, 256, 0, stream>>>(w1, bn1g, bn1v, W1h, W1l,
                                      w2, bn2g, bn2v, W2h, W2l,
                                      u1, ubn1g, ubn1v, U1h, U1l,
                                      u2, ubn2g, ubn2v, U2h, U2l);
    fold_all<<<20, 256, 0, stream>>>(w1, bn1g, bn1b, bn1m, bn1v, B1f,
                                     w2, bn2g, bn2b, bn2m, bn2v, B2f,
                                     u1, ubn1g, ubn1b, ubn1m, ubn1v, C1f,
                                     u2, ubn2g, ubn2b, ubn2m, ubn2v, C2f,
                                     cnt, spillCnt);

    prep_fill<<<FILLB + 392, 512, 0, stream>>>(reps, edges, W1h, W1l, B1f,
                                               W2h, W2l, B2f, msgN,
                                               cnt, spillCnt, spill, bucket);
    agg_node<<<NN / 16, 256, 0, stream>>>(reps, edges, ew, bucket, cnt,
                                          spillCnt, spill, msgN,
                                          U1h, U1l, C1f, U2h, U2l, C2f,
                                          (float*)d_out);
}